// Round 4
// baseline (6634.862 us; speedup 1.0000x reference)
//
#include <hip/hip_runtime.h>

// wave-local LDS ordering fence (single-wave region; LDS pipe is in-order per wave)
#define WSYNC asm volatile("s_waitcnt lgkmcnt(0)" ::: "memory")

__device__ const int g_offtab[4][5] = {{0,128,384,640,896},
                                       {1024,1152,1664,2176,2688},
                                       {2816,2944,3456,3968,4480},
                                       {4608,4736,5248,5760,6272}};
__device__ const int g_ufin[6] = {1,4,8,8,8,4};
__device__ const int g_dfin[6] = {4,8,8,8,4,1};

struct SH {
  float *pool, *CUR, *BIGT, *GbM, *TM, *GM, *ATile, *PdL, *PuL, *nrmI, *sinvv, *sdiv;
  int *isel, *xi;
};

// ============ kernel 1: proj[s][k] = ETA*mlp(x_s)[k] ============
__global__ __launch_bounds__(256) void mlp_kernel(
    const float* __restrict__ W1, const float* __restrict__ b1,
    const float* __restrict__ W2, const float* __restrict__ b2,
    const int* __restrict__ x, float* __restrict__ proj)
{
  __shared__ float hbuf[8][64];
  const int tid = threadIdx.x;
  const int s0 = blockIdx.x << 3;
  for (int e = tid; e < 512; e += 256) {
    const int sl = e >> 6, hh = e & 63;
    const int* xr = x + (s0 + sl) * 36;
    const float* wr = W1 + hh * 36;
    float acc = b1[hh];
    #pragma unroll
    for (int t = 0; t < 36; ++t) acc += wr[t] * (float)xr[t];
    hbuf[sl][hh] = fmaxf(acc, 0.0f);
  }
  __syncthreads();
  for (int k = tid; k < 6400; k += 256) {
    const float4* wr = (const float4*)(W2 + (size_t)k * 64);
    float acc[8];
    #pragma unroll
    for (int s2 = 0; s2 < 8; ++s2) acc[s2] = 0.0f;
    #pragma unroll
    for (int c = 0; c < 16; ++c) {
      const float4 w = wr[c];
      #pragma unroll
      for (int s2 = 0; s2 < 8; ++s2) {
        const float4 hv = ((const float4*)hbuf[s2])[c];
        acc[s2] += w.x * hv.x + w.y * hv.y + w.z * hv.z + w.w * hv.w;
      }
    }
    const float bb = b2[k];
    #pragma unroll
    for (int s2 = 0; s2 < 8; ++s2)
      proj[(size_t)(s0 + s2) * 6400 + k] = 0.001f * (acc[s2] + bb);
  }
}

// ---------------- reduce-scatter: after run, lane holds sum for index (lane & (P-1)) ----------------
template<int CL>
struct RS {
  static __device__ __forceinline__ void run(float* a, int lane) {
    constexpr int M = CL / 2;
    float rx[CL];
    #pragma unroll
    for (int t = 0; t < CL; ++t) rx[t] = __shfl_xor(a[t], M);
    const bool up = (lane & M) != 0;
    #pragma unroll
    for (int t = 0; t < M; ++t)
      a[t] = up ? (a[t + M] + rx[t + M]) : (a[t] + rx[t]);
    RS<M>::run(a, lane);
  }
};
template<> struct RS<1> { static __device__ __forceinline__ void run(float*, int) {} };

// ============ one-sided (Hestenes) register Jacobi — WAVE0 ONLY, barrier-free ============
// Gin: NxN sym PSD (stride 36). V gets UNnormalized W columns (w_k = lambda_k u_k);
// lamD[k*37] = lambda_k; nrmI[k] = 1/||w_k||.  Column norms tracked IN REGISTERS.
template<int N, int MAXSW>
__device__ __forceinline__ void jacobiR(const float* __restrict__ Gin, float* __restrict__ V,
                                        float* __restrict__ lamD, float* __restrict__ nrmI, int lane)
{
  constexpr int P = N / 2;
  float w[N];
  #pragma unroll
  for (int c = 0; c < N; ++c) w[c] = 0.0f;
  float cn = 0.0f;
  if (lane < N) {
    #pragma unroll
    for (int c = 0; c < N; ++c) w[c] = Gin[lane * 36 + c];
    #pragma unroll
    for (int r = 0; r < N; ++r) { const float g = Gin[r * 36 + lane]; cn += g * g; }
  }
  const int myk = lane & (P - 1);
  float np_ = __shfl(cn, 2 * myk);
  float nq_ = __shfl(cn, 2 * myk + 1);
  for (int sw = 0; sw < MAXSW; ++sw) {
    bool conv = true;
    for (int rd = 0; rd < N - 1; ++rd) {
      float a0[P];
      #pragma unroll
      for (int k = 0; k < P; ++k) a0[k] = w[2 * k] * w[2 * k + 1];
      #pragma unroll
      for (int t = 0; t < P; ++t) a0[t] += __shfl_xor(a0[t], P);
      RS<P>::run(a0, lane);
      const float apq = a0[0];
      float c_ = 1.0f, s_ = 0.0f;
      if (fabsf(apq) > 1e-36f + 1e-12f * (np_ + nq_)) {
        const float tau = (nq_ - np_) / (2.0f * apq);
        const float t = copysignf(1.0f, tau) / (fabsf(tau) + sqrtf(1.0f + tau * tau));
        c_ = 1.0f / sqrtf(1.0f + t * t);
        s_ = t * c_;
      }
      conv = conv && (fabsf(apq) <= 1e-6f * sqrtf(np_ * nq_) + 1e-30f);
      // norm update + seat-shift redistribution (registers + 3 shfls, no LDS)
      const float cs2 = 2.0f * c_ * s_ * apq;
      const float npn = c_ * c_ * np_ + s_ * s_ * nq_ - cs2;
      const float nqn = s_ * s_ * np_ + c_ * c_ * nq_ + cs2;
      const float shA = __shfl(npn, (myk > 0) ? (myk - 1) : 0);
      const float shB = __shfl(nqn, 0);
      const float shC = __shfl(nqn, (myk < P - 1) ? (myk + 1) : 0);
      np_ = (myk == 0) ? npn : ((myk == 1) ? shB : shA);
      nq_ = (myk == P - 1) ? npn : shC;
      // rotate own row + static tournament seat permutation
      float nw[N];
      #pragma unroll
      for (int k = 0; k < P; ++k) {
        const float ck = __shfl(c_, k);
        const float sk = __shfl(s_, k);
        const float a = w[2 * k], b = w[2 * k + 1];
        const float wa = ck * a - sk * b;
        const float wb = sk * a + ck * b;
        const int t0 = (k == 0) ? 0 : ((k == P - 1) ? (2 * P - 1) : (2 * k + 2));
        const int t1 = (k == 0) ? 2 : (2 * k - 1);
        nw[t0] = wa; nw[t1] = wb;
      }
      #pragma unroll
      for (int c2 = 0; c2 < N; ++c2) w[c2] = nw[c2];
    }
    if (__all(conv)) break;
  }
  if (lane < N) {
    #pragma unroll
    for (int c = 0; c < N; ++c) V[lane * 36 + c] = w[c];
  }
  WSYNC;
  if (lane < N) {
    float acc = 0.0f;
    #pragma unroll
    for (int r = 0; r < N; ++r) { const float v = V[r * 36 + lane]; acc += v * v; }
    lamD[lane * 37] = sqrtf(acc);
    nrmI[lane] = (acc > 1e-38f) ? (1.0f / sqrtf(acc)) : 0.0f;
  }
  WSYNC;
}

// top-CB eigen selection + scales — WAVE0 ONLY
template<int N, int CB>
__device__ __forceinline__ void selectTop(const SH& sh, int tid) {
  float v_ = (tid < N) ? sh.GM[tid * 37] : -3.0e38f;
  int ix = tid;
  #pragma unroll
  for (int t = 0; t < CB; ++t) {
    float bv = v_; int bi = ix;
    #pragma unroll
    for (int mk = 32; mk; mk >>= 1) {
      const float ov = __shfl_xor(bv, mk);
      const int oi = __shfl_xor(bi, mk);
      if (ov > bv || (ov == bv && oi < bi)) { bv = ov; bi = oi; }
    }
    if (tid == 0) sh.isel[t] = bi;
    if (ix == bi) v_ = -3.0e38f;
  }
  WSYNC;
  if (tid < CB) {
    const int a = sh.isel[tid];
    const float lam = sh.GM[a * 37];
    const float s_ = sqrtf(fmaxf(lam, 0.0f));
    sh.sinvv[tid] = (1.0f / sqrtf(s_ + 1e-12f)) * sh.nrmI[a];
    sh.sdiv[tid] = 1.0f / fmaxf(s_, 1e-25f);
  }
  WSYNC;
}

// absorb site (i1,j): BIGT[(rr-RR0)*DBW+db][ua] = sum_x pool[u,x,d] * A[a,rr,b,x]   (128T)
template<int U, int DD, int BD, int RR0, int RR1>
__device__ __forceinline__ void absorbT(const float* __restrict__ Tg, const float* __restrict__ poolS,
    float* __restrict__ BIGT, float* __restrict__ ATile, const int* __restrict__ xi,
    int i1, int j, int tid)
{
  constexpr int DBW = DD * BD;
  constexpr int MT = U * 4;
  constexpr int MTL = (MT == 32) ? 5 : 4;
  constexpr int DBL = (DBW == 32) ? 5 : ((DBW == 16) ? 4 : 0);
  constexpr int BDL = (BD == 4) ? 2 : 0;
  constexpr int NEL = MT * DBW * (RR1 - RR0);
  const int ph = xi[i1 * 6 + j];
  const float* tb = Tg + (size_t)(i1 * 6 + j) * 512;
  for (int e = tid; e < 256; e += 128) ATile[e] = tb[e * 2 + ph];
  __syncthreads();
  for (int e = tid; e < NEL; e += 128) {
    const int ua = e & (MT - 1);
    const int db = (e >> MTL) & (DBW - 1);
    const int rr = RR0 + (e >> (MTL + DBL));
    const int u = ua >> 2, a = ua & 3;
    const int d_ = db >> BDL, b = db & (BD - 1);
    const float* op = poolS + u * 33 + d_;
    const float4 av = *(const float4*)(ATile + a * 64 + rr * 16 + b * 4);
    BIGT[((rr - RR0) * DBW + db) * 36 + ua] = op[0] * av.x + op[8] * av.y + op[16] * av.z + op[24] * av.w;
  }
  __syncthreads();
}

// G(+)= A^T A over NR stride-36 rows, MC cols (128T)
template<int NR, int MC, bool INIT>
__device__ __forceinline__ void gramT(float* __restrict__ G, const float* __restrict__ A, int tid)
{
  constexpr int Q4 = MC / 4;
  constexpr int NEL = MC * Q4;
  for (int e = tid; e < NEL; e += 128) {
    const int c2q = e & (Q4 - 1);
    const int c1 = e >> ((MC == 32) ? 3 : 2);
    float ax = 0.f, ay = 0.f, az = 0.f, aw = 0.f;
    #pragma unroll 8
    for (int r = 0; r < NR; ++r) {
      const float a1 = A[r * 36 + c1];
      const float4 a2 = *(const float4*)(A + r * 36 + c2q * 4);
      ax += a1 * a2.x; ay += a1 * a2.y; az += a1 * a2.z; aw += a1 * a2.w;
    }
    float4* gp = (float4*)(G + c1 * 36 + c2q * 4);
    if (INIT) { float4 o; o.x = ax; o.y = ay; o.z = az; o.w = aw; *gp = o; }
    else { float4 o = *gp; o.x += ax; o.y += ay; o.z += az; o.w += aw; *gp = o; }
  }
  __syncthreads();
}

// Bn[i+1] slice: CUR[(cc*4+RR0+rrL)][dd] (or pool[5]) = sum_m BIGT[rrL*DN+dd][m]*Pu[m][cc] (128T)
template<int NLOC, int DN, int CB, int M, bool LAST, int RR0>
__device__ __forceinline__ void bn1T(const SH& sh, int tid)
{
  constexpr int MQ4 = M / 4;
  constexpr int DNL = (DN == 32) ? 5 : ((DN == 16) ? 4 : 0);
  constexpr int NEL = CB * NLOC * DN;
  for (int e = tid; e < NEL; e += 128) {
    const int dd = e & (DN - 1);
    const int t2 = e >> DNL;
    const int rrL = t2 & (NLOC - 1);
    const int cc = t2 >> ((NLOC == 4) ? 2 : 1);
    const int row = rrL * DN + dd;
    float acc = 0.f;
    #pragma unroll
    for (int mq = 0; mq < MQ4; ++mq) {
      const float4 bv = *(const float4*)(sh.BIGT + row * 36 + mq * 4);
      acc += bv.x * sh.PuL[(mq * 4 + 0) * 8 + cc] + bv.y * sh.PuL[(mq * 4 + 1) * 8 + cc]
           + bv.z * sh.PuL[(mq * 4 + 2) * 8 + cc] + bv.w * sh.PuL[(mq * 4 + 3) * 8 + cc];
    }
    if (!LAST) sh.CUR[(cc * 4 + RR0 + rrL) * 36 + dd] = acc;
    else       sh.pool[5 * 264 + cc * 33 + (RR0 + rrL) * 8] = acc;
  }
  __syncthreads();
}

// ============ one truncation pair, fully compile-time specialized ============
template<int M, int CB, int UCUR, int PATH, int U1, int DD1, int BD1, int I>
__device__ __forceinline__ void trunc(const float* __restrict__ Tg, const SH& sh,
                                      int j, bool svd, float* __restrict__ projb, int tid)
{
  constexpr int P = UCUR * 4;
  constexpr int DN = DD1 * BD1;
  constexpr bool TWO = (DN == 32);
  constexpr int MQ4 = M / 4;
  constexpr int CBL = (CB == 8) ? 3 : 2;
  const float* poolN = sh.pool + (I + 1) * 264;

  if (svd) {
    if (PATH == 2) {
      absorbT<U1, DD1, BD1, 0, 4>(Tg, poolN, sh.BIGT, sh.ATile, sh.xi, I + 1, j, tid);
      gramT<P, M, true>(sh.GbM, sh.CUR, tid);   // Gt
      if (tid < 64) {
        { // T1 = Gt*mb (M x 4) -> TM   (mb[l][r] = BIGT[r][l])
          const int r = tid & 3, k = tid >> 2;
          float acc = 0.f;
          #pragma unroll
          for (int lq = 0; lq < MQ4; ++lq) {
            const float4 g = *(const float4*)(sh.GbM + k * 36 + lq * 4);
            const float4 b = *(const float4*)(sh.BIGT + r * 36 + lq * 4);
            acc += g.x * b.x + g.y * b.y + g.z * b.z + g.w * b.w;
          }
          if (tid < M * 4) sh.TM[k * 36 + r] = acc;
        }
        WSYNC;
        if (tid < 16) {  // G = mb^T*T1 (4x4)
          const int c = tid & 3, r = tid >> 2;
          float acc = 0.f;
          #pragma unroll
          for (int k = 0; k < M; ++k) acc += sh.BIGT[r * 36 + k] * sh.TM[k * 36 + c];
          sh.GM[r * 36 + c] = acc;
        }
        WSYNC;
        jacobiR<4, 6>(sh.GM, sh.TM + 576, sh.GM, sh.nrmI, tid);
        selectTop<4, CB>(sh, tid);
      }
      __syncthreads();
      for (int e = tid; e < M * CB; e += 128) {  // Pd = mb W sinv'
        const int k = e & (CB - 1), mrow = e >> CBL;
        const int a = sh.isel[k];
        float acc = 0.f;
        #pragma unroll
        for (int r = 0; r < 4; ++r) acc += sh.BIGT[r * 36 + mrow] * sh.TM[576 + r * 36 + a];
        sh.PdL[mrow * 8 + k] = acc * sh.sinvv[k];
      }
      __syncthreads();
      for (int e = tid; e < M * CB; e += 128) {  // Pu = Gt Pd / s
        const int k = e & (CB - 1), mrow = e >> CBL;
        float acc = 0.f;
        #pragma unroll
        for (int l = 0; l < M; ++l) acc += sh.GbM[mrow * 36 + l] * sh.PdL[l * 8 + k];
        sh.PuL[mrow * 8 + k] = acc * sh.sdiv[k];
      }
      __syncthreads();
    } else if (PATH == 0) {
      if (!TWO) {
        absorbT<U1, DD1, BD1, 0, 4>(Tg, poolN, sh.BIGT, sh.ATile, sh.xi, I + 1, j, tid);
        gramT<4 * DN, M, true>(sh.GbM, sh.BIGT, tid);
      } else {
        absorbT<U1, DD1, BD1, 0, 2>(Tg, poolN, sh.BIGT, sh.ATile, sh.xi, I + 1, j, tid);
        gramT<2 * DN, M, true>(sh.GbM, sh.BIGT, tid);
        absorbT<U1, DD1, BD1, 2, 4>(Tg, poolN, sh.BIGT, sh.ATile, sh.xi, I + 1, j, tid);
        gramT<2 * DN, M, false>(sh.GbM, sh.BIGT, tid);
      }
      for (int e = tid; e < P * MQ4; e += 128) {   // T = mt*Gb (P x M)
        const int lq = e & (MQ4 - 1);
        const int pr = e >> ((M == 32) ? 3 : 2);
        float ax = 0.f, ay = 0.f, az = 0.f, aw = 0.f;
        #pragma unroll 8
        for (int k = 0; k < M; ++k) {
          const float a1 = sh.CUR[pr * 36 + k];
          const float4 g = *(const float4*)(sh.GbM + k * 36 + lq * 4);
          ax += a1 * g.x; ay += a1 * g.y; az += a1 * g.z; aw += a1 * g.w;
        }
        float4 o; o.x = ax; o.y = ay; o.z = az; o.w = aw;
        *(float4*)(sh.TM + pr * 36 + lq * 4) = o;
      }
      __syncthreads();
      for (int e = tid; e < P * P; e += 128) {     // G = T*mt^T (P x P)
        const int pc = e & (P - 1);
        const int pr = e >> ((P == 32) ? 5 : ((P == 16) ? 4 : 2));
        float acc = 0.f;
        #pragma unroll
        for (int lq = 0; lq < MQ4; ++lq) {
          const float4 t = *(const float4*)(sh.TM + pr * 36 + lq * 4);
          const float4 c = *(const float4*)(sh.CUR + pc * 36 + lq * 4);
          acc += t.x * c.x + t.y * c.y + t.z * c.z + t.w * c.w;
        }
        sh.GM[pr * 36 + pc] = acc;
      }
      __syncthreads();
      if (tid < 64) {
        jacobiR<P, ((P == 32) ? 10 : ((P == 16) ? 9 : 6))>(sh.GM, sh.TM, sh.GM, sh.nrmI, tid);
        selectTop<P, CB>(sh, tid);
      }
      __syncthreads();
      for (int e = tid; e < M * CB; e += 128) {  // Pu = mt^T W sinv'
        const int k = e & (CB - 1), mrow = e >> CBL;
        const int a = sh.isel[k];
        float acc = 0.f;
        #pragma unroll 8
        for (int pr = 0; pr < P; ++pr) acc += sh.CUR[pr * 36 + mrow] * sh.TM[pr * 36 + a];
        sh.PuL[mrow * 8 + k] = acc * sh.sinvv[k];
      }
      __syncthreads();
      for (int e = tid; e < M * CB; e += 128) {  // Pd = Gb Pu / s
        const int k = e & (CB - 1), mrow = e >> CBL;
        float acc = 0.f;
        #pragma unroll 8
        for (int l = 0; l < M; ++l) acc += sh.GbM[mrow * 36 + l] * sh.PuL[l * 8 + k];
        sh.PdL[mrow * 8 + k] = acc * sh.sdiv[k];
      }
      __syncthreads();
    } else {
      // PATH 1: Gt, Gb, chol(Gb)->R2, H = R2 Gt R2^T (16x16)
      absorbT<U1, DD1, BD1, 0, 4>(Tg, poolN, sh.BIGT, sh.ATile, sh.xi, I + 1, j, tid);
      gramT<P, M, true>(sh.GbM + 576, sh.CUR, tid);   // Gt
      gramT<4 * DN, M, true>(sh.GbM, sh.BIGT, tid);   // Gb
      if (tid < 64) {
        float v_ = (tid < 16) ? sh.GbM[tid * 37] : -3.0e38f;
        #pragma unroll
        for (int mk = 32; mk; mk >>= 1) v_ = fmaxf(v_, __shfl_xor(v_, mk));
        const float thr = 1e-10f * v_ + 1e-35f;
        #pragma unroll
        for (int k = 0; k < 16; ++k) {
          const float dk = sh.GbM[k * 37];
          const float rs = (dk > thr) ? (1.0f / sqrtf(dk)) : 0.0f;
          if (tid < 16) sh.TM[k * 36 + tid] = sh.GbM[k * 36 + tid] * rs;
          WSYNC;
          for (int e = tid; e < (15 - k) * 16; e += 64) {
            const int ii = k + 1 + (e >> 4), jc = e & 15;
            sh.GbM[ii * 36 + jc] -= sh.TM[k * 36 + ii] * sh.TM[k * 36 + jc];
          }
          WSYNC;
        }
        { // T1 = R2*Gt -> TM+576
          const int jq = tid & 3, k = tid >> 2;
          float ax = 0.f, ay = 0.f, az = 0.f, aw = 0.f;
          #pragma unroll
          for (int l = 0; l < 16; ++l) {
            const float r2 = sh.TM[k * 36 + l];
            const float4 g = *(const float4*)(sh.GbM + 576 + l * 36 + jq * 4);
            ax += r2 * g.x; ay += r2 * g.y; az += r2 * g.z; aw += r2 * g.w;
          }
          float4 o; o.x = ax; o.y = ay; o.z = az; o.w = aw;
          *(float4*)(sh.TM + 576 + k * 36 + jq * 4) = o;
        }
        WSYNC;
        for (int e = tid; e < 256; e += 64) {  // H = T1*R2^T -> GM
          const int k2 = e & 15, k = e >> 4;
          float acc = 0.f;
          #pragma unroll
          for (int lq = 0; lq < 4; ++lq) {
            const float4 t = *(const float4*)(sh.TM + 576 + k * 36 + lq * 4);
            const float4 r = *(const float4*)(sh.TM + k2 * 36 + lq * 4);
            acc += t.x * r.x + t.y * r.y + t.z * r.z + t.w * r.w;
          }
          sh.GM[k * 36 + k2] = acc;
        }
        WSYNC;
        jacobiR<16, 9>(sh.GM, sh.TM + 576, sh.GM, sh.nrmI, tid);
        selectTop<16, CB>(sh, tid);
      }
      __syncthreads();
      for (int e = tid; e < M * CB; e += 128) {  // Pd = R2^T W sinv'
        const int k = e & (CB - 1), mrow = e >> CBL;
        const int a = sh.isel[k];
        float acc = 0.f;
        #pragma unroll
        for (int t2 = 0; t2 < 16; ++t2) acc += sh.TM[t2 * 36 + mrow] * sh.TM[576 + t2 * 36 + a];
        sh.PdL[mrow * 8 + k] = acc * sh.sinvv[k];
      }
      __syncthreads();
      for (int e = tid; e < M * CB; e += 128) {  // Pu = Gt Pd / s
        const int k = e & (CB - 1), mrow = e >> CBL;
        float acc = 0.f;
        #pragma unroll
        for (int l = 0; l < M; ++l) acc += sh.GbM[576 + mrow * 36 + l] * sh.PdL[l * 8 + k];
        sh.PuL[mrow * 8 + k] = acc * sh.sdiv[k];
      }
      __syncthreads();
    }
    for (int e = tid; e < M * CB; e += 128) projb[e] += sh.PdL[(e >> CBL) * 8 + (e & (CB - 1))];
    for (int e = tid; e < M * CB; e += 128) projb[M * CB + e] += sh.PuL[(e >> CBL) * 8 + (e & (CB - 1))];
  } else {
    // sweep 2: load perturbed projectors + stage mb
    for (int e = tid; e < M * CB; e += 128) sh.PdL[(e >> CBL) * 8 + (e & (CB - 1))] = projb[e];
    for (int e = tid; e < M * CB; e += 128) sh.PuL[(e >> CBL) * 8 + (e & (CB - 1))] = projb[M * CB + e];
    __syncthreads();
    if (!TWO) absorbT<U1, DD1, BD1, 0, 4>(Tg, poolN, sh.BIGT, sh.ATile, sh.xi, I + 1, j, tid);
    else      absorbT<U1, DD1, BD1, 2, 4>(Tg, poolN, sh.BIGT, sh.ATile, sh.xi, I + 1, j, tid);
  }
  // bn0: pool[I] = Tt*Pd
  for (int e = tid; e < UCUR * 4 * CB; e += 128) {
    const int cc = e & (CB - 1);
    const int rr = (e >> CBL) & 3;
    const int u = e >> (CBL + 2);
    const int row = u * 4 + rr;
    float acc = 0.f;
    #pragma unroll
    for (int mq = 0; mq < MQ4; ++mq) {
      const float4 cv = *(const float4*)(sh.CUR + row * 36 + mq * 4);
      acc += cv.x * sh.PdL[(mq * 4 + 0) * 8 + cc] + cv.y * sh.PdL[(mq * 4 + 1) * 8 + cc]
           + cv.z * sh.PdL[(mq * 4 + 2) * 8 + cc] + cv.w * sh.PdL[(mq * 4 + 3) * 8 + cc];
    }
    sh.pool[I * 264 + u * 33 + rr * 8 + cc] = acc;
  }
  __syncthreads();
  if (!TWO) {
    bn1T<4, DN, CB, M, (I == 4), 0>(sh, tid);
  } else {
    bn1T<2, DN, CB, M, false, 2>(sh, tid);
    absorbT<U1, DD1, BD1, 0, 2>(Tg, poolN, sh.BIGT, sh.ATile, sh.xi, I + 1, j, tid);
    bn1T<2, DN, CB, M, false, 0>(sh, tid);
  }
}

template<int JJ>
__device__ __forceinline__ void row_sweep(const float* __restrict__ Tg, const SH& sh,
                                          int j, bool svd, float* __restrict__ projRow, int tid)
{
  if (JJ == 0) {
    trunc<16, 4, 1, 0, 4, 4, 4, 0>(Tg, sh, j, svd, projRow + g_offtab[j - 1][0], tid);
    trunc<16, 8, 4, 0, 4, 4, 4, 1>(Tg, sh, j, svd, projRow + g_offtab[j - 1][1], tid);
    trunc<16, 8, 8, 1, 4, 4, 4, 2>(Tg, sh, j, svd, projRow + g_offtab[j - 1][2], tid);
    trunc<16, 8, 8, 1, 4, 4, 4, 3>(Tg, sh, j, svd, projRow + g_offtab[j - 1][3], tid);
    trunc<16, 4, 8, 2, 4, 1, 1, 4>(Tg, sh, j, svd, projRow + g_offtab[j - 1][4], tid);
  } else {
    trunc<16, 4, 1, 0, 4, 8, 4, 0>(Tg, sh, j, svd, projRow + g_offtab[j - 1][0], tid);
    trunc<32, 8, 4, 0, 8, 8, 4, 1>(Tg, sh, j, svd, projRow + g_offtab[j - 1][1], tid);
    trunc<32, 8, 8, 0, 8, 8, 4, 2>(Tg, sh, j, svd, projRow + g_offtab[j - 1][2], tid);
    trunc<32, 8, 8, 0, 8, 4, 4, 3>(Tg, sh, j, svd, projRow + g_offtab[j - 1][3], tid);
    trunc<16, 4, 8, 2, 4, 1, 1, 4>(Tg, sh, j, svd, projRow + g_offtab[j - 1][4], tid);
  }
}

// ============ kernel 2: one sample per 128-thread workgroup ============
__global__ __launch_bounds__(128) void peps_kernel(
    const float* __restrict__ Tg, const int* __restrict__ x,
    float* __restrict__ proj, float* __restrict__ out)
{
  __shared__ float pool[6 * 264];
  __shared__ float CUR[1152];
  __shared__ float BIGT[2304];
  __shared__ float GbM[1152];
  __shared__ float TM[1152];
  __shared__ float GM[1152];
  __shared__ float ATile[256];
  __shared__ float PdL[256], PuL[256];
  __shared__ float nrmI[32];
  __shared__ float sinvv[8], sdiv[8];
  __shared__ int isel[8];
  __shared__ int xi[36];
  __shared__ float vvec[36], vvec2[36];
  const SH sh{pool, CUR, BIGT, GbM, TM, GM, ATile, PdL, PuL, nrmI, sinvv, sdiv, isel, xi};

  const int s = blockIdx.x;
  const int tid = threadIdx.x;
  if (tid < 36) xi[tid] = x[s * 36 + tid];
  __syncthreads();
  float* projRow = proj + (size_t)s * 6400;

  for (int sweep = 0; sweep < 2; ++sweep) {
    const bool svd = (sweep == 0);
    // init boundary MPS from row j=0
    for (int i2 = 0; i2 < 6; ++i2) {
      const int ad = (i2 == 0) ? 1 : 4, bd = (i2 == 5) ? 1 : 4;
      const int bdlog = (bd == 4) ? 2 : 0;
      const int ph = xi[i2 * 6];
      const float* tb = Tg + (size_t)(i2 * 6) * 512;
      const int nel = ad * 4 * bd;
      for (int e = tid; e < nel; e += 128) {
        const int b = e & (bd - 1);
        const int rr = (e >> bdlog) & 3;
        const int a = e >> (bdlog + 2);
        pool[i2 * 264 + a * 33 + rr * 8 + b] = tb[(a * 64 + rr * 16 + b * 4) * 2 + ph];
      }
    }
    __syncthreads();

    for (int j = 1; j <= 4; ++j) {
      // CUR init: absorb site (0,j) into 4x16
      {
        const int ph = xi[j];
        const float* tb = Tg + (size_t)j * 512;
        for (int e = tid; e < 256; e += 128) ATile[e] = tb[e * 2 + ph];
        __syncthreads();
        if (tid < 64) {
          const int db = tid & 15;
          const int rr = tid >> 4;
          const int d_ = db >> 2, b = db & 3;
          const float* op = pool + d_;
          const float4 av = *(const float4*)(ATile + rr * 16 + b * 4);
          CUR[rr * 36 + db] = op[0] * av.x + op[8] * av.y + op[16] * av.z + op[24] * av.w;
        }
        __syncthreads();
      }
      if (j == 1) row_sweep<0>(Tg, sh, j, svd, projRow, tid);
      else        row_sweep<1>(Tg, sh, j, svd, projRow, tid);
    }

    if (sweep == 1) {
      // finalize: scalar = prod_i C_i
      if (tid == 0) vvec[0] = 1.0f;
      __syncthreads();
      for (int i = 0; i < 6; ++i) {
        const int ad = (i == 0) ? 1 : 4, bd = (i == 5) ? 1 : 4;
        const int adlog = (ad == 4) ? 2 : 0, bdlog = (bd == 4) ? 2 : 0;
        const int rows = g_ufin[i] * ad, cols = g_dfin[i] * bd;
        const int clog = 31 - __clz(cols);
        const int ph = xi[i * 6 + 5];
        const float* tb = Tg + (size_t)(i * 6 + 5) * 512;
        for (int e = tid; e < 256; e += 128) ATile[e] = tb[e * 2 + ph];
        __syncthreads();
        for (int e = tid; e < rows * cols; e += 128) {
          const int col = e & (cols - 1);
          const int ua = e >> clog;
          const int u = ua >> adlog, a = ua & (ad - 1);
          const int d_ = col >> bdlog, b = col & (bd - 1);
          const float* fb = pool + i * 264 + u * 33 + d_;
          const float4 av = *(const float4*)(ATile + a * 64 + b * 4);  // R = 0 slice
          GM[ua * 36 + col] = fb[0] * av.x + fb[8] * av.y + fb[16] * av.z + fb[24] * av.w;
        }
        __syncthreads();
        if (tid < cols) {
          float acc = 0.f;
          for (int r_ = 0; r_ < rows; ++r_) acc += vvec[r_] * GM[r_ * 36 + tid];
          vvec2[tid] = acc;
        }
        __syncthreads();
        if (tid < cols) vvec[tid] = vvec2[tid];
        __syncthreads();
      }
      if (tid == 0) out[s] = vvec[0];
    }
  }
}

extern "C" void kernel_launch(void* const* d_in, const int* in_sizes, int n_in,
                              void* d_out, int out_size, void* d_ws, size_t ws_size,
                              hipStream_t stream) {
  const float* Tg = (const float*)d_in[0];
  const float* W1 = (const float*)d_in[1];
  const float* b1 = (const float*)d_in[2];
  const float* W2 = (const float*)d_in[3];
  const float* b2 = (const float*)d_in[4];
  const int*   x  = (const int*)d_in[5];
  float* out = (float*)d_out;
  float* proj = (float*)d_ws;   // 1024*6400 floats: ETA*mlp then += projectors
  (void)in_sizes; (void)n_in; (void)out_size; (void)ws_size;

  mlp_kernel<<<dim3(128), dim3(256), 0, stream>>>(W1, b1, W2, b2, x, proj);
  peps_kernel<<<dim3(1024), dim3(128), 0, stream>>>(Tg, x, proj, out);
}

// Round 5
// 4908.885 us; speedup vs baseline: 1.3516x; 1.3516x over previous
//
#include <hip/hip_runtime.h>

// wave-local LDS ordering fence (redundant-per-wave regions; LDS pipe is in-order per wave)
#define WSYNC asm volatile("s_waitcnt lgkmcnt(0)" ::: "memory")

// ---------------- static schedule tables ----------------
__device__ const int g_uprev[2][6] = {{1,4,4,4,4,4},{1,4,8,8,8,4}};
__device__ const int g_dprev[2][6] = {{4,4,4,4,4,1},{4,8,8,8,4,1}};
__device__ const int g_mtab[2][5]  = {{16,16,16,16,16},{16,32,32,32,16}};
__device__ const int g_cbtab[5]    = {4,8,8,8,4};
__device__ const int g_ucurtab[5]  = {1,4,8,8,8};
__device__ const int g_dntab[2][5] = {{16,16,16,16,1},{32,32,32,16,1}};
__device__ const int g_path[2][5]  = {{0,0,1,1,2},{0,0,0,0,2}};  // 0=p-side,1=m-side(chol),2=q-side
__device__ const int g_offtab[4][5]= {{0,128,384,640,896},
                                      {1024,1152,1664,2176,2688},
                                      {2816,2944,3456,3968,4480},
                                      {4608,4736,5248,5760,6272}};
__device__ const int g_ufin[6] = {1,4,8,8,8,4};
__device__ const int g_dfin[6] = {4,8,8,8,4,1};

// ============ kernel 1: proj[s][k] = ETA*mlp(x_s)[k] ============
__global__ __launch_bounds__(256) void mlp_kernel(
    const float* __restrict__ W1, const float* __restrict__ b1,
    const float* __restrict__ W2, const float* __restrict__ b2,
    const int* __restrict__ x, float* __restrict__ proj)
{
  __shared__ float hbuf[8][64];
  const int tid = threadIdx.x;
  const int s0 = blockIdx.x << 3;
  for (int e = tid; e < 512; e += 256) {
    const int sl = e >> 6, hh = e & 63;
    const int* xr = x + (s0 + sl) * 36;
    const float* wr = W1 + hh * 36;
    float acc = b1[hh];
    #pragma unroll
    for (int t = 0; t < 36; ++t) acc += wr[t] * (float)xr[t];
    hbuf[sl][hh] = fmaxf(acc, 0.0f);
  }
  __syncthreads();
  for (int k = tid; k < 6400; k += 256) {
    const float4* wr = (const float4*)(W2 + (size_t)k * 64);
    float acc[8];
    #pragma unroll
    for (int s2 = 0; s2 < 8; ++s2) acc[s2] = 0.0f;
    #pragma unroll
    for (int c = 0; c < 16; ++c) {
      const float4 w = wr[c];
      #pragma unroll
      for (int s2 = 0; s2 < 8; ++s2) {
        const float4 hv = ((const float4*)hbuf[s2])[c];
        acc[s2] += w.x * hv.x + w.y * hv.y + w.z * hv.z + w.w * hv.w;
      }
    }
    const float bb = b2[k];
    #pragma unroll
    for (int s2 = 0; s2 < 8; ++s2)
      proj[(size_t)(s0 + s2) * 6400 + k] = 0.001f * (acc[s2] + bb);
  }
}

// ---------------- reduce-scatter: after run, lane holds sum for index (lane & (P-1)) ----------------
template<int CL>
struct RS {
  static __device__ __forceinline__ void run(float* a, int lane) {
    constexpr int M = CL / 2;
    float rx[CL];
    #pragma unroll
    for (int t = 0; t < CL; ++t) rx[t] = __shfl_xor(a[t], M);
    const bool up = (lane & M) != 0;
    #pragma unroll
    for (int t = 0; t < M; ++t)
      a[t] = up ? (a[t + M] + rx[t + M]) : (a[t] + rx[t]);
    RS<M>::run(a, lane);
  }
};
template<> struct RS<1> { static __device__ __forceinline__ void run(float*, int) {} };

// ============ one-sided (Hestenes) register Jacobi — executed redundantly by BOTH waves ============
// Gin: NxN sym PSD (stride 36). V gets UNnormalized W columns (w_k = lambda_k u_k);
// lamA[k] = lambda_k; nrmI[k] = 1/||w_k||. Both waves write identical values; zero barriers.
template<int N, int MAXSW>
__device__ __forceinline__ void jacobiR(const float* __restrict__ Gin, float* __restrict__ V,
                                        float* __restrict__ lamA, float* __restrict__ nrmI, int lane)
{
  constexpr int P = N / 2;
  float w[N];
  #pragma unroll
  for (int c = 0; c < N; ++c) w[c] = 0.0f;
  float cn = 0.0f;
  if (lane < N) {
    #pragma unroll
    for (int c = 0; c < N; ++c) w[c] = Gin[lane * 36 + c];
    #pragma unroll
    for (int r = 0; r < N; ++r) { const float g = Gin[r * 36 + lane]; cn += g * g; }
  }
  const int myk = lane & (P - 1);
  float np_ = __shfl(cn, 2 * myk);
  float nq_ = __shfl(cn, 2 * myk + 1);
  for (int sw = 0; sw < MAXSW; ++sw) {
    bool conv = true;
    for (int rd = 0; rd < N - 1; ++rd) {
      float a0[P];
      #pragma unroll
      for (int k = 0; k < P; ++k) a0[k] = w[2 * k] * w[2 * k + 1];
      #pragma unroll
      for (int t = 0; t < P; ++t) a0[t] += __shfl_xor(a0[t], P);
      RS<P>::run(a0, lane);
      const float apq = a0[0];
      float c_ = 1.0f, s_ = 0.0f;
      if (fabsf(apq) > 1e-36f + 1e-12f * (np_ + nq_)) {
        const float tau = (nq_ - np_) / (2.0f * apq);
        const float t = copysignf(1.0f, tau) / (fabsf(tau) + sqrtf(1.0f + tau * tau));
        c_ = 1.0f / sqrtf(1.0f + t * t);
        s_ = t * c_;
      }
      conv = conv && (fabsf(apq) <= 1e-6f * sqrtf(np_ * nq_) + 1e-30f);
      // norm update + seat-shift redistribution (registers + 3 shfls, no LDS)
      const float cs2 = 2.0f * c_ * s_ * apq;
      const float npn = c_ * c_ * np_ + s_ * s_ * nq_ - cs2;
      const float nqn = s_ * s_ * np_ + c_ * c_ * nq_ + cs2;
      const float shA = __shfl(npn, (myk > 0) ? (myk - 1) : 0);
      const float shB = __shfl(nqn, 0);
      const float shC = __shfl(nqn, (myk < P - 1) ? (myk + 1) : 0);
      np_ = (myk == 0) ? npn : ((myk == 1) ? shB : shA);
      nq_ = (myk == P - 1) ? npn : shC;
      // rotate own row + static tournament seat permutation
      float nw[N];
      #pragma unroll
      for (int k = 0; k < P; ++k) {
        const float ck = __shfl(c_, k);
        const float sk = __shfl(s_, k);
        const float a = w[2 * k], b = w[2 * k + 1];
        const float wa = ck * a - sk * b;
        const float wb = sk * a + ck * b;
        const int t0 = (k == 0) ? 0 : ((k == P - 1) ? (2 * P - 1) : (2 * k + 2));
        const int t1 = (k == 0) ? 2 : (2 * k - 1);
        nw[t0] = wa; nw[t1] = wb;
      }
      #pragma unroll
      for (int c2 = 0; c2 < N; ++c2) w[c2] = nw[c2];
    }
    if (__all(conv)) break;
  }
  if (lane < N) {
    #pragma unroll
    for (int c = 0; c < N; ++c) V[lane * 36 + c] = w[c];
  }
  WSYNC;
  if (lane < N) {
    float acc = 0.0f;
    #pragma unroll
    for (int r = 0; r < N; ++r) { const float v = V[r * 36 + lane]; acc += v * v; }
    lamA[lane] = sqrtf(acc);                                  // lambda = sigma^2
    nrmI[lane] = (acc > 1e-38f) ? (1.0f / sqrtf(acc)) : 0.0f; // 1/||w||
  }
  WSYNC;
}

// G(+)= A^T A over 'nrows' stride-36 rows of A, mcols in {16,32}; float4 on column quads (128T)
__device__ __forceinline__ void gram_cols(float* __restrict__ G, const float* __restrict__ A,
                                          int nrows, int mcols, bool init, int tid)
{
  const int q4 = mcols >> 2;
  const int q4log = (mcols == 32) ? 3 : 2;
  const int nel = mcols * q4;
  const float4* A4 = (const float4*)A;
  float4* G4 = (float4*)G;
  for (int e = tid; e < nel; e += 128) {
    const int c2q = e & (q4 - 1);
    const int c1 = e >> q4log;
    float ax = 0.f, ay = 0.f, az = 0.f, aw = 0.f;
    for (int r = 0; r < nrows; ++r) {
      const float a1 = A[r * 36 + c1];
      const float4 a2 = A4[r * 9 + c2q];
      ax += a1 * a2.x; ay += a1 * a2.y; az += a1 * a2.z; aw += a1 * a2.w;
    }
    float4* gp = G4 + c1 * 9 + c2q;
    if (init) { float4 o; o.x = ax; o.y = ay; o.z = az; o.w = aw; *gp = o; }
    else { float4 o = *gp; o.x += ax; o.y += ay; o.z += az; o.w += aw; *gp = o; }
  }
  __syncthreads();
}

// absorb column i1 of row j into BIGT[(rr-rr0)*dbw+db][ua] (stride 36), rr in [rr0,rr1)  (128T)
__device__ __forceinline__ void absorb_T(const float* __restrict__ Tg, const float* __restrict__ poolS,
    float* __restrict__ BIGT, float* __restrict__ ATile, const int* __restrict__ xi,
    int i1, int j, int U, int Dd, int rr0, int rr1, int tid)
{
  const int bd = (i1 == 5) ? 1 : 4;
  const int dbw = Dd * bd;
  const int mt_ = U * 4;
  const int ph = xi[i1 * 6 + j];
  const float* tb = Tg + (size_t)(i1 * 6 + j) * 512;
  for (int e = tid; e < 256; e += 128) ATile[e] = tb[e * 2 + ph];
  __syncthreads();
  const int mlog = (mt_ == 32) ? 5 : 4;
  const int dblog = 31 - __clz(dbw);
  const int bdlog = (bd == 4) ? 2 : 0;
  const int nel = mt_ * dbw * (rr1 - rr0);
  for (int e = tid; e < nel; e += 128) {
    const int ua = e & (mt_ - 1);
    const int db = (e >> mlog) & (dbw - 1);
    const int rr = rr0 + (e >> (mlog + dblog));
    const int u = ua >> 2, a = ua & 3;
    const int d_ = db >> bdlog, b = db & (bd - 1);
    const float* op = poolS + u * 33 + d_;
    const float4 av = *(const float4*)(ATile + a * 64 + rr * 16 + b * 4);
    BIGT[((rr - rr0) * dbw + db) * 36 + ua] = op[0] * av.x + op[8] * av.y + op[16] * av.z + op[24] * av.w;
  }
  __syncthreads();
}

// ============ kernel 2: one sample per 128-thread workgroup ============
__global__ __launch_bounds__(128, 2) void peps_kernel(
    const float* __restrict__ Tg, const int* __restrict__ x,
    float* __restrict__ proj, float* __restrict__ out)
{
  __shared__ float pool[6 * 264];   // [i][u<=8 stride33][x=4 stride8][d<=8]
  __shared__ float CUR[1152];       // mt: rows (u*4+rr)<=32, stride 36
  __shared__ float BIGT[2304];      // mb^T half: rows (rr*dbw+db)<=64 stride 36
  __shared__ float GbM[1152];       // Gb (or Gt); m-path: Gb@0, Gt@576
  __shared__ float TM[1152];        // T / R2@0+V@576 / eigvecs V
  __shared__ float GM[1152];        // G / H
  __shared__ float ATile[256];
  __shared__ float PdL[256], PuL[256];  // [mrow][8]
  __shared__ float lamA[32], nrmI[32];
  __shared__ int isel[8];
  __shared__ float sinvv[8], sdiv[8];
  __shared__ int xi[36];
  __shared__ float vvec[36], vvec2[36];

  const int s = blockIdx.x;
  const int tid = threadIdx.x;
  const int lane = tid & 63;
  if (tid < 36) xi[tid] = x[s * 36 + tid];
  __syncthreads();

  for (int sweep = 0; sweep < 2; ++sweep) {
    // --- init boundary MPS from row j=0 ---
    for (int i2 = 0; i2 < 6; ++i2) {
      const int ad = (i2 == 0) ? 1 : 4, bd = (i2 == 5) ? 1 : 4;
      const int bdlog = (bd == 4) ? 2 : 0;
      const int ph = xi[i2 * 6];
      const float* tb = Tg + (size_t)(i2 * 6) * 512;
      const int nel = ad * 4 * bd;
      for (int e = tid; e < nel; e += 128) {
        const int b = e & (bd - 1);
        const int rr = (e >> bdlog) & 3;
        const int a = e >> (bdlog + 2);
        pool[i2 * 264 + a * 33 + rr * 8 + b] = tb[(a * 64 + rr * 16 + b * 4) * 2 + ph];
      }
    }
    __syncthreads();

    for (int j = 1; j <= 4; ++j) {
      const int jj = (j > 1) ? 1 : 0;
      // absorb column 0 into CUR (4 rows x 16 cols)
      {
        const int ph = xi[j];
        const float* tb = Tg + (size_t)j * 512;
        for (int e = tid; e < 256; e += 128) ATile[e] = tb[e * 2 + ph];
        __syncthreads();
        if (tid < 64) {
          const int db = tid & 15;
          const int rr = tid >> 4;
          const int d_ = db >> 2, b = db & 3;
          const float* op = pool + d_;
          const float4 av = *(const float4*)(ATile + rr * 16 + b * 4);
          CUR[rr * 36 + db] = op[0] * av.x + op[8] * av.y + op[16] * av.z + op[24] * av.w;
        }
        __syncthreads();
      }

      for (int i = 0; i < 5; ++i) {
        const int m = g_mtab[jj][i], cb = g_cbtab[i], ucur = g_ucurtab[i], dn = g_dntab[jj][i];
        const int p = ucur * 4, path = g_path[jj][i];
        const int U1 = g_uprev[jj][i + 1], Dd1 = g_dprev[jj][i + 1];
        const bool two = (dn == 32);
        const int cblog = (cb == 8) ? 3 : 2;
        const int mq4 = m >> 2;
        float* projb = proj + (size_t)s * 6400 + g_offtab[j - 1][i];

        if (sweep == 0) {
          if (path == 2) {
            // ---- q-side (i=4): G = mb^T Gt mb (4x4) ----
            absorb_T(Tg, pool + (i + 1) * 264, BIGT, ATile, xi, i + 1, j, U1, Dd1, 0, 4, tid);
            gram_cols(GbM, CUR, p, m, true, tid);   // Gt (16x16)
            for (int e = tid; e < 64; e += 128) {   // T1 = Gt*mb (16x4) -> TM
              const int r = e & 3, k = e >> 2;
              float acc = 0.f;
              const float4* G4 = (const float4*)GbM;
              const float4* B4 = (const float4*)BIGT;
              for (int lq = 0; lq < 4; ++lq) {
                const float4 g = G4[k * 9 + lq], b = B4[r * 9 + lq];
                acc += g.x * b.x + g.y * b.y + g.z * b.z + g.w * b.w;
              }
              TM[k * 36 + r] = acc;
            }
            __syncthreads();
            for (int e = tid; e < 16; e += 128) {   // G = mb^T * T1 (4x4)
              const int c = e & 3, r = e >> 2;
              float acc = 0.f;
              for (int k = 0; k < 16; ++k) acc += BIGT[r * 36 + k] * TM[k * 36 + c];
              GM[r * 36 + c] = acc;
            }
            __syncthreads();
            jacobiR<4, 6>(GM, TM + 576, lamA, nrmI, lane);
          } else if (path == 0) {
            // ---- p-side: G = mt Gb mt^T (p x p) ----
            if (!two) {
              absorb_T(Tg, pool + (i + 1) * 264, BIGT, ATile, xi, i + 1, j, U1, Dd1, 0, 4, tid);
              gram_cols(GbM, BIGT, 4 * dn, m, true, tid);
            } else {
              absorb_T(Tg, pool + (i + 1) * 264, BIGT, ATile, xi, i + 1, j, U1, Dd1, 0, 2, tid);
              gram_cols(GbM, BIGT, 2 * dn, m, true, tid);
              absorb_T(Tg, pool + (i + 1) * 264, BIGT, ATile, xi, i + 1, j, U1, Dd1, 2, 4, tid);
              gram_cols(GbM, BIGT, 2 * dn, m, false, tid);
            }
            const int q4log = (m == 32) ? 3 : 2;
            for (int e = tid; e < p * mq4; e += 128) {  // T = mt*Gb (p x m)
              const int lq = e & (mq4 - 1), pr = e >> q4log;
              float ax = 0.f, ay = 0.f, az = 0.f, aw = 0.f;
              const float4* G4 = (const float4*)GbM;
              for (int k = 0; k < m; ++k) {
                const float a1 = CUR[pr * 36 + k];
                const float4 g = G4[k * 9 + lq];
                ax += a1 * g.x; ay += a1 * g.y; az += a1 * g.z; aw += a1 * g.w;
              }
              float4 o; o.x = ax; o.y = ay; o.z = az; o.w = aw;
              ((float4*)TM)[pr * 9 + lq] = o;
            }
            __syncthreads();
            const int plog = (p == 32) ? 5 : ((p == 16) ? 4 : 2);
            for (int e = tid; e < p * p; e += 128) {    // G = T*mt^T (p x p)
              const int pc = e & (p - 1), pr = e >> plog;
              float acc = 0.f;
              const float4* T4 = (const float4*)TM;
              const float4* C4 = (const float4*)CUR;
              for (int lq = 0; lq < mq4; ++lq) {
                const float4 t = T4[pr * 9 + lq], c = C4[pc * 9 + lq];
                acc += t.x * c.x + t.y * c.y + t.z * c.z + t.w * c.w;
              }
              GM[pr * 36 + pc] = acc;
            }
            __syncthreads();
            if (p == 4)       jacobiR<4, 6>(GM, TM, lamA, nrmI, lane);
            else if (p == 16) jacobiR<16, 9>(GM, TM, lamA, nrmI, lane);
            else              jacobiR<32, 10>(GM, TM, lamA, nrmI, lane);
          } else {
            // ---- m-side (j=1, i=2,3): Gt, Gb, chol(Gb)->R2, H = R2 Gt R2^T (16x16) ----
            absorb_T(Tg, pool + (i + 1) * 264, BIGT, ATile, xi, i + 1, j, U1, Dd1, 0, 4, tid);
            gram_cols(GbM + 576, CUR, p, m, true, tid);     // Gt
            gram_cols(GbM, BIGT, 4 * dn, m, true, tid);     // Gb
            float thr;
            {  // barrier-free per-wave max-diag broadcast
              float v_ = (lane < 16) ? GbM[lane * 37] : -3.0e38f;
              #pragma unroll
              for (int mk = 32; mk; mk >>= 1) v_ = fmaxf(v_, __shfl_xor(v_, mk));
              thr = 1e-10f * v_ + 1e-35f;
            }
            for (int k = 0; k < 16; ++k) {
              const float dk = GbM[k * 37];
              const float rs = (dk > thr) ? (1.0f / sqrtf(dk)) : 0.0f;
              if (tid < 16) TM[k * 36 + tid] = GbM[k * 36 + tid] * rs;
              __syncthreads();
              const int rows = 15 - k;
              for (int e = tid; e < rows * 16; e += 128) {
                const int ii = k + 1 + (e >> 4), jc = e & 15;
                GbM[ii * 36 + jc] -= TM[k * 36 + ii] * TM[k * 36 + jc];
              }
              __syncthreads();
            }
            for (int e = tid; e < 64; e += 128) {   // T1 = R2*Gt -> TM+576
              const int jq = e & 3, k = e >> 2;
              float ax = 0.f, ay = 0.f, az = 0.f, aw = 0.f;
              const float4* Gt4 = (const float4*)(GbM + 576);
              for (int l = 0; l < 16; ++l) {
                const float r2 = TM[k * 36 + l];
                const float4 g = Gt4[l * 9 + jq];
                ax += r2 * g.x; ay += r2 * g.y; az += r2 * g.z; aw += r2 * g.w;
              }
              float4 o; o.x = ax; o.y = ay; o.z = az; o.w = aw;
              ((float4*)(TM + 576))[k * 9 + jq] = o;
            }
            __syncthreads();
            for (int e = tid; e < 256; e += 128) {  // H = T1*R2^T -> GM
              const int k2 = e & 15, k = e >> 4;
              float acc = 0.f;
              const float4* T14 = (const float4*)(TM + 576);
              const float4* R24 = (const float4*)TM;
              for (int lq = 0; lq < 4; ++lq) {
                const float4 t = T14[k * 9 + lq], r = R24[k2 * 9 + lq];
                acc += t.x * r.x + t.y * r.y + t.z * r.z + t.w * r.w;
              }
              GM[k * 36 + k2] = acc;
            }
            __syncthreads();
            jacobiR<16, 9>(GM, TM + 576, lamA, nrmI, lane);
          }

          // ---- top-cb selection + scales (redundant per-wave, barrier-free) ----
          const int N_ = (path == 2) ? 4 : ((path == 1) ? 16 : p);
          {
            float v_ = (lane < N_) ? lamA[lane] : -3.0e38f;
            int ix = lane;
            for (int t = 0; t < cb; ++t) {
              float bv = v_; int bi = ix;
              for (int mk = 32; mk; mk >>= 1) {
                const float ov = __shfl_xor(bv, mk);
                const int oi = __shfl_xor(bi, mk);
                if (ov > bv || (ov == bv && oi < bi)) { bv = ov; bi = oi; }
              }
              if (lane == 0) isel[t] = bi;
              if (ix == bi) v_ = -3.0e38f;
            }
            WSYNC;
            if (lane < cb) {
              const int a = isel[lane];
              const float lam = lamA[a];
              const float s_ = sqrtf(fmaxf(lam, 0.0f));
              sinvv[lane] = (1.0f / sqrtf(s_ + 1e-12f)) * nrmI[a];
              sdiv[lane] = 1.0f / fmaxf(s_, 1e-25f);
            }
            WSYNC;
          }

          // ---- projectors ----
          if (path == 0) {
            // Pu = mt^T W sinv' ; Pd = Gb Pu / s   (W cols in TM)
            for (int e = tid; e < m * cb; e += 128) {
              const int k = e & (cb - 1), mrow = e >> cblog;
              const int a = isel[k];
              float acc = 0.f;
              for (int pr = 0; pr < p; ++pr) acc += CUR[pr * 36 + mrow] * TM[pr * 36 + a];
              PuL[mrow * 8 + k] = acc * sinvv[k];
            }
            __syncthreads();
            for (int e = tid; e < m * cb; e += 128) {
              const int k = e & (cb - 1), mrow = e >> cblog;
              float acc = 0.f;
              for (int l = 0; l < m; ++l) acc += GbM[mrow * 36 + l] * PuL[l * 8 + k];
              PdL[mrow * 8 + k] = acc * sdiv[k];
            }
            __syncthreads();
          } else if (path == 2) {
            // Pd = mb W sinv' ; Pu = Gt Pd / s   (W in TM+576, Gt in GbM)
            for (int e = tid; e < m * cb; e += 128) {
              const int k = e & (cb - 1), mrow = e >> cblog;
              const int a = isel[k];
              float acc = 0.f;
              for (int r = 0; r < 4; ++r) acc += BIGT[r * 36 + mrow] * TM[576 + r * 36 + a];
              PdL[mrow * 8 + k] = acc * sinvv[k];
            }
            __syncthreads();
            for (int e = tid; e < m * cb; e += 128) {
              const int k = e & (cb - 1), mrow = e >> cblog;
              float acc = 0.f;
              for (int l = 0; l < m; ++l) acc += GbM[mrow * 36 + l] * PdL[l * 8 + k];
              PuL[mrow * 8 + k] = acc * sdiv[k];
            }
            __syncthreads();
          } else {
            // Pd = R2^T W sinv' ; Pu = Gt Pd / s  (R2 in TM[0:576], W in TM+576, Gt in GbM+576)
            for (int e = tid; e < m * cb; e += 128) {
              const int k = e & (cb - 1), mrow = e >> cblog;
              const int a = isel[k];
              float acc = 0.f;
              for (int t = 0; t < 16; ++t) acc += TM[t * 36 + mrow] * TM[576 + t * 36 + a];
              PdL[mrow * 8 + k] = acc * sinvv[k];
            }
            __syncthreads();
            for (int e = tid; e < m * cb; e += 128) {
              const int k = e & (cb - 1), mrow = e >> cblog;
              float acc = 0.f;
              for (int l = 0; l < m; ++l) acc += GbM[576 + mrow * 36 + l] * PdL[l * 8 + k];
              PuL[mrow * 8 + k] = acc * sdiv[k];
            }
            __syncthreads();
          }
          // store perturbed projectors (ws slot preloaded with ETA*mlp)
          for (int e = tid; e < m * cb; e += 128)
            projb[e] += PdL[(e >> cblog) * 8 + (e & (cb - 1))];
          for (int e = tid; e < m * cb; e += 128)
            projb[m * cb + e] += PuL[(e >> cblog) * 8 + (e & (cb - 1))];
        } else {
          // ---- sweep 2: load perturbed projectors + stage mb ----
          for (int e = tid; e < m * cb; e += 128)
            PdL[(e >> cblog) * 8 + (e & (cb - 1))] = projb[e];
          for (int e = tid; e < m * cb; e += 128)
            PuL[(e >> cblog) * 8 + (e & (cb - 1))] = projb[m * cb + e];
          __syncthreads();
          if (!two) absorb_T(Tg, pool + (i + 1) * 264, BIGT, ATile, xi, i + 1, j, U1, Dd1, 0, 4, tid);
          else      absorb_T(Tg, pool + (i + 1) * 264, BIGT, ATile, xi, i + 1, j, U1, Dd1, 2, 4, tid);
        }

        // ---- common: Bn[i] = Tt*Pd -> pool[i]; Bn[i+1] = Pu applied to mb -> CUR (or pool[5]) ----
        {
          const int nel = ucur * 4 * cb;
          const float4* C4 = (const float4*)CUR;
          for (int e = tid; e < nel; e += 128) {
            const int cc = e & (cb - 1);
            const int rr = (e >> cblog) & 3;
            const int u = e >> (cblog + 2);
            const int row = u * 4 + rr;
            float acc = 0.f;
            for (int mq = 0; mq < mq4; ++mq) {
              const float4 cv = C4[row * 9 + mq];
              acc += cv.x * PdL[(mq * 4 + 0) * 8 + cc] + cv.y * PdL[(mq * 4 + 1) * 8 + cc]
                   + cv.z * PdL[(mq * 4 + 2) * 8 + cc] + cv.w * PdL[(mq * 4 + 3) * 8 + cc];
            }
            pool[i * 264 + u * 33 + rr * 8 + cc] = acc;
          }
          __syncthreads();

          const int dnlog = 31 - __clz(dn);
          auto bn1 = [&](int rr0, int nloc) {
            const int ne2 = cb * nloc * dn;
            const float4* B4 = (const float4*)BIGT;
            for (int e = tid; e < ne2; e += 128) {
              const int dd = e & (dn - 1);
              const int t = e >> dnlog;
              const int rrL = t & (nloc - 1);
              const int cc = t >> ((nloc == 4) ? 2 : 1);
              const int row = rrL * dn + dd;
              float acc = 0.f;
              for (int mq = 0; mq < mq4; ++mq) {
                const float4 bv = B4[row * 9 + mq];
                acc += bv.x * PuL[(mq * 4 + 0) * 8 + cc] + bv.y * PuL[(mq * 4 + 1) * 8 + cc]
                     + bv.z * PuL[(mq * 4 + 2) * 8 + cc] + bv.w * PuL[(mq * 4 + 3) * 8 + cc];
              }
              if (i < 4) CUR[(cc * 4 + rr0 + rrL) * 36 + dd] = acc;
              else       pool[5 * 264 + cc * 33 + (rr0 + rrL) * 8] = acc;
            }
            __syncthreads();
          };
          if (!two) {
            bn1(0, 4);
          } else {
            bn1(2, 2);
            absorb_T(Tg, pool + (i + 1) * 264, BIGT, ATile, xi, i + 1, j, U1, Dd1, 0, 2, tid);
            bn1(0, 2);
          }
        }
      }
    }

    if (sweep == 1) {
      // ---- finalize: scalar = prod_i C_i ----
      if (tid == 0) vvec[0] = 1.0f;
      __syncthreads();
      for (int i = 0; i < 6; ++i) {
        const int ad = (i == 0) ? 1 : 4, bd = (i == 5) ? 1 : 4;
        const int adlog = (ad == 4) ? 2 : 0, bdlog = (bd == 4) ? 2 : 0;
        const int rows = g_ufin[i] * ad, cols = g_dfin[i] * bd;
        const int clog = 31 - __clz(cols);
        const int ph = xi[i * 6 + 5];
        const float* tb = Tg + (size_t)(i * 6 + 5) * 512;
        for (int e = tid; e < 256; e += 128) ATile[e] = tb[e * 2 + ph];
        __syncthreads();
        for (int e = tid; e < rows * cols; e += 128) {
          const int col = e & (cols - 1);
          const int ua = e >> clog;
          const int u = ua >> adlog, a = ua & (ad - 1);
          const int d_ = col >> bdlog, b = col & (bd - 1);
          const float* fb = pool + i * 264 + u * 33 + d_;
          const float4 av = *(const float4*)(ATile + a * 64 + b * 4);  // R = 0 slice
          GM[ua * 36 + col] = fb[0] * av.x + fb[8] * av.y + fb[16] * av.z + fb[24] * av.w;
        }
        __syncthreads();
        if (tid < cols) {
          float acc = 0.f;
          for (int r_ = 0; r_ < rows; ++r_) acc += vvec[r_] * GM[r_ * 36 + tid];
          vvec2[tid] = acc;
        }
        __syncthreads();
        if (tid < cols) vvec[tid] = vvec2[tid];
        __syncthreads();
      }
      if (tid == 0) out[s] = vvec[0];
    }
  }
}

extern "C" void kernel_launch(void* const* d_in, const int* in_sizes, int n_in,
                              void* d_out, int out_size, void* d_ws, size_t ws_size,
                              hipStream_t stream) {
  const float* Tg = (const float*)d_in[0];
  const float* W1 = (const float*)d_in[1];
  const float* b1 = (const float*)d_in[2];
  const float* W2 = (const float*)d_in[3];
  const float* b2 = (const float*)d_in[4];
  const int*   x  = (const int*)d_in[5];
  float* out = (float*)d_out;
  float* proj = (float*)d_ws;   // 1024*6400 floats: ETA*mlp then += projectors
  (void)in_sizes; (void)n_in; (void)out_size; (void)ws_size;

  mlp_kernel<<<dim3(128), dim3(256), 0, stream>>>(W1, b1, W2, b2, x, proj);
  peps_kernel<<<dim3(1024), dim3(128), 0, stream>>>(Tg, x, proj, out);
}

// Round 6
// 2822.447 us; speedup vs baseline: 2.3507x; 1.7392x over previous
//
#include <hip/hip_runtime.h>

// ---------------- static schedule tables ----------------
__device__ const int g_uprev[2][6] = {{1,4,4,4,4,4},{1,4,8,8,8,4}};
__device__ const int g_dprev[2][6] = {{4,4,4,4,4,1},{4,8,8,8,4,1}};
__device__ const int g_mtab[2][5]  = {{16,16,16,16,16},{16,32,32,32,16}};
__device__ const int g_cbtab[5]    = {4,8,8,8,4};
__device__ const int g_ucurtab[5]  = {1,4,8,8,8};
__device__ const int g_dntab[2][5] = {{16,16,16,16,1},{32,32,32,16,1}};
__device__ const int g_path[2][5]  = {{0,0,1,1,2},{0,0,0,0,2}};  // 0=p-side,1=m-side(chol),2=q-side
__device__ const int g_offtab[4][5]= {{0,128,384,640,896},
                                      {1024,1152,1664,2176,2688},
                                      {2816,2944,3456,3968,4480},
                                      {4608,4736,5248,5760,6272}};
__device__ const int g_ufin[6] = {1,4,8,8,8,4};
__device__ const int g_dfin[6] = {4,8,8,8,4,1};

// ============ kernel 1: proj[s][k] = ETA*mlp(x_s)[k] ============
__global__ __launch_bounds__(256) void mlp_kernel(
    const float* __restrict__ W1, const float* __restrict__ b1,
    const float* __restrict__ W2, const float* __restrict__ b2,
    const int* __restrict__ x, float* __restrict__ proj)
{
  __shared__ float hbuf[8][64];
  const int tid = threadIdx.x;
  const int s0 = blockIdx.x << 3;
  for (int e = tid; e < 512; e += 256) {
    const int sl = e >> 6, hh = e & 63;
    const int* xr = x + (s0 + sl) * 36;
    const float* wr = W1 + hh * 36;
    float acc = b1[hh];
    #pragma unroll
    for (int t = 0; t < 36; ++t) acc += wr[t] * (float)xr[t];
    hbuf[sl][hh] = fmaxf(acc, 0.0f);
  }
  __syncthreads();
  for (int k = tid; k < 6400; k += 256) {
    const float4* wr = (const float4*)(W2 + (size_t)k * 64);
    float acc[8];
    #pragma unroll
    for (int s2 = 0; s2 < 8; ++s2) acc[s2] = 0.0f;
    #pragma unroll
    for (int c = 0; c < 16; ++c) {
      const float4 w = wr[c];
      #pragma unroll
      for (int s2 = 0; s2 < 8; ++s2) {
        const float4 hv = ((const float4*)hbuf[s2])[c];
        acc[s2] += w.x * hv.x + w.y * hv.y + w.z * hv.z + w.w * hv.w;
      }
    }
    const float bb = b2[k];
    #pragma unroll
    for (int s2 = 0; s2 < 8; ++s2)
      proj[(size_t)(s0 + s2) * 6400 + k] = 0.001f * (acc[s2] + bb);
  }
}

// ---------------- small device helpers ----------------
template<int N>
__device__ __forceinline__ void pairpq(int t, int rd, int& p, int& q) {
  const int nm1 = N - 1;
  int a, b;
  if (t == 0) { a = nm1; b = rd % nm1; }
  else { a = (rd + t) % nm1; b = (rd - t + 2 * nm1) % nm1; }
  p = a < b ? a : b;
  q = a < b ? b : a;
}

__device__ __forceinline__ void jrot(float app, float aqq, float apq, float& c, float& sn) {
  c = 1.0f; sn = 0.0f;
  if (fabsf(apq) > 1e-36f + 1e-12f * (fabsf(app) + fabsf(aqq))) {
    const float tau = (aqq - app) / (2.0f * apq);
    const float t = copysignf(1.0f, tau) / (fabsf(tau) + sqrtf(1.0f + tau * tau));
    c = 1.0f / sqrtf(1.0f + t * t);
    sn = t * c;
  }
}

// pair-blocked two-sided Jacobi; H,V stride-36; diag -> eigenvalues; V columns = eigvecs
// (R2 structure; only MAXSW and the exit tolerance are changed)
template<int N>
__device__ void jacobi_pb(float* __restrict__ H, float* __restrict__ V,
                          float* __restrict__ red, int tid)
{
  constexpr int NP = N / 2;
  constexpr int NL = (N == 32) ? 5 : ((N == 16) ? 4 : 2);
  constexpr int NBMAX = (N == 32) ? 2 : 1;
  constexpr int NVMAX = (N == 32) ? 4 : 1;
  const int MAXSW = (N == 32) ? 6 : ((N == 16) ? 5 : 3);
  for (int e = tid; e < N * N; e += 128) {
    const int r = e >> NL, c = e & (N - 1);
    V[r * 36 + c] = (r == c) ? 1.0f : 0.0f;
  }
  __syncthreads();
  const int cp = tid & (NP - 1);
  const bool hact = (N == 32) ? true : (tid < NP * NP);
  const bool vact = (N >= 16) ? true : (tid < N * NP);
  for (int sw = 0; sw < MAXSW; ++sw) {
    for (int rd = 0; rd < N - 1; ++rd) {
      int q0, q1; pairpq<N>(cp, rd, q0, q1);
      float cc_, cs_;
      jrot(H[q0 * 37], H[q1 * 37], H[q0 * 36 + q1], cc_, cs_);
      float o00[NBMAX], o01[NBMAX], o10[NBMAX], o11[NBMAX];
      int P0[NBMAX], P1[NBMAX];
      #pragma unroll
      for (int bi = 0; bi < NBMAX; ++bi) {
        if (bi == 0 && !hact) continue;
        const int rp = (N == 32) ? ((tid >> 4) + 8 * bi) : ((N == 16) ? (tid >> 3) : (tid >> 1));
        int p0, p1; pairpq<N>(rp, rd, p0, p1);
        float cr_, sr_;
        jrot(H[p0 * 37], H[p1 * 37], H[p0 * 36 + p1], cr_, sr_);
        const float a  = H[p0 * 36 + q0], b = H[p0 * 36 + q1];
        const float c2 = H[p1 * 36 + q0], d = H[p1 * 36 + q1];
        const float t1 = cr_ * a - sr_ * c2, t2 = cr_ * b - sr_ * d;
        const float u1 = sr_ * a + cr_ * c2, u2 = sr_ * b + cr_ * d;
        o00[bi] = cc_ * t1 - cs_ * t2; o01[bi] = cs_ * t1 + cc_ * t2;
        o10[bi] = cc_ * u1 - cs_ * u2; o11[bi] = cs_ * u1 + cc_ * u2;
        P0[bi] = p0; P1[bi] = p1;
      }
      float v0[NVMAX], v1[NVMAX];
      #pragma unroll
      for (int vi = 0; vi < NVMAX; ++vi) {
        if (vi == 0 && !vact) continue;
        const int row = (N == 32) ? ((tid >> 4) + 8 * vi) : ((N == 16) ? (tid >> 3) : (tid >> 1));
        const float a0 = V[row * 36 + q0], a1 = V[row * 36 + q1];
        v0[vi] = cc_ * a0 - cs_ * a1; v1[vi] = cs_ * a0 + cc_ * a1;
      }
      __syncthreads();
      #pragma unroll
      for (int bi = 0; bi < NBMAX; ++bi) {
        if (bi == 0 && !hact) continue;
        H[P0[bi] * 36 + q0] = o00[bi]; H[P0[bi] * 36 + q1] = o01[bi];
        H[P1[bi] * 36 + q0] = o10[bi]; H[P1[bi] * 36 + q1] = o11[bi];
      }
      #pragma unroll
      for (int vi = 0; vi < NVMAX; ++vi) {
        if (vi == 0 && !vact) continue;
        const int row = (N == 32) ? ((tid >> 4) + 8 * vi) : ((N == 16) ? (tid >> 3) : (tid >> 1));
        V[row * 36 + q0] = v0[vi]; V[row * 36 + q1] = v1[vi];
      }
      __syncthreads();
    }
    if (N >= 16) {
      float offs = 0.0f, dia = 0.0f;
      for (int e = tid; e < N * N; e += 128) {
        const int r = e >> NL, c = e & (N - 1);
        const float v_ = H[r * 36 + c];
        if (r == c) dia += v_ * v_; else offs += v_ * v_;
      }
      for (int mk = 32; mk; mk >>= 1) { offs += __shfl_xor(offs, mk); dia += __shfl_xor(dia, mk); }
      if ((tid & 63) == 0) { red[(tid >> 6) * 2] = offs; red[(tid >> 6) * 2 + 1] = dia; }
      __syncthreads();
      const float to = red[0] + red[2];
      const float td = red[1] + red[3];
      const bool done = (to <= 1e-8f * td);
      __syncthreads();
      if (done) break;
    }
  }
  __syncthreads();
}

// G(+)= A^T A over 'nrows' stride-36 rows of A, mcols in {16,32}; float4 on column quads
__device__ __forceinline__ void gram_cols(float* __restrict__ G, const float* __restrict__ A,
                                          int nrows, int mcols, bool init, int tid)
{
  const int q4 = mcols >> 2;
  const int q4log = (mcols == 32) ? 3 : 2;
  const int nel = mcols * q4;
  const float4* A4 = (const float4*)A;
  float4* G4 = (float4*)G;
  for (int e = tid; e < nel; e += 128) {
    const int c2q = e & (q4 - 1);
    const int c1 = e >> q4log;
    float ax = 0.f, ay = 0.f, az = 0.f, aw = 0.f;
    for (int r = 0; r < nrows; ++r) {
      const float a1 = A[r * 36 + c1];
      const float4 a2 = A4[r * 9 + c2q];
      ax += a1 * a2.x; ay += a1 * a2.y; az += a1 * a2.z; aw += a1 * a2.w;
    }
    float4* gp = G4 + c1 * 9 + c2q;
    if (init) { float4 o; o.x = ax; o.y = ay; o.z = az; o.w = aw; *gp = o; }
    else { float4 o = *gp; o.x += ax; o.y += ay; o.z += az; o.w += aw; *gp = o; }
  }
  __syncthreads();
}

// absorb column i1 of row j into BIGT[(rr-rr0)*dbw+db][ua] (stride 36), rr in [rr0,rr1)
__device__ __forceinline__ void absorb_T(const float* __restrict__ Tg, const float* __restrict__ poolS,
    float* __restrict__ BIGT, float* __restrict__ ATile, const int* __restrict__ xi,
    int i1, int j, int U, int Dd, int rr0, int rr1, int tid)
{
  const int bd = (i1 == 5) ? 1 : 4;
  const int dbw = Dd * bd;
  const int mt_ = U * 4;
  const int ph = xi[i1 * 6 + j];
  const float* tb = Tg + (size_t)(i1 * 6 + j) * 512;
  for (int e = tid; e < 256; e += 128) ATile[e] = tb[e * 2 + ph];
  __syncthreads();
  const int mlog = (mt_ == 32) ? 5 : 4;
  const int dblog = 31 - __clz(dbw);
  const int bdlog = (bd == 4) ? 2 : 0;
  const int nel = mt_ * dbw * (rr1 - rr0);
  for (int e = tid; e < nel; e += 128) {
    const int ua = e & (mt_ - 1);
    const int db = (e >> mlog) & (dbw - 1);
    const int rr = rr0 + (e >> (mlog + dblog));
    const int u = ua >> 2, a = ua & 3;
    const int d_ = db >> bdlog, b = db & (bd - 1);
    const float* op = poolS + u * 33 + d_;
    const float4 av = *(const float4*)(ATile + a * 64 + rr * 16 + b * 4);
    BIGT[((rr - rr0) * dbw + db) * 36 + ua] = op[0] * av.x + op[8] * av.y + op[16] * av.z + op[24] * av.w;
  }
  __syncthreads();
}

// ============ kernel 2: one sample per 128-thread workgroup ============
__global__ __launch_bounds__(128, 2) void peps_kernel(
    const float* __restrict__ Tg, const int* __restrict__ x,
    float* __restrict__ proj, float* __restrict__ out)
{
  __shared__ float pool[6 * 264];   // [i][u<=8 stride33][x=4 stride8][d<=8]
  __shared__ float CUR[1152];       // mt: rows (u*4+rr)<=32, stride 36
  __shared__ float BIGT[2304];      // mb^T half: rows (rr*dbw+db)<=64 stride 36
  __shared__ float GbM[1152];       // Gb (or Gt for q-path); m-path: Gb@0, Gt@576
  __shared__ float TM[1152];        // T / R2@0+T1@576 / eigvecs V
  __shared__ float GM[1152];        // G / H (diagonalized in place)
  __shared__ float ATile[256];
  __shared__ float PdL[256], PuL[256];  // [mrow][8]
  __shared__ float red[4];
  __shared__ int isel[8];
  __shared__ float sinvv[8], sdiv[8];
  __shared__ int xi[36];
  __shared__ float vvec[36], vvec2[36];

  const int s = blockIdx.x;
  const int tid = threadIdx.x;
  if (tid < 36) xi[tid] = x[s * 36 + tid];
  __syncthreads();

  for (int sweep = 0; sweep < 2; ++sweep) {
    // --- init boundary MPS from row j=0 ---
    for (int i2 = 0; i2 < 6; ++i2) {
      const int ad = (i2 == 0) ? 1 : 4, bd = (i2 == 5) ? 1 : 4;
      const int bdlog = (bd == 4) ? 2 : 0;
      const int ph = xi[i2 * 6];
      const float* tb = Tg + (size_t)(i2 * 6) * 512;
      const int nel = ad * 4 * bd;
      for (int e = tid; e < nel; e += 128) {
        const int b = e & (bd - 1);
        const int rr = (e >> bdlog) & 3;
        const int a = e >> (bdlog + 2);
        pool[i2 * 264 + a * 33 + rr * 8 + b] = tb[(a * 64 + rr * 16 + b * 4) * 2 + ph];
      }
    }
    __syncthreads();

    for (int j = 1; j <= 4; ++j) {
      const int jj = (j > 1) ? 1 : 0;
      // absorb column 0 into CUR (4 rows x 16 cols)
      {
        const int ph = xi[j];          // site (0,j)
        const float* tb = Tg + (size_t)j * 512;
        for (int e = tid; e < 256; e += 128) ATile[e] = tb[e * 2 + ph];
        __syncthreads();
        for (int e = tid; e < 64; e += 128) {
          const int db = e & 15;
          const int rr = e >> 4;
          const int d_ = db >> 2, b = db & 3;
          const float* op = pool + d_;  // slot 0, u=0
          const float4 av = *(const float4*)(ATile + rr * 16 + b * 4);  // a=0
          CUR[rr * 36 + db] = op[0] * av.x + op[8] * av.y + op[16] * av.z + op[24] * av.w;
        }
        __syncthreads();
      }

      for (int i = 0; i < 5; ++i) {
        const int m = g_mtab[jj][i], cb = g_cbtab[i], ucur = g_ucurtab[i], dn = g_dntab[jj][i];
        const int p = ucur * 4, path = g_path[jj][i];
        const int U1 = g_uprev[jj][i + 1], Dd1 = g_dprev[jj][i + 1];
        const bool two = (dn == 32);
        const int cblog = (cb == 8) ? 3 : 2;
        const int mq4 = m >> 2;
        float* projb = proj + (size_t)s * 6400 + g_offtab[j - 1][i];

        if (sweep == 0) {
          if (path == 2) {
            // ---- q-side (i=4): G = mb^T Gt mb (4x4) ----
            absorb_T(Tg, pool + (i + 1) * 264, BIGT, ATile, xi, i + 1, j, U1, Dd1, 0, 4, tid);
            gram_cols(GbM, CUR, p, m, true, tid);   // Gt (16x16)
            for (int e = tid; e < 64; e += 128) {   // T1 = Gt*mb (16x4)
              const int r = e & 3, k = e >> 2;
              float acc = 0.f;
              const float4* G4 = (const float4*)GbM;
              const float4* B4 = (const float4*)BIGT;
              for (int lq = 0; lq < 4; ++lq) {
                const float4 g = G4[k * 9 + lq], b = B4[r * 9 + lq];
                acc += g.x * b.x + g.y * b.y + g.z * b.z + g.w * b.w;
              }
              TM[k * 36 + r] = acc;
            }
            __syncthreads();
            for (int e = tid; e < 16; e += 128) {   // G = mb^T * T1 (4x4)
              const int c = e & 3, r = e >> 2;
              float acc = 0.f;
              for (int k = 0; k < 16; ++k) acc += BIGT[r * 36 + k] * TM[k * 36 + c];
              GM[r * 36 + c] = acc;
            }
            __syncthreads();
            jacobi_pb<4>(GM, TM + 576, red, tid);
          } else if (path == 0) {
            // ---- p-side: G = mt Gb mt^T (p x p), no Cholesky ----
            if (!two) {
              absorb_T(Tg, pool + (i + 1) * 264, BIGT, ATile, xi, i + 1, j, U1, Dd1, 0, 4, tid);
              gram_cols(GbM, BIGT, 4 * dn, m, true, tid);
            } else {
              absorb_T(Tg, pool + (i + 1) * 264, BIGT, ATile, xi, i + 1, j, U1, Dd1, 0, 2, tid);
              gram_cols(GbM, BIGT, 2 * dn, m, true, tid);
              absorb_T(Tg, pool + (i + 1) * 264, BIGT, ATile, xi, i + 1, j, U1, Dd1, 2, 4, tid);
              gram_cols(GbM, BIGT, 2 * dn, m, false, tid);
            }
            const int q4log = (m == 32) ? 3 : 2;
            for (int e = tid; e < p * mq4; e += 128) {  // T = mt*Gb (p x m)
              const int lq = e & (mq4 - 1), pr = e >> q4log;
              float ax = 0.f, ay = 0.f, az = 0.f, aw = 0.f;
              const float4* G4 = (const float4*)GbM;
              for (int k = 0; k < m; ++k) {
                const float a1 = CUR[pr * 36 + k];
                const float4 g = G4[k * 9 + lq];
                ax += a1 * g.x; ay += a1 * g.y; az += a1 * g.z; aw += a1 * g.w;
              }
              float4 o; o.x = ax; o.y = ay; o.z = az; o.w = aw;
              ((float4*)TM)[pr * 9 + lq] = o;
            }
            __syncthreads();
            const int plog = (p == 32) ? 5 : ((p == 16) ? 4 : 2);
            for (int e = tid; e < p * p; e += 128) {    // G = T*mt^T (p x p)
              const int pc = e & (p - 1), pr = e >> plog;
              float acc = 0.f;
              const float4* T4 = (const float4*)TM;
              const float4* C4 = (const float4*)CUR;
              for (int lq = 0; lq < mq4; ++lq) {
                const float4 t = T4[pr * 9 + lq], c = C4[pc * 9 + lq];
                acc += t.x * c.x + t.y * c.y + t.z * c.z + t.w * c.w;
              }
              GM[pr * 36 + pc] = acc;
            }
            __syncthreads();
            if (p == 4)       jacobi_pb<4>(GM, TM, red, tid);
            else if (p == 16) jacobi_pb<16>(GM, TM, red, tid);
            else              jacobi_pb<32>(GM, TM, red, tid);
          } else {
            // ---- m-side (jj0 i=2,3): Gt, Gb, chol(Gb), H = R2 Gt R2^T (16x16) ----
            absorb_T(Tg, pool + (i + 1) * 264, BIGT, ATile, xi, i + 1, j, U1, Dd1, 0, 4, tid);
            gram_cols(GbM + 576, CUR, p, m, true, tid);     // Gt
            gram_cols(GbM, BIGT, 4 * dn, m, true, tid);     // Gb
            // cholesky Gb -> R2 (TM[0:576]) with zero-skip
            if (tid < 64) {
              float v_ = (tid < 16) ? GbM[tid * 37] : -3.0e38f;
              for (int mk = 32; mk; mk >>= 1) v_ = fmaxf(v_, __shfl_xor(v_, mk));
              if (tid == 0) red[0] = v_;
            }
            __syncthreads();
            const float thr = 1e-10f * red[0] + 1e-35f;
            for (int k = 0; k < 16; ++k) {
              const float dk = GbM[k * 37];
              const float rs = (dk > thr) ? (1.0f / sqrtf(dk)) : 0.0f;
              if (tid < 16) TM[k * 36 + tid] = GbM[k * 36 + tid] * rs;
              __syncthreads();
              const int rows = 15 - k;
              for (int e = tid; e < rows * 16; e += 128) {
                const int ii = k + 1 + (e >> 4), jc = e & 15;
                GbM[ii * 36 + jc] -= TM[k * 36 + ii] * TM[k * 36 + jc];
              }
              __syncthreads();
            }
            for (int e = tid; e < 64; e += 128) {   // T1 = R2*Gt -> TM+576
              const int jq = e & 3, k = e >> 2;
              float ax = 0.f, ay = 0.f, az = 0.f, aw = 0.f;
              const float4* Gt4 = (const float4*)(GbM + 576);
              for (int l = 0; l < 16; ++l) {
                const float r2 = TM[k * 36 + l];
                const float4 g = Gt4[l * 9 + jq];
                ax += r2 * g.x; ay += r2 * g.y; az += r2 * g.z; aw += r2 * g.w;
              }
              float4 o; o.x = ax; o.y = ay; o.z = az; o.w = aw;
              ((float4*)(TM + 576))[k * 9 + jq] = o;
            }
            __syncthreads();
            for (int e = tid; e < 256; e += 128) {  // H = T1*R2^T -> GM
              const int k2 = e & 15, k = e >> 4;
              float acc = 0.f;
              const float4* T14 = (const float4*)(TM + 576);
              const float4* R24 = (const float4*)TM;
              for (int lq = 0; lq < 4; ++lq) {
                const float4 t = T14[k * 9 + lq], r = R24[k2 * 9 + lq];
                acc += t.x * r.x + t.y * r.y + t.z * r.z + t.w * r.w;
              }
              GM[k * 36 + k2] = acc;
            }
            __syncthreads();
            jacobi_pb<16>(GM, TM + 576, red, tid);
          }

          // ---- top-cb selection + scales ----
          const int N = (path == 2) ? 4 : ((path == 1) ? 16 : p);
          if (tid < 64) {
            float v_ = (tid < N) ? GM[tid * 37] : -3.0e38f;
            int ix = tid;
            for (int t = 0; t < cb; ++t) {
              float bv = v_; int bi = ix;
              for (int mk = 32; mk; mk >>= 1) {
                const float ov = __shfl_xor(bv, mk);
                const int oi = __shfl_xor(bi, mk);
                if (ov > bv || (ov == bv && oi < bi)) { bv = ov; bi = oi; }
              }
              if (tid == 0) isel[t] = bi;
              if (ix == bi) v_ = -3.0e38f;
            }
          }
          __syncthreads();
          if (tid < cb) {
            const float lam = GM[isel[tid] * 37];
            const float s_ = sqrtf(fmaxf(lam, 0.0f));
            sinvv[tid] = 1.0f / sqrtf(s_ + 1e-12f);
            sdiv[tid]  = 1.0f / fmaxf(s_, 1e-25f);
          }
          __syncthreads();

          // ---- projectors ----
          if (path == 0) {
            // Pu = mt^T U sinv ; Pd = Gb Pu / s   (U cols in TM)
            for (int e = tid; e < m * cb; e += 128) {
              const int k = e & (cb - 1), mrow = e >> cblog;
              const int a = isel[k];
              float acc = 0.f;
              for (int pr = 0; pr < p; ++pr) acc += CUR[pr * 36 + mrow] * TM[pr * 36 + a];
              PuL[mrow * 8 + k] = acc * sinvv[k];
            }
            __syncthreads();
            for (int e = tid; e < m * cb; e += 128) {
              const int k = e & (cb - 1), mrow = e >> cblog;
              float acc = 0.f;
              for (int l = 0; l < m; ++l) acc += GbM[mrow * 36 + l] * PuL[l * 8 + k];
              PdL[mrow * 8 + k] = acc * sdiv[k];
            }
            __syncthreads();
          } else if (path == 2) {
            // Pd = mb V sinv ; Pu = Gt Pd / s   (V in TM+576, Gt in GbM)
            for (int e = tid; e < m * cb; e += 128) {
              const int k = e & (cb - 1), mrow = e >> cblog;
              const int a = isel[k];
              float acc = 0.f;
              for (int r = 0; r < 4; ++r) acc += BIGT[r * 36 + mrow] * TM[576 + r * 36 + a];
              PdL[mrow * 8 + k] = acc * sinvv[k];
            }
            __syncthreads();
            for (int e = tid; e < m * cb; e += 128) {
              const int k = e & (cb - 1), mrow = e >> cblog;
              float acc = 0.f;
              for (int l = 0; l < m; ++l) acc += GbM[mrow * 36 + l] * PdL[l * 8 + k];
              PuL[mrow * 8 + k] = acc * sdiv[k];
            }
            __syncthreads();
          } else {
            // Pd = R2^T V sinv ; Pu = Gt Pd / s  (R2 in TM[0:576], V in TM+576, Gt in GbM+576)
            for (int e = tid; e < m * cb; e += 128) {
              const int k = e & (cb - 1), mrow = e >> cblog;
              const int a = isel[k];
              float acc = 0.f;
              for (int t = 0; t < 16; ++t) acc += TM[t * 36 + mrow] * TM[576 + t * 36 + a];
              PdL[mrow * 8 + k] = acc * sinvv[k];
            }
            __syncthreads();
            for (int e = tid; e < m * cb; e += 128) {
              const int k = e & (cb - 1), mrow = e >> cblog;
              float acc = 0.f;
              for (int l = 0; l < m; ++l) acc += GbM[576 + mrow * 36 + l] * PdL[l * 8 + k];
              PuL[mrow * 8 + k] = acc * sdiv[k];
            }
            __syncthreads();
          }
          // store perturbed projectors (ws slot preloaded with ETA*mlp)
          for (int e = tid; e < m * cb; e += 128)
            projb[e] += PdL[(e >> cblog) * 8 + (e & (cb - 1))];
          for (int e = tid; e < m * cb; e += 128)
            projb[m * cb + e] += PuL[(e >> cblog) * 8 + (e & (cb - 1))];
        } else {
          // ---- sweep 2: load perturbed projectors + stage mb (B-half for two-pass) ----
          for (int e = tid; e < m * cb; e += 128)
            PdL[(e >> cblog) * 8 + (e & (cb - 1))] = projb[e];
          for (int e = tid; e < m * cb; e += 128)
            PuL[(e >> cblog) * 8 + (e & (cb - 1))] = projb[m * cb + e];
          __syncthreads();
          if (!two) absorb_T(Tg, pool + (i + 1) * 264, BIGT, ATile, xi, i + 1, j, U1, Dd1, 0, 4, tid);
          else      absorb_T(Tg, pool + (i + 1) * 264, BIGT, ATile, xi, i + 1, j, U1, Dd1, 2, 4, tid);
        }

        // ---- common: Bn[i] = Tt*Pd -> pool[i]; Bn[i+1] = Pu applied to mb -> CUR (or pool[5]) ----
        {
          const int nel = ucur * 4 * cb;
          const float4* C4 = (const float4*)CUR;
          for (int e = tid; e < nel; e += 128) {
            const int cc = e & (cb - 1);
            const int rr = (e >> cblog) & 3;
            const int u = e >> (cblog + 2);
            const int row = u * 4 + rr;
            float acc = 0.f;
            for (int mq = 0; mq < mq4; ++mq) {
              const float4 cv = C4[row * 9 + mq];
              acc += cv.x * PdL[(mq * 4 + 0) * 8 + cc] + cv.y * PdL[(mq * 4 + 1) * 8 + cc]
                   + cv.z * PdL[(mq * 4 + 2) * 8 + cc] + cv.w * PdL[(mq * 4 + 3) * 8 + cc];
            }
            pool[i * 264 + u * 33 + rr * 8 + cc] = acc;
          }
          __syncthreads();

          const int dnlog = 31 - __clz(dn);
          auto bn1 = [&](int rr0, int nloc) {
            const int ne2 = cb * nloc * dn;
            const float4* B4 = (const float4*)BIGT;
            for (int e = tid; e < ne2; e += 128) {
              const int dd = e & (dn - 1);
              const int t = e >> dnlog;
              const int rrL = t & (nloc - 1);
              const int cc = t >> ((nloc == 4) ? 2 : 1);
              const int row = rrL * dn + dd;
              float acc = 0.f;
              for (int mq = 0; mq < mq4; ++mq) {
                const float4 bv = B4[row * 9 + mq];
                acc += bv.x * PuL[(mq * 4 + 0) * 8 + cc] + bv.y * PuL[(mq * 4 + 1) * 8 + cc]
                     + bv.z * PuL[(mq * 4 + 2) * 8 + cc] + bv.w * PuL[(mq * 4 + 3) * 8 + cc];
              }
              if (i < 4) CUR[(cc * 4 + rr0 + rrL) * 36 + dd] = acc;
              else       pool[5 * 264 + cc * 33 + (rr0 + rrL) * 8] = acc;
            }
            __syncthreads();
          };
          if (!two) {
            bn1(0, 4);
          } else {
            bn1(2, 2);
            absorb_T(Tg, pool + (i + 1) * 264, BIGT, ATile, xi, i + 1, j, U1, Dd1, 0, 2, tid);
            bn1(0, 2);
          }
        }
      }
    }

    if (sweep == 1) {
      // ---- finalize: scalar = prod_i C_i ----
      if (tid == 0) vvec[0] = 1.0f;
      __syncthreads();
      for (int i = 0; i < 6; ++i) {
        const int ad = (i == 0) ? 1 : 4, bd = (i == 5) ? 1 : 4;
        const int adlog = (ad == 4) ? 2 : 0, bdlog = (bd == 4) ? 2 : 0;
        const int rows = g_ufin[i] * ad, cols = g_dfin[i] * bd;
        const int clog = 31 - __clz(cols);
        const int ph = xi[i * 6 + 5];
        const float* tb = Tg + (size_t)(i * 6 + 5) * 512;
        for (int e = tid; e < 256; e += 128) ATile[e] = tb[e * 2 + ph];
        __syncthreads();
        for (int e = tid; e < rows * cols; e += 128) {
          const int col = e & (cols - 1);
          const int ua = e >> clog;
          const int u = ua >> adlog, a = ua & (ad - 1);
          const int d_ = col >> bdlog, b = col & (bd - 1);
          const float* fb = pool + i * 264 + u * 33 + d_;
          const float4 av = *(const float4*)(ATile + a * 64 + b * 4);  // R = 0 slice
          GM[ua * 36 + col] = fb[0] * av.x + fb[8] * av.y + fb[16] * av.z + fb[24] * av.w;
        }
        __syncthreads();
        if (tid < cols) {
          float acc = 0.f;
          for (int r_ = 0; r_ < rows; ++r_) acc += vvec[r_] * GM[r_ * 36 + tid];
          vvec2[tid] = acc;
        }
        __syncthreads();
        if (tid < cols) vvec[tid] = vvec2[tid];
        __syncthreads();
      }
      if (tid == 0) out[s] = vvec[0];
    }
  }
}

extern "C" void kernel_launch(void* const* d_in, const int* in_sizes, int n_in,
                              void* d_out, int out_size, void* d_ws, size_t ws_size,
                              hipStream_t stream) {
  const float* Tg = (const float*)d_in[0];
  const float* W1 = (const float*)d_in[1];
  const float* b1 = (const float*)d_in[2];
  const float* W2 = (const float*)d_in[3];
  const float* b2 = (const float*)d_in[4];
  const int*   x  = (const int*)d_in[5];
  float* out = (float*)d_out;
  float* proj = (float*)d_ws;   // 1024*6400 floats: ETA*mlp then += projectors
  (void)in_sizes; (void)n_in; (void)out_size; (void)ws_size;

  mlp_kernel<<<dim3(128), dim3(256), 0, stream>>>(W1, b1, W2, b2, x, proj);
  peps_kernel<<<dim3(1024), dim3(128), 0, stream>>>(Tg, x, proj, out);
}

// Round 7
// 2121.735 us; speedup vs baseline: 3.1271x; 1.3303x over previous
//
#include <hip/hip_runtime.h>

// ---------------- static schedule tables ----------------
__device__ const int g_uprev[2][6] = {{1,4,4,4,4,4},{1,4,8,8,8,4}};
__device__ const int g_dprev[2][6] = {{4,4,4,4,4,1},{4,8,8,8,4,1}};
__device__ const int g_mtab[2][5]  = {{16,16,16,16,16},{16,32,32,32,16}};
__device__ const int g_cbtab[5]    = {4,8,8,8,4};
__device__ const int g_ucurtab[5]  = {1,4,8,8,8};
__device__ const int g_dntab[2][5] = {{16,16,16,16,1},{32,32,32,16,1}};
__device__ const int g_path[2][5]  = {{0,0,1,1,2},{0,0,0,0,2}};  // 0=p-side,1=m-side(chol),2=q-side
__device__ const int g_offtab[4][5]= {{0,128,384,640,896},
                                      {1024,1152,1664,2176,2688},
                                      {2816,2944,3456,3968,4480},
                                      {4608,4736,5248,5760,6272}};
__device__ const int g_ufin[6] = {1,4,8,8,8,4};
__device__ const int g_dfin[6] = {4,8,8,8,4,1};

// ============ kernel 1: proj[s][k] = ETA*mlp(x_s)[k] ============
__global__ __launch_bounds__(256) void mlp_kernel(
    const float* __restrict__ W1, const float* __restrict__ b1,
    const float* __restrict__ W2, const float* __restrict__ b2,
    const int* __restrict__ x, float* __restrict__ proj)
{
  __shared__ float hbuf[8][64];
  const int tid = threadIdx.x;
  const int s0 = blockIdx.x << 3;
  for (int e = tid; e < 512; e += 256) {
    const int sl = e >> 6, hh = e & 63;
    const int* xr = x + (s0 + sl) * 36;
    const float* wr = W1 + hh * 36;
    float acc = b1[hh];
    #pragma unroll
    for (int t = 0; t < 36; ++t) acc += wr[t] * (float)xr[t];
    hbuf[sl][hh] = fmaxf(acc, 0.0f);
  }
  __syncthreads();
  for (int k = tid; k < 6400; k += 256) {
    const float4* wr = (const float4*)(W2 + (size_t)k * 64);
    float acc[8];
    #pragma unroll
    for (int s2 = 0; s2 < 8; ++s2) acc[s2] = 0.0f;
    #pragma unroll
    for (int c = 0; c < 16; ++c) {
      const float4 w = wr[c];
      #pragma unroll
      for (int s2 = 0; s2 < 8; ++s2) {
        const float4 hv = ((const float4*)hbuf[s2])[c];
        acc[s2] += w.x * hv.x + w.y * hv.y + w.z * hv.z + w.w * hv.w;
      }
    }
    const float bb = b2[k];
    #pragma unroll
    for (int s2 = 0; s2 < 8; ++s2)
      proj[(size_t)(s0 + s2) * 6400 + k] = 0.001f * (acc[s2] + bb);
  }
}

// ---------------- small device helpers ----------------
template<int N>
__device__ __forceinline__ void pairpq(int t, int rd, int& p, int& q) {
  const int nm1 = N - 1;
  int a, b;
  if (t == 0) { a = nm1; b = rd % nm1; }
  else { a = (rd + t) % nm1; b = (rd - t + 2 * nm1) % nm1; }
  p = a < b ? a : b;
  q = a < b ? b : a;
}

__device__ __forceinline__ void jrot(float app, float aqq, float apq, float& c, float& sn) {
  c = 1.0f; sn = 0.0f;
  if (fabsf(apq) > 1e-36f + 1e-12f * (fabsf(app) + fabsf(aqq))) {
    const float tau = (aqq - app) / (2.0f * apq);
    const float t = copysignf(1.0f, tau) / (fabsf(tau) + sqrtf(1.0f + tau * tau));
    c = 1.0f / sqrtf(1.0f + t * t);
    sn = t * c;
  }
}

// pair-blocked two-sided Jacobi; H,V stride-36; diag -> eigenvalues; V columns = eigvecs.
// Angles computed ONCE per pair per wave (lane t handles pair t) and shfl-broadcast.
// Fixed sweep counts (no exit check): 6/5/3.
template<int N>
__device__ void jacobi_pb(float* __restrict__ H, float* __restrict__ V, int tid)
{
  constexpr int NP = N / 2;
  constexpr int NL = (N == 32) ? 5 : ((N == 16) ? 4 : 2);
  constexpr int NBMAX = (N == 32) ? 2 : 1;
  constexpr int NVMAX = (N == 32) ? 4 : 1;
  constexpr int MAXSW = (N == 32) ? 6 : ((N == 16) ? 5 : 3);
  for (int e = tid; e < N * N; e += 128) {
    const int r = e >> NL, c = e & (N - 1);
    V[r * 36 + c] = (r == c) ? 1.0f : 0.0f;
  }
  __syncthreads();
  const int lane = tid & 63;
  const int cp = tid & (NP - 1);
  const bool hact = (N == 32) ? true : (tid < NP * NP);
  const bool vact = (N >= 16) ? true : (tid < N * NP);
  for (int sw = 0; sw < MAXSW; ++sw) {
    for (int rd = 0; rd < N - 1; ++rd) {
      // one jrot chain per lane (pair = lane & (NP-1)); wave holds all NP angles in lanes 0..NP-1
      int ap, aq; pairpq<N>(lane & (NP - 1), rd, ap, aq);
      float myc, mys;
      jrot(H[ap * 37], H[aq * 37], H[ap * 36 + aq], myc, mys);
      int q0, q1; pairpq<N>(cp, rd, q0, q1);
      const float cc_ = __shfl(myc, cp);
      const float cs_ = __shfl(mys, cp);
      float o00[NBMAX], o01[NBMAX], o10[NBMAX], o11[NBMAX];
      int P0[NBMAX], P1[NBMAX];
      #pragma unroll
      for (int bi = 0; bi < NBMAX; ++bi) {
        if (bi == 0 && !hact) continue;
        const int rp = (N == 32) ? ((tid >> 4) + 8 * bi) : ((N == 16) ? (tid >> 3) : (tid >> 1));
        int p0, p1; pairpq<N>(rp, rd, p0, p1);
        const float cr_ = __shfl(myc, rp);
        const float sr_ = __shfl(mys, rp);
        const float a  = H[p0 * 36 + q0], b = H[p0 * 36 + q1];
        const float c2 = H[p1 * 36 + q0], d = H[p1 * 36 + q1];
        const float t1 = cr_ * a - sr_ * c2, t2 = cr_ * b - sr_ * d;
        const float u1 = sr_ * a + cr_ * c2, u2 = sr_ * b + cr_ * d;
        o00[bi] = cc_ * t1 - cs_ * t2; o01[bi] = cs_ * t1 + cc_ * t2;
        o10[bi] = cc_ * u1 - cs_ * u2; o11[bi] = cs_ * u1 + cc_ * u2;
        P0[bi] = p0; P1[bi] = p1;
      }
      float v0[NVMAX], v1[NVMAX];
      #pragma unroll
      for (int vi = 0; vi < NVMAX; ++vi) {
        if (vi == 0 && !vact) continue;
        const int row = (N == 32) ? ((tid >> 4) + 8 * vi) : ((N == 16) ? (tid >> 3) : (tid >> 1));
        const float a0 = V[row * 36 + q0], a1 = V[row * 36 + q1];
        v0[vi] = cc_ * a0 - cs_ * a1; v1[vi] = cs_ * a0 + cc_ * a1;
      }
      __syncthreads();
      #pragma unroll
      for (int bi = 0; bi < NBMAX; ++bi) {
        if (bi == 0 && !hact) continue;
        H[P0[bi] * 36 + q0] = o00[bi]; H[P0[bi] * 36 + q1] = o01[bi];
        H[P1[bi] * 36 + q0] = o10[bi]; H[P1[bi] * 36 + q1] = o11[bi];
      }
      #pragma unroll
      for (int vi = 0; vi < NVMAX; ++vi) {
        if (vi == 0 && !vact) continue;
        const int row = (N == 32) ? ((tid >> 4) + 8 * vi) : ((N == 16) ? (tid >> 3) : (tid >> 1));
        V[row * 36 + q0] = v0[vi]; V[row * 36 + q1] = v1[vi];
      }
      __syncthreads();
    }
  }
}

// G(+)= A^T A over 'nrows' stride-36 rows of A, mcols in {16,32}; float4 on column quads
__device__ __forceinline__ void gram_cols(float* __restrict__ G, const float* __restrict__ A,
                                          int nrows, int mcols, bool init, int tid)
{
  const int q4 = mcols >> 2;
  const int q4log = (mcols == 32) ? 3 : 2;
  const int nel = mcols * q4;
  const float4* A4 = (const float4*)A;
  float4* G4 = (float4*)G;
  for (int e = tid; e < nel; e += 128) {
    const int c2q = e & (q4 - 1);
    const int c1 = e >> q4log;
    float ax = 0.f, ay = 0.f, az = 0.f, aw = 0.f;
    for (int r = 0; r < nrows; ++r) {
      const float a1 = A[r * 36 + c1];
      const float4 a2 = A4[r * 9 + c2q];
      ax += a1 * a2.x; ay += a1 * a2.y; az += a1 * a2.z; aw += a1 * a2.w;
    }
    float4* gp = G4 + c1 * 9 + c2q;
    if (init) { float4 o; o.x = ax; o.y = ay; o.z = az; o.w = aw; *gp = o; }
    else { float4 o = *gp; o.x += ax; o.y += ay; o.z += az; o.w += aw; *gp = o; }
  }
  __syncthreads();
}

// absorb column i1 of row j into BIGT[(rr-rr0)*dbw+db][ua] (stride 36), rr in [rr0,rr1)
__device__ __forceinline__ void absorb_T(const float* __restrict__ Tg, const float* __restrict__ poolS,
    float* __restrict__ BIGT, float* __restrict__ ATile, const int* __restrict__ xi,
    int i1, int j, int U, int Dd, int rr0, int rr1, int tid)
{
  const int bd = (i1 == 5) ? 1 : 4;
  const int dbw = Dd * bd;
  const int mt_ = U * 4;
  const int ph = xi[i1 * 6 + j];
  const float* tb = Tg + (size_t)(i1 * 6 + j) * 512;
  for (int e = tid; e < 256; e += 128) ATile[e] = tb[e * 2 + ph];
  __syncthreads();
  const int mlog = (mt_ == 32) ? 5 : 4;
  const int dblog = 31 - __clz(dbw);
  const int bdlog = (bd == 4) ? 2 : 0;
  const int nel = mt_ * dbw * (rr1 - rr0);
  for (int e = tid; e < nel; e += 128) {
    const int ua = e & (mt_ - 1);
    const int db = (e >> mlog) & (dbw - 1);
    const int rr = rr0 + (e >> (mlog + dblog));
    const int u = ua >> 2, a = ua & 3;
    const int d_ = db >> bdlog, b = db & (bd - 1);
    const float* op = poolS + u * 33 + d_;
    const float4 av = *(const float4*)(ATile + a * 64 + rr * 16 + b * 4);
    BIGT[((rr - rr0) * dbw + db) * 36 + ua] = op[0] * av.x + op[8] * av.y + op[16] * av.z + op[24] * av.w;
  }
  __syncthreads();
}

// ============ kernel 2: one sample per 128-thread workgroup ============
__global__ __launch_bounds__(128, 2) void peps_kernel(
    const float* __restrict__ Tg, const int* __restrict__ x,
    float* __restrict__ proj, float* __restrict__ out)
{
  __shared__ float pool[6 * 264];   // [i][u<=8 stride33][x=4 stride8][d<=8]
  __shared__ float CUR[1152];       // mt: rows (u*4+rr)<=32, stride 36
  __shared__ float BIGT[2304];      // mb^T half: rows (rr*dbw+db)<=64 stride 36
  __shared__ float GbM[1152];       // Gb (or Gt for q-path); m-path: Gb@0, Gt@576
  __shared__ float TM[1152];        // T / R2@0+T1@576 / eigvecs V
  __shared__ float GM[1152];        // G / H (diagonalized in place)
  __shared__ float ATile[256];
  __shared__ float PdL[256], PuL[256];  // [mrow][8]
  __shared__ float red[4];
  __shared__ int isel[8];
  __shared__ float sinvv[8], sdiv[8];
  __shared__ int xi[36];
  __shared__ float vvec[36], vvec2[36];

  const int s = blockIdx.x;
  const int tid = threadIdx.x;
  if (tid < 36) xi[tid] = x[s * 36 + tid];
  __syncthreads();

  for (int sweep = 0; sweep < 2; ++sweep) {
    // --- init boundary MPS from row j=0 ---
    for (int i2 = 0; i2 < 6; ++i2) {
      const int ad = (i2 == 0) ? 1 : 4, bd = (i2 == 5) ? 1 : 4;
      const int bdlog = (bd == 4) ? 2 : 0;
      const int ph = xi[i2 * 6];
      const float* tb = Tg + (size_t)(i2 * 6) * 512;
      const int nel = ad * 4 * bd;
      for (int e = tid; e < nel; e += 128) {
        const int b = e & (bd - 1);
        const int rr = (e >> bdlog) & 3;
        const int a = e >> (bdlog + 2);
        pool[i2 * 264 + a * 33 + rr * 8 + b] = tb[(a * 64 + rr * 16 + b * 4) * 2 + ph];
      }
    }
    __syncthreads();

    for (int j = 1; j <= 4; ++j) {
      const int jj = (j > 1) ? 1 : 0;
      // absorb column 0 into CUR (4 rows x 16 cols)
      {
        const int ph = xi[j];          // site (0,j)
        const float* tb = Tg + (size_t)j * 512;
        for (int e = tid; e < 256; e += 128) ATile[e] = tb[e * 2 + ph];
        __syncthreads();
        for (int e = tid; e < 64; e += 128) {
          const int db = e & 15;
          const int rr = e >> 4;
          const int d_ = db >> 2, b = db & 3;
          const float* op = pool + d_;  // slot 0, u=0
          const float4 av = *(const float4*)(ATile + rr * 16 + b * 4);  // a=0
          CUR[rr * 36 + db] = op[0] * av.x + op[8] * av.y + op[16] * av.z + op[24] * av.w;
        }
        __syncthreads();
      }

      for (int i = 0; i < 5; ++i) {
        const int m = g_mtab[jj][i], cb = g_cbtab[i], ucur = g_ucurtab[i], dn = g_dntab[jj][i];
        const int p = ucur * 4, path = g_path[jj][i];
        const int U1 = g_uprev[jj][i + 1], Dd1 = g_dprev[jj][i + 1];
        const bool two = (dn == 32);
        const int cblog = (cb == 8) ? 3 : 2;
        const int mq4 = m >> 2;
        float* projb = proj + (size_t)s * 6400 + g_offtab[j - 1][i];

        if (sweep == 0) {
          if (path == 2) {
            // ---- q-side (i=4): G = mb^T Gt mb (4x4) ----
            absorb_T(Tg, pool + (i + 1) * 264, BIGT, ATile, xi, i + 1, j, U1, Dd1, 0, 4, tid);
            gram_cols(GbM, CUR, p, m, true, tid);   // Gt (16x16)
            for (int e = tid; e < 64; e += 128) {   // T1 = Gt*mb (16x4)
              const int r = e & 3, k = e >> 2;
              float acc = 0.f;
              const float4* G4 = (const float4*)GbM;
              const float4* B4 = (const float4*)BIGT;
              for (int lq = 0; lq < 4; ++lq) {
                const float4 g = G4[k * 9 + lq], b = B4[r * 9 + lq];
                acc += g.x * b.x + g.y * b.y + g.z * b.z + g.w * b.w;
              }
              TM[k * 36 + r] = acc;
            }
            __syncthreads();
            for (int e = tid; e < 16; e += 128) {   // G = mb^T * T1 (4x4)
              const int c = e & 3, r = e >> 2;
              float acc = 0.f;
              for (int k = 0; k < 16; ++k) acc += BIGT[r * 36 + k] * TM[k * 36 + c];
              GM[r * 36 + c] = acc;
            }
            __syncthreads();
            jacobi_pb<4>(GM, TM + 576, tid);
          } else if (path == 0) {
            // ---- p-side: G = mt Gb mt^T (p x p), no Cholesky ----
            if (!two) {
              absorb_T(Tg, pool + (i + 1) * 264, BIGT, ATile, xi, i + 1, j, U1, Dd1, 0, 4, tid);
              gram_cols(GbM, BIGT, 4 * dn, m, true, tid);
            } else {
              absorb_T(Tg, pool + (i + 1) * 264, BIGT, ATile, xi, i + 1, j, U1, Dd1, 0, 2, tid);
              gram_cols(GbM, BIGT, 2 * dn, m, true, tid);
              absorb_T(Tg, pool + (i + 1) * 264, BIGT, ATile, xi, i + 1, j, U1, Dd1, 2, 4, tid);
              gram_cols(GbM, BIGT, 2 * dn, m, false, tid);
            }
            const int q4log = (m == 32) ? 3 : 2;
            for (int e = tid; e < p * mq4; e += 128) {  // T = mt*Gb (p x m)
              const int lq = e & (mq4 - 1), pr = e >> q4log;
              float ax = 0.f, ay = 0.f, az = 0.f, aw = 0.f;
              const float4* G4 = (const float4*)GbM;
              for (int k = 0; k < m; ++k) {
                const float a1 = CUR[pr * 36 + k];
                const float4 g = G4[k * 9 + lq];
                ax += a1 * g.x; ay += a1 * g.y; az += a1 * g.z; aw += a1 * g.w;
              }
              float4 o; o.x = ax; o.y = ay; o.z = az; o.w = aw;
              ((float4*)TM)[pr * 9 + lq] = o;
            }
            __syncthreads();
            const int plog = (p == 32) ? 5 : ((p == 16) ? 4 : 2);
            for (int e = tid; e < p * p; e += 128) {    // G = T*mt^T (p x p)
              const int pc = e & (p - 1), pr = e >> plog;
              float acc = 0.f;
              const float4* T4 = (const float4*)TM;
              const float4* C4 = (const float4*)CUR;
              for (int lq = 0; lq < mq4; ++lq) {
                const float4 t = T4[pr * 9 + lq], c = C4[pc * 9 + lq];
                acc += t.x * c.x + t.y * c.y + t.z * c.z + t.w * c.w;
              }
              GM[pr * 36 + pc] = acc;
            }
            __syncthreads();
            if (p == 4)       jacobi_pb<4>(GM, TM, tid);
            else if (p == 16) jacobi_pb<16>(GM, TM, tid);
            else              jacobi_pb<32>(GM, TM, tid);
          } else {
            // ---- m-side (jj0 i=2,3): Gt, Gb, chol(Gb), H = R2 Gt R2^T (16x16) ----
            absorb_T(Tg, pool + (i + 1) * 264, BIGT, ATile, xi, i + 1, j, U1, Dd1, 0, 4, tid);
            gram_cols(GbM + 576, CUR, p, m, true, tid);     // Gt
            gram_cols(GbM, BIGT, 4 * dn, m, true, tid);     // Gb
            // cholesky Gb -> R2 (TM[0:576]) with zero-skip
            if (tid < 64) {
              float v_ = (tid < 16) ? GbM[tid * 37] : -3.0e38f;
              for (int mk = 32; mk; mk >>= 1) v_ = fmaxf(v_, __shfl_xor(v_, mk));
              if (tid == 0) red[0] = v_;
            }
            __syncthreads();
            const float thr = 1e-10f * red[0] + 1e-35f;
            for (int k = 0; k < 16; ++k) {
              const float dk = GbM[k * 37];
              const float rs = (dk > thr) ? (1.0f / sqrtf(dk)) : 0.0f;
              if (tid < 16) TM[k * 36 + tid] = GbM[k * 36 + tid] * rs;
              __syncthreads();
              const int rows = 15 - k;
              for (int e = tid; e < rows * 16; e += 128) {
                const int ii = k + 1 + (e >> 4), jc = e & 15;
                GbM[ii * 36 + jc] -= TM[k * 36 + ii] * TM[k * 36 + jc];
              }
              __syncthreads();
            }
            for (int e = tid; e < 64; e += 128) {   // T1 = R2*Gt -> TM+576
              const int jq = e & 3, k = e >> 2;
              float ax = 0.f, ay = 0.f, az = 0.f, aw = 0.f;
              const float4* Gt4 = (const float4*)(GbM + 576);
              for (int l = 0; l < 16; ++l) {
                const float r2 = TM[k * 36 + l];
                const float4 g = Gt4[l * 9 + jq];
                ax += r2 * g.x; ay += r2 * g.y; az += r2 * g.z; aw += r2 * g.w;
              }
              float4 o; o.x = ax; o.y = ay; o.z = az; o.w = aw;
              ((float4*)(TM + 576))[k * 9 + jq] = o;
            }
            __syncthreads();
            for (int e = tid; e < 256; e += 128) {  // H = T1*R2^T -> GM
              const int k2 = e & 15, k = e >> 4;
              float acc = 0.f;
              const float4* T14 = (const float4*)(TM + 576);
              const float4* R24 = (const float4*)TM;
              for (int lq = 0; lq < 4; ++lq) {
                const float4 t = T14[k * 9 + lq], r = R24[k2 * 9 + lq];
                acc += t.x * r.x + t.y * r.y + t.z * r.z + t.w * r.w;
              }
              GM[k * 36 + k2] = acc;
            }
            __syncthreads();
            jacobi_pb<16>(GM, TM + 576, tid);
          }

          // ---- top-cb selection + scales ----
          const int N = (path == 2) ? 4 : ((path == 1) ? 16 : p);
          if (tid < 64) {
            float v_ = (tid < N) ? GM[tid * 37] : -3.0e38f;
            int ix = tid;
            for (int t = 0; t < cb; ++t) {
              float bv = v_; int bi = ix;
              for (int mk = 32; mk; mk >>= 1) {
                const float ov = __shfl_xor(bv, mk);
                const int oi = __shfl_xor(bi, mk);
                if (ov > bv || (ov == bv && oi < bi)) { bv = ov; bi = oi; }
              }
              if (tid == 0) isel[t] = bi;
              if (ix == bi) v_ = -3.0e38f;
            }
          }
          __syncthreads();
          if (tid < cb) {
            const float lam = GM[isel[tid] * 37];
            const float s_ = sqrtf(fmaxf(lam, 0.0f));
            sinvv[tid] = 1.0f / sqrtf(s_ + 1e-12f);
            sdiv[tid]  = 1.0f / fmaxf(s_, 1e-25f);
          }
          __syncthreads();

          // ---- projectors ----
          if (path == 0) {
            // Pu = mt^T U sinv ; Pd = Gb Pu / s   (U cols in TM)
            for (int e = tid; e < m * cb; e += 128) {
              const int k = e & (cb - 1), mrow = e >> cblog;
              const int a = isel[k];
              float acc = 0.f;
              for (int pr = 0; pr < p; ++pr) acc += CUR[pr * 36 + mrow] * TM[pr * 36 + a];
              PuL[mrow * 8 + k] = acc * sinvv[k];
            }
            __syncthreads();
            for (int e = tid; e < m * cb; e += 128) {
              const int k = e & (cb - 1), mrow = e >> cblog;
              float acc = 0.f;
              for (int l = 0; l < m; ++l) acc += GbM[mrow * 36 + l] * PuL[l * 8 + k];
              PdL[mrow * 8 + k] = acc * sdiv[k];
            }
            __syncthreads();
          } else if (path == 2) {
            // Pd = mb V sinv ; Pu = Gt Pd / s   (V in TM+576, Gt in GbM)
            for (int e = tid; e < m * cb; e += 128) {
              const int k = e & (cb - 1), mrow = e >> cblog;
              const int a = isel[k];
              float acc = 0.f;
              for (int r = 0; r < 4; ++r) acc += BIGT[r * 36 + mrow] * TM[576 + r * 36 + a];
              PdL[mrow * 8 + k] = acc * sinvv[k];
            }
            __syncthreads();
            for (int e = tid; e < m * cb; e += 128) {
              const int k = e & (cb - 1), mrow = e >> cblog;
              float acc = 0.f;
              for (int l = 0; l < m; ++l) acc += GbM[mrow * 36 + l] * PdL[l * 8 + k];
              PuL[mrow * 8 + k] = acc * sdiv[k];
            }
            __syncthreads();
          } else {
            // Pd = R2^T V sinv ; Pu = Gt Pd / s  (R2 in TM[0:576], V in TM+576, Gt in GbM+576)
            for (int e = tid; e < m * cb; e += 128) {
              const int k = e & (cb - 1), mrow = e >> cblog;
              const int a = isel[k];
              float acc = 0.f;
              for (int t = 0; t < 16; ++t) acc += TM[t * 36 + mrow] * TM[576 + t * 36 + a];
              PdL[mrow * 8 + k] = acc * sinvv[k];
            }
            __syncthreads();
            for (int e = tid; e < m * cb; e += 128) {
              const int k = e & (cb - 1), mrow = e >> cblog;
              float acc = 0.f;
              for (int l = 0; l < m; ++l) acc += GbM[576 + mrow * 36 + l] * PdL[l * 8 + k];
              PuL[mrow * 8 + k] = acc * sdiv[k];
            }
            __syncthreads();
          }
          // store perturbed projectors (ws slot preloaded with ETA*mlp)
          for (int e = tid; e < m * cb; e += 128)
            projb[e] += PdL[(e >> cblog) * 8 + (e & (cb - 1))];
          for (int e = tid; e < m * cb; e += 128)
            projb[m * cb + e] += PuL[(e >> cblog) * 8 + (e & (cb - 1))];
        } else {
          // ---- sweep 2: load perturbed projectors + stage mb (B-half for two-pass) ----
          for (int e = tid; e < m * cb; e += 128)
            PdL[(e >> cblog) * 8 + (e & (cb - 1))] = projb[e];
          for (int e = tid; e < m * cb; e += 128)
            PuL[(e >> cblog) * 8 + (e & (cb - 1))] = projb[m * cb + e];
          __syncthreads();
          if (!two) absorb_T(Tg, pool + (i + 1) * 264, BIGT, ATile, xi, i + 1, j, U1, Dd1, 0, 4, tid);
          else      absorb_T(Tg, pool + (i + 1) * 264, BIGT, ATile, xi, i + 1, j, U1, Dd1, 2, 4, tid);
        }

        // ---- common: Bn[i] = Tt*Pd -> pool[i]; Bn[i+1] = Pu applied to mb -> CUR (or pool[5]) ----
        {
          const int nel = ucur * 4 * cb;
          const float4* C4 = (const float4*)CUR;
          for (int e = tid; e < nel; e += 128) {
            const int cc = e & (cb - 1);
            const int rr = (e >> cblog) & 3;
            const int u = e >> (cblog + 2);
            const int row = u * 4 + rr;
            float acc = 0.f;
            for (int mq = 0; mq < mq4; ++mq) {
              const float4 cv = C4[row * 9 + mq];
              acc += cv.x * PdL[(mq * 4 + 0) * 8 + cc] + cv.y * PdL[(mq * 4 + 1) * 8 + cc]
                   + cv.z * PdL[(mq * 4 + 2) * 8 + cc] + cv.w * PdL[(mq * 4 + 3) * 8 + cc];
            }
            pool[i * 264 + u * 33 + rr * 8 + cc] = acc;
          }
          __syncthreads();

          const int dnlog = 31 - __clz(dn);
          auto bn1 = [&](int rr0, int nloc) {
            const int ne2 = cb * nloc * dn;
            const float4* B4 = (const float4*)BIGT;
            for (int e = tid; e < ne2; e += 128) {
              const int dd = e & (dn - 1);
              const int t = e >> dnlog;
              const int rrL = t & (nloc - 1);
              const int cc = t >> ((nloc == 4) ? 2 : 1);
              const int row = rrL * dn + dd;
              float acc = 0.f;
              for (int mq = 0; mq < mq4; ++mq) {
                const float4 bv = B4[row * 9 + mq];
                acc += bv.x * PuL[(mq * 4 + 0) * 8 + cc] + bv.y * PuL[(mq * 4 + 1) * 8 + cc]
                     + bv.z * PuL[(mq * 4 + 2) * 8 + cc] + bv.w * PuL[(mq * 4 + 3) * 8 + cc];
              }
              if (i < 4) CUR[(cc * 4 + rr0 + rrL) * 36 + dd] = acc;
              else       pool[5 * 264 + cc * 33 + (rr0 + rrL) * 8] = acc;
            }
            __syncthreads();
          };
          if (!two) {
            bn1(0, 4);
          } else {
            bn1(2, 2);
            absorb_T(Tg, pool + (i + 1) * 264, BIGT, ATile, xi, i + 1, j, U1, Dd1, 0, 2, tid);
            bn1(0, 2);
          }
        }
      }
    }

    if (sweep == 1) {
      // ---- finalize: scalar = prod_i C_i ----
      if (tid == 0) vvec[0] = 1.0f;
      __syncthreads();
      for (int i = 0; i < 6; ++i) {
        const int ad = (i == 0) ? 1 : 4, bd = (i == 5) ? 1 : 4;
        const int adlog = (ad == 4) ? 2 : 0, bdlog = (bd == 4) ? 2 : 0;
        const int rows = g_ufin[i] * ad, cols = g_dfin[i] * bd;
        const int clog = 31 - __clz(cols);
        const int ph = xi[i * 6 + 5];
        const float* tb = Tg + (size_t)(i * 6 + 5) * 512;
        for (int e = tid; e < 256; e += 128) ATile[e] = tb[e * 2 + ph];
        __syncthreads();
        for (int e = tid; e < rows * cols; e += 128) {
          const int col = e & (cols - 1);
          const int ua = e >> clog;
          const int u = ua >> adlog, a = ua & (ad - 1);
          const int d_ = col >> bdlog, b = col & (bd - 1);
          const float* fb = pool + i * 264 + u * 33 + d_;
          const float4 av = *(const float4*)(ATile + a * 64 + b * 4);  // R = 0 slice
          GM[ua * 36 + col] = fb[0] * av.x + fb[8] * av.y + fb[16] * av.z + fb[24] * av.w;
        }
        __syncthreads();
        if (tid < cols) {
          float acc = 0.f;
          for (int r_ = 0; r_ < rows; ++r_) acc += vvec[r_] * GM[r_ * 36 + tid];
          vvec2[tid] = acc;
        }
        __syncthreads();
        if (tid < cols) vvec[tid] = vvec2[tid];
        __syncthreads();
      }
      if (tid == 0) out[s] = vvec[0];
    }
  }
}

extern "C" void kernel_launch(void* const* d_in, const int* in_sizes, int n_in,
                              void* d_out, int out_size, void* d_ws, size_t ws_size,
                              hipStream_t stream) {
  const float* Tg = (const float*)d_in[0];
  const float* W1 = (const float*)d_in[1];
  const float* b1 = (const float*)d_in[2];
  const float* W2 = (const float*)d_in[3];
  const float* b2 = (const float*)d_in[4];
  const int*   x  = (const int*)d_in[5];
  float* out = (float*)d_out;
  float* proj = (float*)d_ws;   // 1024*6400 floats: ETA*mlp then += projectors
  (void)in_sizes; (void)n_in; (void)out_size; (void)ws_size;

  mlp_kernel<<<dim3(128), dim3(256), 0, stream>>>(W1, b1, W2, b2, x, proj);
  peps_kernel<<<dim3(1024), dim3(128), 0, stream>>>(Tg, x, proj, out);
}

// Round 8
// 1808.739 us; speedup vs baseline: 3.6682x; 1.1730x over previous
//
#include <hip/hip_runtime.h>

// ---------------- static schedule tables ----------------
__device__ const int g_uprev[2][6] = {{1,4,4,4,4,4},{1,4,8,8,8,4}};
__device__ const int g_dprev[2][6] = {{4,4,4,4,4,1},{4,8,8,8,4,1}};
__device__ const int g_mtab[2][5]  = {{16,16,16,16,16},{16,32,32,32,16}};
__device__ const int g_cbtab[5]    = {4,8,8,8,4};
__device__ const int g_ucurtab[5]  = {1,4,8,8,8};
__device__ const int g_dntab[2][5] = {{16,16,16,16,1},{32,32,32,16,1}};
__device__ const int g_path[2][5]  = {{0,0,1,1,2},{0,0,0,0,2}};  // 0=p-side,1=m-side(chol),2=q-side
__device__ const int g_offtab[4][5]= {{0,128,384,640,896},
                                      {1024,1152,1664,2176,2688},
                                      {2816,2944,3456,3968,4480},
                                      {4608,4736,5248,5760,6272}};
__device__ const int g_ufin[6] = {1,4,8,8,8,4};
__device__ const int g_dfin[6] = {4,8,8,8,4,1};

// ============ kernel 1: proj[s][k] = ETA*mlp(x_s)[k] ============
__global__ __launch_bounds__(256) void mlp_kernel(
    const float* __restrict__ W1, const float* __restrict__ b1,
    const float* __restrict__ W2, const float* __restrict__ b2,
    const int* __restrict__ x, float* __restrict__ proj)
{
  __shared__ float hbuf[8][64];
  const int tid = threadIdx.x;
  const int s0 = blockIdx.x << 3;
  for (int e = tid; e < 512; e += 256) {
    const int sl = e >> 6, hh = e & 63;
    const int* xr = x + (s0 + sl) * 36;
    const float* wr = W1 + hh * 36;
    float acc = b1[hh];
    #pragma unroll
    for (int t = 0; t < 36; ++t) acc += wr[t] * (float)xr[t];
    hbuf[sl][hh] = fmaxf(acc, 0.0f);
  }
  __syncthreads();
  for (int k = tid; k < 6400; k += 256) {
    const float4* wr = (const float4*)(W2 + (size_t)k * 64);
    float acc[8];
    #pragma unroll
    for (int s2 = 0; s2 < 8; ++s2) acc[s2] = 0.0f;
    #pragma unroll
    for (int c = 0; c < 16; ++c) {
      const float4 w = wr[c];
      #pragma unroll
      for (int s2 = 0; s2 < 8; ++s2) {
        const float4 hv = ((const float4*)hbuf[s2])[c];
        acc[s2] += w.x * hv.x + w.y * hv.y + w.z * hv.z + w.w * hv.w;
      }
    }
    const float bb = b2[k];
    #pragma unroll
    for (int s2 = 0; s2 < 8; ++s2)
      proj[(size_t)(s0 + s2) * 6400 + k] = 0.001f * (acc[s2] + bb);
  }
}

// ---------------- rotation angle ----------------
__device__ __forceinline__ void jrot(float app, float aqq, float apq, float& c, float& sn) {
  c = 1.0f; sn = 0.0f;
  if (fabsf(apq) > 1e-36f + 1e-12f * (fabsf(app) + fabsf(aqq))) {
    const float tau = (aqq - app) / (2.0f * apq);
    const float t = copysignf(1.0f, tau) / (fabsf(tau) + sqrtf(1.0f + tau * tau));
    c = 1.0f / sqrtf(1.0f + t * t);
    sn = t * c;
  }
}

// pair-blocked two-sided Jacobi; H,V stride-36; diag -> eigenvalues; V columns = eigvecs.
// Tournament pairing maintained INCREMENTALLY in registers (a_{rd+1} = (a+1) mod (N-1),
// exactly periodic across sweeps). Lane's own column-pair angle needs no shfl; row-pair
// angles come from 2 shfls. Fixed sweeps 5/5/3.
template<int N>
__device__ void jacobi_pb(float* __restrict__ H, float* __restrict__ V, int tid)
{
  constexpr int NP = N / 2;
  constexpr int NM1 = N - 1;
  constexpr int NL = (N == 32) ? 5 : ((N == 16) ? 4 : 2);
  constexpr int NBMAX = (N == 32) ? 2 : 1;
  constexpr int NVMAX = (N == 32) ? 4 : 1;
  constexpr int MAXSW = (N == 32) ? 5 : ((N == 16) ? 5 : 3);
  for (int e = tid; e < N * N; e += 128) {
    const int r = e >> NL, c = e & (N - 1);
    V[r * 36 + c] = (r == c) ? 1.0f : 0.0f;
  }
  __syncthreads();
  const int cp = tid & (NP - 1);
  const bool hact = (N == 32) ? true : (tid < NP * NP);
  const bool vact = (N >= 16) ? true : (tid < N * NP);
  // incremental tournament state: col-pair (= this lane's angle pair)
  int ca  = (cp == 0) ? NM1 : cp;
  int cb2 = (cp == 0) ? 0 : (NM1 - cp);
  // row-pair states (garbage-but-unused on !hact lanes)
  int ra[NBMAX], rb[NBMAX], rt[NBMAX];
  #pragma unroll
  for (int bi = 0; bi < NBMAX; ++bi) {
    const int t = (N == 32) ? ((tid >> 4) + 8 * bi) : ((N == 16) ? (tid >> 3) : (tid >> 1));
    rt[bi] = t;
    const int tm = t % NM1;
    ra[bi] = (t == 0) ? NM1 : tm;
    rb[bi] = (t == 0) ? 0 : (NM1 - tm) % NM1;
  }
  for (int sw = 0; sw < MAXSW; ++sw) {
    for (int rd = 0; rd < NM1; ++rd) {
      const int q0 = (ca < cb2) ? ca : cb2;
      const int q1 = (ca < cb2) ? cb2 : ca;
      float cc_, cs_;
      jrot(H[q0 * 37], H[q1 * 37], H[q0 * 36 + q1], cc_, cs_);
      float o00[NBMAX], o01[NBMAX], o10[NBMAX], o11[NBMAX];
      int P0[NBMAX], P1[NBMAX];
      #pragma unroll
      for (int bi = 0; bi < NBMAX; ++bi) {
        if (bi == 0 && !hact) continue;
        const int p0 = (ra[bi] < rb[bi]) ? ra[bi] : rb[bi];
        const int p1 = (ra[bi] < rb[bi]) ? rb[bi] : ra[bi];
        const float cr_ = __shfl(cc_, rt[bi]);
        const float sr_ = __shfl(cs_, rt[bi]);
        const float a  = H[p0 * 36 + q0], b = H[p0 * 36 + q1];
        const float c2 = H[p1 * 36 + q0], d = H[p1 * 36 + q1];
        const float t1 = cr_ * a - sr_ * c2, t2 = cr_ * b - sr_ * d;
        const float u1 = sr_ * a + cr_ * c2, u2 = sr_ * b + cr_ * d;
        o00[bi] = cc_ * t1 - cs_ * t2; o01[bi] = cs_ * t1 + cc_ * t2;
        o10[bi] = cc_ * u1 - cs_ * u2; o11[bi] = cs_ * u1 + cc_ * u2;
        P0[bi] = p0; P1[bi] = p1;
      }
      float v0[NVMAX], v1[NVMAX];
      #pragma unroll
      for (int vi = 0; vi < NVMAX; ++vi) {
        if (vi == 0 && !vact) continue;
        const int row = (N == 32) ? ((tid >> 4) + 8 * vi) : ((N == 16) ? (tid >> 3) : (tid >> 1));
        const float a0 = V[row * 36 + q0], a1 = V[row * 36 + q1];
        v0[vi] = cc_ * a0 - cs_ * a1; v1[vi] = cs_ * a0 + cc_ * a1;
      }
      __syncthreads();
      #pragma unroll
      for (int bi = 0; bi < NBMAX; ++bi) {
        if (bi == 0 && !hact) continue;
        H[P0[bi] * 36 + q0] = o00[bi]; H[P0[bi] * 36 + q1] = o01[bi];
        H[P1[bi] * 36 + q0] = o10[bi]; H[P1[bi] * 36 + q1] = o11[bi];
      }
      #pragma unroll
      for (int vi = 0; vi < NVMAX; ++vi) {
        if (vi == 0 && !vact) continue;
        const int row = (N == 32) ? ((tid >> 4) + 8 * vi) : ((N == 16) ? (tid >> 3) : (tid >> 1));
        V[row * 36 + q0] = v0[vi]; V[row * 36 + q1] = v1[vi];
      }
      __syncthreads();
      // advance tournament (periodic mod NM1; seat 0 keeps partner NM1)
      ca  = (cp == 0) ? NM1 : ((ca + 1 == NM1) ? 0 : ca + 1);
      cb2 = (cb2 + 1 == NM1) ? 0 : cb2 + 1;
      #pragma unroll
      for (int bi = 0; bi < NBMAX; ++bi) {
        ra[bi] = (rt[bi] == 0) ? NM1 : ((ra[bi] + 1 == NM1) ? 0 : ra[bi] + 1);
        rb[bi] = (rb[bi] + 1 == NM1) ? 0 : rb[bi] + 1;
      }
    }
  }
}

// G(+)= A^T A over 'nrows' stride-36 rows of A, mcols in {16,32}; float4 on column quads
__device__ __forceinline__ void gram_cols(float* __restrict__ G, const float* __restrict__ A,
                                          int nrows, int mcols, bool init, int tid)
{
  const int q4 = mcols >> 2;
  const int q4log = (mcols == 32) ? 3 : 2;
  const int nel = mcols * q4;
  const float4* A4 = (const float4*)A;
  float4* G4 = (float4*)G;
  for (int e = tid; e < nel; e += 128) {
    const int c2q = e & (q4 - 1);
    const int c1 = e >> q4log;
    float ax = 0.f, ay = 0.f, az = 0.f, aw = 0.f;
    for (int r = 0; r < nrows; ++r) {
      const float a1 = A[r * 36 + c1];
      const float4 a2 = A4[r * 9 + c2q];
      ax += a1 * a2.x; ay += a1 * a2.y; az += a1 * a2.z; aw += a1 * a2.w;
    }
    float4* gp = G4 + c1 * 9 + c2q;
    if (init) { float4 o; o.x = ax; o.y = ay; o.z = az; o.w = aw; *gp = o; }
    else { float4 o = *gp; o.x += ax; o.y += ay; o.z += az; o.w += aw; *gp = o; }
  }
  __syncthreads();
}

// absorb column i1 of row j into BIGT[(rr-rr0)*dbw+db][ua] (stride 36), rr in [rr0,rr1)
__device__ __forceinline__ void absorb_T(const float* __restrict__ Tg, const float* __restrict__ poolS,
    float* __restrict__ BIGT, float* __restrict__ ATile, const int* __restrict__ xi,
    int i1, int j, int U, int Dd, int rr0, int rr1, int tid)
{
  const int bd = (i1 == 5) ? 1 : 4;
  const int dbw = Dd * bd;
  const int mt_ = U * 4;
  const int ph = xi[i1 * 6 + j];
  const float* tb = Tg + (size_t)(i1 * 6 + j) * 512;
  for (int e = tid; e < 256; e += 128) ATile[e] = tb[e * 2 + ph];
  __syncthreads();
  const int mlog = (mt_ == 32) ? 5 : 4;
  const int dblog = 31 - __clz(dbw);
  const int bdlog = (bd == 4) ? 2 : 0;
  const int nel = mt_ * dbw * (rr1 - rr0);
  for (int e = tid; e < nel; e += 128) {
    const int ua = e & (mt_ - 1);
    const int db = (e >> mlog) & (dbw - 1);
    const int rr = rr0 + (e >> (mlog + dblog));
    const int u = ua >> 2, a = ua & 3;
    const int d_ = db >> bdlog, b = db & (bd - 1);
    const float* op = poolS + u * 33 + d_;
    const float4 av = *(const float4*)(ATile + a * 64 + rr * 16 + b * 4);
    BIGT[((rr - rr0) * dbw + db) * 36 + ua] = op[0] * av.x + op[8] * av.y + op[16] * av.z + op[24] * av.w;
  }
  __syncthreads();
}

// ============ kernel 2: one sample per 128-thread workgroup ============
__global__ __launch_bounds__(128, 2) void peps_kernel(
    const float* __restrict__ Tg, const int* __restrict__ x,
    float* __restrict__ proj, float* __restrict__ out)
{
  __shared__ float pool[6 * 264];   // [i][u<=8 stride33][x=4 stride8][d<=8]
  __shared__ float CUR[1152];       // mt: rows (u*4+rr)<=32, stride 36
  __shared__ float BIGT[2304];      // mb^T half: rows (rr*dbw+db)<=64 stride 36
  __shared__ float GbM[1152];       // Gb (or Gt for q-path); m-path: Gb@0, Gt@576
  __shared__ float TM[1152];        // T / R2@0+T1@576 / eigvecs V
  __shared__ float GM[1152];        // G / H (diagonalized in place)
  __shared__ float ATile[256];
  __shared__ float PdL[256], PuL[256];  // [mrow][8]
  __shared__ float red[4];
  __shared__ int isel[8];
  __shared__ float sinvv[8], sdiv[8];
  __shared__ int xi[36];
  __shared__ float vvec[36], vvec2[36];

  const int s = blockIdx.x;
  const int tid = threadIdx.x;
  if (tid < 36) xi[tid] = x[s * 36 + tid];
  __syncthreads();

  for (int sweep = 0; sweep < 2; ++sweep) {
    // --- init boundary MPS from row j=0 ---
    for (int i2 = 0; i2 < 6; ++i2) {
      const int ad = (i2 == 0) ? 1 : 4, bd = (i2 == 5) ? 1 : 4;
      const int bdlog = (bd == 4) ? 2 : 0;
      const int ph = xi[i2 * 6];
      const float* tb = Tg + (size_t)(i2 * 6) * 512;
      const int nel = ad * 4 * bd;
      for (int e = tid; e < nel; e += 128) {
        const int b = e & (bd - 1);
        const int rr = (e >> bdlog) & 3;
        const int a = e >> (bdlog + 2);
        pool[i2 * 264 + a * 33 + rr * 8 + b] = tb[(a * 64 + rr * 16 + b * 4) * 2 + ph];
      }
    }
    __syncthreads();

    for (int j = 1; j <= 4; ++j) {
      const int jj = (j > 1) ? 1 : 0;
      // absorb column 0 into CUR (4 rows x 16 cols)
      {
        const int ph = xi[j];          // site (0,j)
        const float* tb = Tg + (size_t)j * 512;
        for (int e = tid; e < 256; e += 128) ATile[e] = tb[e * 2 + ph];
        __syncthreads();
        for (int e = tid; e < 64; e += 128) {
          const int db = e & 15;
          const int rr = e >> 4;
          const int d_ = db >> 2, b = db & 3;
          const float* op = pool + d_;  // slot 0, u=0
          const float4 av = *(const float4*)(ATile + rr * 16 + b * 4);  // a=0
          CUR[rr * 36 + db] = op[0] * av.x + op[8] * av.y + op[16] * av.z + op[24] * av.w;
        }
        __syncthreads();
      }

      for (int i = 0; i < 5; ++i) {
        const int m = g_mtab[jj][i], cb = g_cbtab[i], ucur = g_ucurtab[i], dn = g_dntab[jj][i];
        const int p = ucur * 4, path = g_path[jj][i];
        const int U1 = g_uprev[jj][i + 1], Dd1 = g_dprev[jj][i + 1];
        const bool two = (dn == 32);
        const int cblog = (cb == 8) ? 3 : 2;
        const int mq4 = m >> 2;
        float* projb = proj + (size_t)s * 6400 + g_offtab[j - 1][i];

        if (sweep == 0) {
          if (path == 2) {
            // ---- q-side (i=4): G = mb^T Gt mb (4x4) ----
            absorb_T(Tg, pool + (i + 1) * 264, BIGT, ATile, xi, i + 1, j, U1, Dd1, 0, 4, tid);
            gram_cols(GbM, CUR, p, m, true, tid);   // Gt (16x16)
            for (int e = tid; e < 64; e += 128) {   // T1 = Gt*mb (16x4)
              const int r = e & 3, k = e >> 2;
              float acc = 0.f;
              const float4* G4 = (const float4*)GbM;
              const float4* B4 = (const float4*)BIGT;
              for (int lq = 0; lq < 4; ++lq) {
                const float4 g = G4[k * 9 + lq], b = B4[r * 9 + lq];
                acc += g.x * b.x + g.y * b.y + g.z * b.z + g.w * b.w;
              }
              TM[k * 36 + r] = acc;
            }
            __syncthreads();
            for (int e = tid; e < 16; e += 128) {   // G = mb^T * T1 (4x4)
              const int c = e & 3, r = e >> 2;
              float acc = 0.f;
              for (int k = 0; k < 16; ++k) acc += BIGT[r * 36 + k] * TM[k * 36 + c];
              GM[r * 36 + c] = acc;
            }
            __syncthreads();
            jacobi_pb<4>(GM, TM + 576, tid);
          } else if (path == 0) {
            // ---- p-side: G = mt Gb mt^T (p x p), no Cholesky ----
            if (!two) {
              absorb_T(Tg, pool + (i + 1) * 264, BIGT, ATile, xi, i + 1, j, U1, Dd1, 0, 4, tid);
              gram_cols(GbM, BIGT, 4 * dn, m, true, tid);
            } else {
              absorb_T(Tg, pool + (i + 1) * 264, BIGT, ATile, xi, i + 1, j, U1, Dd1, 0, 2, tid);
              gram_cols(GbM, BIGT, 2 * dn, m, true, tid);
              absorb_T(Tg, pool + (i + 1) * 264, BIGT, ATile, xi, i + 1, j, U1, Dd1, 2, 4, tid);
              gram_cols(GbM, BIGT, 2 * dn, m, false, tid);
            }
            const int q4log = (m == 32) ? 3 : 2;
            for (int e = tid; e < p * mq4; e += 128) {  // T = mt*Gb (p x m)
              const int lq = e & (mq4 - 1), pr = e >> q4log;
              float ax = 0.f, ay = 0.f, az = 0.f, aw = 0.f;
              const float4* G4 = (const float4*)GbM;
              for (int k = 0; k < m; ++k) {
                const float a1 = CUR[pr * 36 + k];
                const float4 g = G4[k * 9 + lq];
                ax += a1 * g.x; ay += a1 * g.y; az += a1 * g.z; aw += a1 * g.w;
              }
              float4 o; o.x = ax; o.y = ay; o.z = az; o.w = aw;
              ((float4*)TM)[pr * 9 + lq] = o;
            }
            __syncthreads();
            const int plog = (p == 32) ? 5 : ((p == 16) ? 4 : 2);
            for (int e = tid; e < p * p; e += 128) {    // G = T*mt^T (p x p)
              const int pc = e & (p - 1), pr = e >> plog;
              float acc = 0.f;
              const float4* T4 = (const float4*)TM;
              const float4* C4 = (const float4*)CUR;
              for (int lq = 0; lq < mq4; ++lq) {
                const float4 t = T4[pr * 9 + lq], c = C4[pc * 9 + lq];
                acc += t.x * c.x + t.y * c.y + t.z * c.z + t.w * c.w;
              }
              GM[pr * 36 + pc] = acc;
            }
            __syncthreads();
            if (p == 4)       jacobi_pb<4>(GM, TM, tid);
            else if (p == 16) jacobi_pb<16>(GM, TM, tid);
            else              jacobi_pb<32>(GM, TM, tid);
          } else {
            // ---- m-side (jj0 i=2,3): Gt, Gb, chol(Gb), H = R2 Gt R2^T (16x16) ----
            absorb_T(Tg, pool + (i + 1) * 264, BIGT, ATile, xi, i + 1, j, U1, Dd1, 0, 4, tid);
            gram_cols(GbM + 576, CUR, p, m, true, tid);     // Gt
            gram_cols(GbM, BIGT, 4 * dn, m, true, tid);     // Gb
            // cholesky Gb -> R2 (TM[0:576]) with zero-skip
            if (tid < 64) {
              float v_ = (tid < 16) ? GbM[tid * 37] : -3.0e38f;
              for (int mk = 32; mk; mk >>= 1) v_ = fmaxf(v_, __shfl_xor(v_, mk));
              if (tid == 0) red[0] = v_;
            }
            __syncthreads();
            const float thr = 1e-10f * red[0] + 1e-35f;
            for (int k = 0; k < 16; ++k) {
              const float dk = GbM[k * 37];
              const float rs = (dk > thr) ? (1.0f / sqrtf(dk)) : 0.0f;
              if (tid < 16) TM[k * 36 + tid] = GbM[k * 36 + tid] * rs;
              __syncthreads();
              const int rows = 15 - k;
              for (int e = tid; e < rows * 16; e += 128) {
                const int ii = k + 1 + (e >> 4), jc = e & 15;
                GbM[ii * 36 + jc] -= TM[k * 36 + ii] * TM[k * 36 + jc];
              }
              __syncthreads();
            }
            for (int e = tid; e < 64; e += 128) {   // T1 = R2*Gt -> TM+576
              const int jq = e & 3, k = e >> 2;
              float ax = 0.f, ay = 0.f, az = 0.f, aw = 0.f;
              const float4* Gt4 = (const float4*)(GbM + 576);
              for (int l = 0; l < 16; ++l) {
                const float r2 = TM[k * 36 + l];
                const float4 g = Gt4[l * 9 + jq];
                ax += r2 * g.x; ay += r2 * g.y; az += r2 * g.z; aw += r2 * g.w;
              }
              float4 o; o.x = ax; o.y = ay; o.z = az; o.w = aw;
              ((float4*)(TM + 576))[k * 9 + jq] = o;
            }
            __syncthreads();
            for (int e = tid; e < 256; e += 128) {  // H = T1*R2^T -> GM
              const int k2 = e & 15, k = e >> 4;
              float acc = 0.f;
              const float4* T14 = (const float4*)(TM + 576);
              const float4* R24 = (const float4*)TM;
              for (int lq = 0; lq < 4; ++lq) {
                const float4 t = T14[k * 9 + lq], r = R24[k2 * 9 + lq];
                acc += t.x * r.x + t.y * r.y + t.z * r.z + t.w * r.w;
              }
              GM[k * 36 + k2] = acc;
            }
            __syncthreads();
            jacobi_pb<16>(GM, TM + 576, tid);
          }

          // ---- top-cb selection + scales ----
          const int N = (path == 2) ? 4 : ((path == 1) ? 16 : p);
          if (tid < 64) {
            float v_ = (tid < N) ? GM[tid * 37] : -3.0e38f;
            int ix = tid;
            for (int t = 0; t < cb; ++t) {
              float bv = v_; int bi = ix;
              for (int mk = 32; mk; mk >>= 1) {
                const float ov = __shfl_xor(bv, mk);
                const int oi = __shfl_xor(bi, mk);
                if (ov > bv || (ov == bv && oi < bi)) { bv = ov; bi = oi; }
              }
              if (tid == 0) isel[t] = bi;
              if (ix == bi) v_ = -3.0e38f;
            }
          }
          __syncthreads();
          if (tid < cb) {
            const float lam = GM[isel[tid] * 37];
            const float s_ = sqrtf(fmaxf(lam, 0.0f));
            sinvv[tid] = 1.0f / sqrtf(s_ + 1e-12f);
            sdiv[tid]  = 1.0f / fmaxf(s_, 1e-25f);
          }
          __syncthreads();

          // ---- projectors ----
          if (path == 0) {
            // Pu = mt^T U sinv ; Pd = Gb Pu / s   (U cols in TM)
            for (int e = tid; e < m * cb; e += 128) {
              const int k = e & (cb - 1), mrow = e >> cblog;
              const int a = isel[k];
              float acc = 0.f;
              for (int pr = 0; pr < p; ++pr) acc += CUR[pr * 36 + mrow] * TM[pr * 36 + a];
              PuL[mrow * 8 + k] = acc * sinvv[k];
            }
            __syncthreads();
            for (int e = tid; e < m * cb; e += 128) {
              const int k = e & (cb - 1), mrow = e >> cblog;
              float acc = 0.f;
              for (int l = 0; l < m; ++l) acc += GbM[mrow * 36 + l] * PuL[l * 8 + k];
              PdL[mrow * 8 + k] = acc * sdiv[k];
            }
            __syncthreads();
          } else if (path == 2) {
            // Pd = mb V sinv ; Pu = Gt Pd / s   (V in TM+576, Gt in GbM)
            for (int e = tid; e < m * cb; e += 128) {
              const int k = e & (cb - 1), mrow = e >> cblog;
              const int a = isel[k];
              float acc = 0.f;
              for (int r = 0; r < 4; ++r) acc += BIGT[r * 36 + mrow] * TM[576 + r * 36 + a];
              PdL[mrow * 8 + k] = acc * sinvv[k];
            }
            __syncthreads();
            for (int e = tid; e < m * cb; e += 128) {
              const int k = e & (cb - 1), mrow = e >> cblog;
              float acc = 0.f;
              for (int l = 0; l < m; ++l) acc += GbM[mrow * 36 + l] * PdL[l * 8 + k];
              PuL[mrow * 8 + k] = acc * sdiv[k];
            }
            __syncthreads();
          } else {
            // Pd = R2^T V sinv ; Pu = Gt Pd / s  (R2 in TM[0:576], V in TM+576, Gt in GbM+576)
            for (int e = tid; e < m * cb; e += 128) {
              const int k = e & (cb - 1), mrow = e >> cblog;
              const int a = isel[k];
              float acc = 0.f;
              for (int t = 0; t < 16; ++t) acc += TM[t * 36 + mrow] * TM[576 + t * 36 + a];
              PdL[mrow * 8 + k] = acc * sinvv[k];
            }
            __syncthreads();
            for (int e = tid; e < m * cb; e += 128) {
              const int k = e & (cb - 1), mrow = e >> cblog;
              float acc = 0.f;
              for (int l = 0; l < m; ++l) acc += GbM[576 + mrow * 36 + l] * PdL[l * 8 + k];
              PuL[mrow * 8 + k] = acc * sdiv[k];
            }
            __syncthreads();
          }
          // store perturbed projectors (ws slot preloaded with ETA*mlp)
          for (int e = tid; e < m * cb; e += 128)
            projb[e] += PdL[(e >> cblog) * 8 + (e & (cb - 1))];
          for (int e = tid; e < m * cb; e += 128)
            projb[m * cb + e] += PuL[(e >> cblog) * 8 + (e & (cb - 1))];
        } else {
          // ---- sweep 2: load perturbed projectors + stage mb (B-half for two-pass) ----
          for (int e = tid; e < m * cb; e += 128)
            PdL[(e >> cblog) * 8 + (e & (cb - 1))] = projb[e];
          for (int e = tid; e < m * cb; e += 128)
            PuL[(e >> cblog) * 8 + (e & (cb - 1))] = projb[m * cb + e];
          __syncthreads();
          if (!two) absorb_T(Tg, pool + (i + 1) * 264, BIGT, ATile, xi, i + 1, j, U1, Dd1, 0, 4, tid);
          else      absorb_T(Tg, pool + (i + 1) * 264, BIGT, ATile, xi, i + 1, j, U1, Dd1, 2, 4, tid);
        }

        // ---- common: Bn[i] = Tt*Pd -> pool[i]; Bn[i+1] = Pu applied to mb -> CUR (or pool[5]) ----
        {
          const int nel = ucur * 4 * cb;
          const float4* C4 = (const float4*)CUR;
          for (int e = tid; e < nel; e += 128) {
            const int cc = e & (cb - 1);
            const int rr = (e >> cblog) & 3;
            const int u = e >> (cblog + 2);
            const int row = u * 4 + rr;
            float acc = 0.f;
            for (int mq = 0; mq < mq4; ++mq) {
              const float4 cv = C4[row * 9 + mq];
              acc += cv.x * PdL[(mq * 4 + 0) * 8 + cc] + cv.y * PdL[(mq * 4 + 1) * 8 + cc]
                   + cv.z * PdL[(mq * 4 + 2) * 8 + cc] + cv.w * PdL[(mq * 4 + 3) * 8 + cc];
            }
            pool[i * 264 + u * 33 + rr * 8 + cc] = acc;
          }
          __syncthreads();

          const int dnlog = 31 - __clz(dn);
          auto bn1 = [&](int rr0, int nloc) {
            const int ne2 = cb * nloc * dn;
            const float4* B4 = (const float4*)BIGT;
            for (int e = tid; e < ne2; e += 128) {
              const int dd = e & (dn - 1);
              const int t = e >> dnlog;
              const int rrL = t & (nloc - 1);
              const int cc = t >> ((nloc == 4) ? 2 : 1);
              const int row = rrL * dn + dd;
              float acc = 0.f;
              for (int mq = 0; mq < mq4; ++mq) {
                const float4 bv = B4[row * 9 + mq];
                acc += bv.x * PuL[(mq * 4 + 0) * 8 + cc] + bv.y * PuL[(mq * 4 + 1) * 8 + cc]
                     + bv.z * PuL[(mq * 4 + 2) * 8 + cc] + bv.w * PuL[(mq * 4 + 3) * 8 + cc];
              }
              if (i < 4) CUR[(cc * 4 + rr0 + rrL) * 36 + dd] = acc;
              else       pool[5 * 264 + cc * 33 + (rr0 + rrL) * 8] = acc;
            }
            __syncthreads();
          };
          if (!two) {
            bn1(0, 4);
          } else {
            bn1(2, 2);
            absorb_T(Tg, pool + (i + 1) * 264, BIGT, ATile, xi, i + 1, j, U1, Dd1, 0, 2, tid);
            bn1(0, 2);
          }
        }
      }
    }

    if (sweep == 1) {
      // ---- finalize: scalar = prod_i C_i ----
      if (tid == 0) vvec[0] = 1.0f;
      __syncthreads();
      for (int i = 0; i < 6; ++i) {
        const int ad = (i == 0) ? 1 : 4, bd = (i == 5) ? 1 : 4;
        const int adlog = (ad == 4) ? 2 : 0, bdlog = (bd == 4) ? 2 : 0;
        const int rows = g_ufin[i] * ad, cols = g_dfin[i] * bd;
        const int clog = 31 - __clz(cols);
        const int ph = xi[i * 6 + 5];
        const float* tb = Tg + (size_t)(i * 6 + 5) * 512;
        for (int e = tid; e < 256; e += 128) ATile[e] = tb[e * 2 + ph];
        __syncthreads();
        for (int e = tid; e < rows * cols; e += 128) {
          const int col = e & (cols - 1);
          const int ua = e >> clog;
          const int u = ua >> adlog, a = ua & (ad - 1);
          const int d_ = col >> bdlog, b = col & (bd - 1);
          const float* fb = pool + i * 264 + u * 33 + d_;
          const float4 av = *(const float4*)(ATile + a * 64 + b * 4);  // R = 0 slice
          GM[ua * 36 + col] = fb[0] * av.x + fb[8] * av.y + fb[16] * av.z + fb[24] * av.w;
        }
        __syncthreads();
        if (tid < cols) {
          float acc = 0.f;
          for (int r_ = 0; r_ < rows; ++r_) acc += vvec[r_] * GM[r_ * 36 + tid];
          vvec2[tid] = acc;
        }
        __syncthreads();
        if (tid < cols) vvec[tid] = vvec2[tid];
        __syncthreads();
      }
      if (tid == 0) out[s] = vvec[0];
    }
  }
}

extern "C" void kernel_launch(void* const* d_in, const int* in_sizes, int n_in,
                              void* d_out, int out_size, void* d_ws, size_t ws_size,
                              hipStream_t stream) {
  const float* Tg = (const float*)d_in[0];
  const float* W1 = (const float*)d_in[1];
  const float* b1 = (const float*)d_in[2];
  const float* W2 = (const float*)d_in[3];
  const float* b2 = (const float*)d_in[4];
  const int*   x  = (const int*)d_in[5];
  float* out = (float*)d_out;
  float* proj = (float*)d_ws;   // 1024*6400 floats: ETA*mlp then += projectors
  (void)in_sizes; (void)n_in; (void)out_size; (void)ws_size;

  mlp_kernel<<<dim3(128), dim3(256), 0, stream>>>(W1, b1, W2, b2, x, proj);
  peps_kernel<<<dim3(1024), dim3(128), 0, stream>>>(Tg, x, proj, out);
}

// Round 10
// 1612.484 us; speedup vs baseline: 4.1147x; 1.1217x over previous
//
#include <hip/hip_runtime.h>

// ---------------- static schedule tables ----------------
__device__ const int g_uprev[2][6] = {{1,4,4,4,4,4},{1,4,8,8,8,4}};
__device__ const int g_dprev[2][6] = {{4,4,4,4,4,1},{4,8,8,8,4,1}};
__device__ const int g_mtab[2][5]  = {{16,16,16,16,16},{16,32,32,32,16}};
__device__ const int g_cbtab[5]    = {4,8,8,8,4};
__device__ const int g_ucurtab[5]  = {1,4,8,8,8};
__device__ const int g_dntab[2][5] = {{16,16,16,16,1},{32,32,32,16,1}};
__device__ const int g_path[2][5]  = {{0,0,1,1,2},{0,0,0,0,2}};  // 0=p-side,1=m-side(chol),2=q-side
__device__ const int g_offtab[4][5]= {{0,128,384,640,896},
                                      {1024,1152,1664,2176,2688},
                                      {2816,2944,3456,3968,4480},
                                      {4608,4736,5248,5760,6272}};
__device__ const int g_ufin[6] = {1,4,8,8,8,4};
__device__ const int g_dfin[6] = {4,8,8,8,4,1};

// ============ kernel 1: proj[s][k] = ETA*mlp(x_s)[k] ============
__global__ __launch_bounds__(256) void mlp_kernel(
    const float* __restrict__ W1, const float* __restrict__ b1,
    const float* __restrict__ W2, const float* __restrict__ b2,
    const int* __restrict__ x, float* __restrict__ proj)
{
  __shared__ float hbuf[8][64];
  const int tid = threadIdx.x;
  const int s0 = blockIdx.x << 3;
  for (int e = tid; e < 512; e += 256) {
    const int sl = e >> 6, hh = e & 63;
    const int* xr = x + (s0 + sl) * 36;
    const float* wr = W1 + hh * 36;
    float acc = b1[hh];
    #pragma unroll
    for (int t = 0; t < 36; ++t) acc += wr[t] * (float)xr[t];
    hbuf[sl][hh] = fmaxf(acc, 0.0f);
  }
  __syncthreads();
  for (int k = tid; k < 6400; k += 256) {
    const float4* wr = (const float4*)(W2 + (size_t)k * 64);
    float acc[8];
    #pragma unroll
    for (int s2 = 0; s2 < 8; ++s2) acc[s2] = 0.0f;
    #pragma unroll
    for (int c = 0; c < 16; ++c) {
      const float4 w = wr[c];
      #pragma unroll
      for (int s2 = 0; s2 < 8; ++s2) {
        const float4 hv = ((const float4*)hbuf[s2])[c];
        acc[s2] += w.x * hv.x + w.y * hv.y + w.z * hv.z + w.w * hv.w;
      }
    }
    const float bb = b2[k];
    #pragma unroll
    for (int s2 = 0; s2 < 8; ++s2)
      proj[(size_t)(s0 + s2) * 6400 + k] = 0.001f * (acc[s2] + bb);
  }
}

// ---------------- rotation angle (HW-approx rcp/rsq/sqrt: v_rcp_f32 etc., ~1ulp) ----------------
__device__ __forceinline__ void jrot(float app, float aqq, float apq, float& c, float& sn) {
  c = 1.0f; sn = 0.0f;
  if (fabsf(apq) > 1e-36f + 1e-12f * (fabsf(app) + fabsf(aqq))) {
    const float tau = (aqq - app) * 0.5f * __builtin_amdgcn_rcpf(apq);
    const float t = copysignf(1.0f, tau) *
                    __builtin_amdgcn_rcpf(fabsf(tau) + __builtin_amdgcn_sqrtf(1.0f + tau * tau));
    c = __builtin_amdgcn_rsqf(1.0f + t * t);
    sn = t * c;
  }
}

// pair-blocked two-sided Jacobi; H,V stride-36; diag -> eigenvalues; V columns = eigvecs.
// Tournament pairing maintained INCREMENTALLY in registers (a_{rd+1} = (a+1) mod (N-1),
// exactly periodic across sweeps). Lane's own column-pair angle needs no shfl; row-pair
// angles come from 2 shfls. Fixed sweeps 5/5/3 (4 sweeps measured insufficient — R9 fail).
template<int N>
__device__ void jacobi_pb(float* __restrict__ H, float* __restrict__ V, int tid)
{
  constexpr int NP = N / 2;
  constexpr int NM1 = N - 1;
  constexpr int NL = (N == 32) ? 5 : ((N == 16) ? 4 : 2);
  constexpr int NBMAX = (N == 32) ? 2 : 1;
  constexpr int NVMAX = (N == 32) ? 4 : 1;
  constexpr int MAXSW = (N == 32) ? 5 : ((N == 16) ? 5 : 3);
  for (int e = tid; e < N * N; e += 128) {
    const int r = e >> NL, c = e & (N - 1);
    V[r * 36 + c] = (r == c) ? 1.0f : 0.0f;
  }
  __syncthreads();
  const int cp = tid & (NP - 1);
  const bool hact = (N == 32) ? true : (tid < NP * NP);
  const bool vact = (N >= 16) ? true : (tid < N * NP);
  // incremental tournament state: col-pair (= this lane's angle pair)
  int ca  = (cp == 0) ? NM1 : cp;
  int cb2 = (cp == 0) ? 0 : (NM1 - cp);
  // row-pair states (garbage-but-unused on !hact lanes)
  int ra[NBMAX], rb[NBMAX], rt[NBMAX];
  #pragma unroll
  for (int bi = 0; bi < NBMAX; ++bi) {
    const int t = (N == 32) ? ((tid >> 4) + 8 * bi) : ((N == 16) ? (tid >> 3) : (tid >> 1));
    rt[bi] = t;
    const int tm = t % NM1;
    ra[bi] = (t == 0) ? NM1 : tm;
    rb[bi] = (t == 0) ? 0 : (NM1 - tm) % NM1;
  }
  for (int sw = 0; sw < MAXSW; ++sw) {
    for (int rd = 0; rd < NM1; ++rd) {
      const int q0 = (ca < cb2) ? ca : cb2;
      const int q1 = (ca < cb2) ? cb2 : ca;
      float cc_, cs_;
      jrot(H[q0 * 37], H[q1 * 37], H[q0 * 36 + q1], cc_, cs_);
      float o00[NBMAX], o01[NBMAX], o10[NBMAX], o11[NBMAX];
      int P0[NBMAX], P1[NBMAX];
      #pragma unroll
      for (int bi = 0; bi < NBMAX; ++bi) {
        if (bi == 0 && !hact) continue;
        const int p0 = (ra[bi] < rb[bi]) ? ra[bi] : rb[bi];
        const int p1 = (ra[bi] < rb[bi]) ? rb[bi] : ra[bi];
        const float cr_ = __shfl(cc_, rt[bi]);
        const float sr_ = __shfl(cs_, rt[bi]);
        const float a  = H[p0 * 36 + q0], b = H[p0 * 36 + q1];
        const float c2 = H[p1 * 36 + q0], d = H[p1 * 36 + q1];
        const float t1 = cr_ * a - sr_ * c2, t2 = cr_ * b - sr_ * d;
        const float u1 = sr_ * a + cr_ * c2, u2 = sr_ * b + cr_ * d;
        o00[bi] = cc_ * t1 - cs_ * t2; o01[bi] = cs_ * t1 + cc_ * t2;
        o10[bi] = cc_ * u1 - cs_ * u2; o11[bi] = cs_ * u1 + cc_ * u2;
        P0[bi] = p0; P1[bi] = p1;
      }
      float v0[NVMAX], v1[NVMAX];
      #pragma unroll
      for (int vi = 0; vi < NVMAX; ++vi) {
        if (vi == 0 && !vact) continue;
        const int row = (N == 32) ? ((tid >> 4) + 8 * vi) : ((N == 16) ? (tid >> 3) : (tid >> 1));
        const float a0 = V[row * 36 + q0], a1 = V[row * 36 + q1];
        v0[vi] = cc_ * a0 - cs_ * a1; v1[vi] = cs_ * a0 + cc_ * a1;
      }
      __syncthreads();
      #pragma unroll
      for (int bi = 0; bi < NBMAX; ++bi) {
        if (bi == 0 && !hact) continue;
        H[P0[bi] * 36 + q0] = o00[bi]; H[P0[bi] * 36 + q1] = o01[bi];
        H[P1[bi] * 36 + q0] = o10[bi]; H[P1[bi] * 36 + q1] = o11[bi];
      }
      #pragma unroll
      for (int vi = 0; vi < NVMAX; ++vi) {
        if (vi == 0 && !vact) continue;
        const int row = (N == 32) ? ((tid >> 4) + 8 * vi) : ((N == 16) ? (tid >> 3) : (tid >> 1));
        V[row * 36 + q0] = v0[vi]; V[row * 36 + q1] = v1[vi];
      }
      __syncthreads();
      // advance tournament (periodic mod NM1; seat 0 keeps partner NM1)
      ca  = (cp == 0) ? NM1 : ((ca + 1 == NM1) ? 0 : ca + 1);
      cb2 = (cb2 + 1 == NM1) ? 0 : cb2 + 1;
      #pragma unroll
      for (int bi = 0; bi < NBMAX; ++bi) {
        ra[bi] = (rt[bi] == 0) ? NM1 : ((ra[bi] + 1 == NM1) ? 0 : ra[bi] + 1);
        rb[bi] = (rb[bi] + 1 == NM1) ? 0 : rb[bi] + 1;
      }
    }
  }
}

// G(+)= A^T A over 'nrows' stride-36 rows of A, mcols in {16,32}; float4 on column quads
__device__ __forceinline__ void gram_cols(float* __restrict__ G, const float* __restrict__ A,
                                          int nrows, int mcols, bool init, int tid)
{
  const int q4 = mcols >> 2;
  const int q4log = (mcols == 32) ? 3 : 2;
  const int nel = mcols * q4;
  const float4* A4 = (const float4*)A;
  float4* G4 = (float4*)G;
  for (int e = tid; e < nel; e += 128) {
    const int c2q = e & (q4 - 1);
    const int c1 = e >> q4log;
    float ax = 0.f, ay = 0.f, az = 0.f, aw = 0.f;
    for (int r = 0; r < nrows; ++r) {
      const float a1 = A[r * 36 + c1];
      const float4 a2 = A4[r * 9 + c2q];
      ax += a1 * a2.x; ay += a1 * a2.y; az += a1 * a2.z; aw += a1 * a2.w;
    }
    float4* gp = G4 + c1 * 9 + c2q;
    if (init) { float4 o; o.x = ax; o.y = ay; o.z = az; o.w = aw; *gp = o; }
    else { float4 o = *gp; o.x += ax; o.y += ay; o.z += az; o.w += aw; *gp = o; }
  }
  __syncthreads();
}

// absorb column i1 of row j into BIGT[(rr-rr0)*dbw+db][ua] (stride 36), rr in [rr0,rr1)
__device__ __forceinline__ void absorb_T(const float* __restrict__ Tg, const float* __restrict__ poolS,
    float* __restrict__ BIGT, float* __restrict__ ATile, const int* __restrict__ xi,
    int i1, int j, int U, int Dd, int rr0, int rr1, int tid)
{
  const int bd = (i1 == 5) ? 1 : 4;
  const int dbw = Dd * bd;
  const int mt_ = U * 4;
  const int ph = xi[i1 * 6 + j];
  const float* tb = Tg + (size_t)(i1 * 6 + j) * 512;
  for (int e = tid; e < 256; e += 128) ATile[e] = tb[e * 2 + ph];
  __syncthreads();
  const int mlog = (mt_ == 32) ? 5 : 4;
  const int dblog = 31 - __clz(dbw);
  const int bdlog = (bd == 4) ? 2 : 0;
  const int nel = mt_ * dbw * (rr1 - rr0);
  for (int e = tid; e < nel; e += 128) {
    const int ua = e & (mt_ - 1);
    const int db = (e >> mlog) & (dbw - 1);
    const int rr = rr0 + (e >> (mlog + dblog));
    const int u = ua >> 2, a = ua & 3;
    const int d_ = db >> bdlog, b = db & (bd - 1);
    const float* op = poolS + u * 33 + d_;
    const float4 av = *(const float4*)(ATile + a * 64 + rr * 16 + b * 4);
    BIGT[((rr - rr0) * dbw + db) * 36 + ua] = op[0] * av.x + op[8] * av.y + op[16] * av.z + op[24] * av.w;
  }
  __syncthreads();
}

// ============ kernel 2: one sample per 128-thread workgroup ============
__global__ __launch_bounds__(128, 2) void peps_kernel(
    const float* __restrict__ Tg, const int* __restrict__ x,
    float* __restrict__ proj, float* __restrict__ out)
{
  __shared__ float pool[6 * 264];   // [i][u<=8 stride33][x=4 stride8][d<=8]
  __shared__ float CUR[1152];       // mt: rows (u*4+rr)<=32, stride 36
  __shared__ float BIGT[2304];      // mb^T half: rows (rr*dbw+db)<=64 stride 36
  __shared__ float GbM[1152];       // Gb (or Gt for q-path); m-path: Gb@0, Gt@576
  __shared__ float TM[1152];        // T / R2@0+T1@576 / eigvecs V
  __shared__ float GM[1152];        // G / H (diagonalized in place)
  __shared__ float ATile[256];
  __shared__ float PdL[256], PuL[256];  // [mrow][8]
  __shared__ float red[4];
  __shared__ int isel[8];
  __shared__ float sinvv[8], sdiv[8];
  __shared__ int xi[36];
  __shared__ float vvec[36], vvec2[36];

  const int s = blockIdx.x;
  const int tid = threadIdx.x;
  if (tid < 36) xi[tid] = x[s * 36 + tid];
  __syncthreads();

  for (int sweep = 0; sweep < 2; ++sweep) {
    // --- init boundary MPS from row j=0 ---
    for (int i2 = 0; i2 < 6; ++i2) {
      const int ad = (i2 == 0) ? 1 : 4, bd = (i2 == 5) ? 1 : 4;
      const int bdlog = (bd == 4) ? 2 : 0;
      const int ph = xi[i2 * 6];
      const float* tb = Tg + (size_t)(i2 * 6) * 512;
      const int nel = ad * 4 * bd;
      for (int e = tid; e < nel; e += 128) {
        const int b = e & (bd - 1);
        const int rr = (e >> bdlog) & 3;
        const int a = e >> (bdlog + 2);
        pool[i2 * 264 + a * 33 + rr * 8 + b] = tb[(a * 64 + rr * 16 + b * 4) * 2 + ph];
      }
    }
    __syncthreads();

    for (int j = 1; j <= 4; ++j) {
      const int jj = (j > 1) ? 1 : 0;
      // absorb column 0 into CUR (4 rows x 16 cols)
      {
        const int ph = xi[j];          // site (0,j)
        const float* tb = Tg + (size_t)j * 512;
        for (int e = tid; e < 256; e += 128) ATile[e] = tb[e * 2 + ph];
        __syncthreads();
        for (int e = tid; e < 64; e += 128) {
          const int db = e & 15;
          const int rr = e >> 4;
          const int d_ = db >> 2, b = db & 3;
          const float* op = pool + d_;  // slot 0, u=0
          const float4 av = *(const float4*)(ATile + rr * 16 + b * 4);  // a=0
          CUR[rr * 36 + db] = op[0] * av.x + op[8] * av.y + op[16] * av.z + op[24] * av.w;
        }
        __syncthreads();
      }

      for (int i = 0; i < 5; ++i) {
        const int m = g_mtab[jj][i], cb = g_cbtab[i], ucur = g_ucurtab[i], dn = g_dntab[jj][i];
        const int p = ucur * 4, path = g_path[jj][i];
        const int U1 = g_uprev[jj][i + 1], Dd1 = g_dprev[jj][i + 1];
        const bool two = (dn == 32);
        const int cblog = (cb == 8) ? 3 : 2;
        const int mq4 = m >> 2;
        float* projb = proj + (size_t)s * 6400 + g_offtab[j - 1][i];

        if (sweep == 0) {
          if (path == 2) {
            // ---- q-side (i=4): G = mb^T Gt mb (4x4) ----
            absorb_T(Tg, pool + (i + 1) * 264, BIGT, ATile, xi, i + 1, j, U1, Dd1, 0, 4, tid);
            gram_cols(GbM, CUR, p, m, true, tid);   // Gt (16x16)
            for (int e = tid; e < 64; e += 128) {   // T1 = Gt*mb (16x4)
              const int r = e & 3, k = e >> 2;
              float acc = 0.f;
              const float4* G4 = (const float4*)GbM;
              const float4* B4 = (const float4*)BIGT;
              for (int lq = 0; lq < 4; ++lq) {
                const float4 g = G4[k * 9 + lq], b = B4[r * 9 + lq];
                acc += g.x * b.x + g.y * b.y + g.z * b.z + g.w * b.w;
              }
              TM[k * 36 + r] = acc;
            }
            __syncthreads();
            for (int e = tid; e < 16; e += 128) {   // G = mb^T * T1 (4x4)
              const int c = e & 3, r = e >> 2;
              float acc = 0.f;
              for (int k = 0; k < 16; ++k) acc += BIGT[r * 36 + k] * TM[k * 36 + c];
              GM[r * 36 + c] = acc;
            }
            __syncthreads();
            jacobi_pb<4>(GM, TM + 576, tid);
          } else if (path == 0) {
            // ---- p-side: G = mt Gb mt^T (p x p), no Cholesky ----
            if (!two) {
              absorb_T(Tg, pool + (i + 1) * 264, BIGT, ATile, xi, i + 1, j, U1, Dd1, 0, 4, tid);
              gram_cols(GbM, BIGT, 4 * dn, m, true, tid);
            } else {
              absorb_T(Tg, pool + (i + 1) * 264, BIGT, ATile, xi, i + 1, j, U1, Dd1, 0, 2, tid);
              gram_cols(GbM, BIGT, 2 * dn, m, true, tid);
              absorb_T(Tg, pool + (i + 1) * 264, BIGT, ATile, xi, i + 1, j, U1, Dd1, 2, 4, tid);
              gram_cols(GbM, BIGT, 2 * dn, m, false, tid);
            }
            const int q4log = (m == 32) ? 3 : 2;
            for (int e = tid; e < p * mq4; e += 128) {  // T = mt*Gb (p x m)
              const int lq = e & (mq4 - 1), pr = e >> q4log;
              float ax = 0.f, ay = 0.f, az = 0.f, aw = 0.f;
              const float4* G4 = (const float4*)GbM;
              for (int k = 0; k < m; ++k) {
                const float a1 = CUR[pr * 36 + k];
                const float4 g = G4[k * 9 + lq];
                ax += a1 * g.x; ay += a1 * g.y; az += a1 * g.z; aw += a1 * g.w;
              }
              float4 o; o.x = ax; o.y = ay; o.z = az; o.w = aw;
              ((float4*)TM)[pr * 9 + lq] = o;
            }
            __syncthreads();
            const int plog = (p == 32) ? 5 : ((p == 16) ? 4 : 2);
            for (int e = tid; e < p * p; e += 128) {    // G = T*mt^T (p x p)
              const int pc = e & (p - 1), pr = e >> plog;
              float acc = 0.f;
              const float4* T4 = (const float4*)TM;
              const float4* C4 = (const float4*)CUR;
              for (int lq = 0; lq < mq4; ++lq) {
                const float4 t = T4[pr * 9 + lq], c = C4[pc * 9 + lq];
                acc += t.x * c.x + t.y * c.y + t.z * c.z + t.w * c.w;
              }
              GM[pr * 36 + pc] = acc;
            }
            __syncthreads();
            if (p == 4)       jacobi_pb<4>(GM, TM, tid);
            else if (p == 16) jacobi_pb<16>(GM, TM, tid);
            else              jacobi_pb<32>(GM, TM, tid);
          } else {
            // ---- m-side (jj0 i=2,3): Gt, Gb, chol(Gb), H = R2 Gt R2^T (16x16) ----
            absorb_T(Tg, pool + (i + 1) * 264, BIGT, ATile, xi, i + 1, j, U1, Dd1, 0, 4, tid);
            gram_cols(GbM + 576, CUR, p, m, true, tid);     // Gt
            gram_cols(GbM, BIGT, 4 * dn, m, true, tid);     // Gb
            // cholesky Gb -> R2 (TM[0:576]) with zero-skip
            if (tid < 64) {
              float v_ = (tid < 16) ? GbM[tid * 37] : -3.0e38f;
              for (int mk = 32; mk; mk >>= 1) v_ = fmaxf(v_, __shfl_xor(v_, mk));
              if (tid == 0) red[0] = v_;
            }
            __syncthreads();
            const float thr = 1e-10f * red[0] + 1e-35f;
            for (int k = 0; k < 16; ++k) {
              const float dk = GbM[k * 37];
              const float rs = (dk > thr) ? (1.0f / sqrtf(dk)) : 0.0f;
              if (tid < 16) TM[k * 36 + tid] = GbM[k * 36 + tid] * rs;
              __syncthreads();
              const int rows = 15 - k;
              for (int e = tid; e < rows * 16; e += 128) {
                const int ii = k + 1 + (e >> 4), jc = e & 15;
                GbM[ii * 36 + jc] -= TM[k * 36 + ii] * TM[k * 36 + jc];
              }
              __syncthreads();
            }
            for (int e = tid; e < 64; e += 128) {   // T1 = R2*Gt -> TM+576
              const int jq = e & 3, k = e >> 2;
              float ax = 0.f, ay = 0.f, az = 0.f, aw = 0.f;
              const float4* Gt4 = (const float4*)(GbM + 576);
              for (int l = 0; l < 16; ++l) {
                const float r2 = TM[k * 36 + l];
                const float4 g = Gt4[l * 9 + jq];
                ax += r2 * g.x; ay += r2 * g.y; az += r2 * g.z; aw += r2 * g.w;
              }
              float4 o; o.x = ax; o.y = ay; o.z = az; o.w = aw;
              ((float4*)(TM + 576))[k * 9 + jq] = o;
            }
            __syncthreads();
            for (int e = tid; e < 256; e += 128) {  // H = T1*R2^T -> GM
              const int k2 = e & 15, k = e >> 4;
              float acc = 0.f;
              const float4* T14 = (const float4*)(TM + 576);
              const float4* R24 = (const float4*)TM;
              for (int lq = 0; lq < 4; ++lq) {
                const float4 t = T14[k * 9 + lq], r = R24[k2 * 9 + lq];
                acc += t.x * r.x + t.y * r.y + t.z * r.z + t.w * r.w;
              }
              GM[k * 36 + k2] = acc;
            }
            __syncthreads();
            jacobi_pb<16>(GM, TM + 576, tid);
          }

          // ---- top-cb selection + scales ----
          const int N = (path == 2) ? 4 : ((path == 1) ? 16 : p);
          if (tid < 64) {
            float v_ = (tid < N) ? GM[tid * 37] : -3.0e38f;
            int ix = tid;
            for (int t = 0; t < cb; ++t) {
              float bv = v_; int bi = ix;
              for (int mk = 32; mk; mk >>= 1) {
                const float ov = __shfl_xor(bv, mk);
                const int oi = __shfl_xor(bi, mk);
                if (ov > bv || (ov == bv && oi < bi)) { bv = ov; bi = oi; }
              }
              if (tid == 0) isel[t] = bi;
              if (ix == bi) v_ = -3.0e38f;
            }
          }
          __syncthreads();
          if (tid < cb) {
            const float lam = GM[isel[tid] * 37];
            const float s_ = sqrtf(fmaxf(lam, 0.0f));
            sinvv[tid] = 1.0f / sqrtf(s_ + 1e-12f);
            sdiv[tid]  = 1.0f / fmaxf(s_, 1e-25f);
          }
          __syncthreads();

          // ---- projectors ----
          if (path == 0) {
            // Pu = mt^T U sinv ; Pd = Gb Pu / s   (U cols in TM)
            for (int e = tid; e < m * cb; e += 128) {
              const int k = e & (cb - 1), mrow = e >> cblog;
              const int a = isel[k];
              float acc = 0.f;
              for (int pr = 0; pr < p; ++pr) acc += CUR[pr * 36 + mrow] * TM[pr * 36 + a];
              PuL[mrow * 8 + k] = acc * sinvv[k];
            }
            __syncthreads();
            for (int e = tid; e < m * cb; e += 128) {
              const int k = e & (cb - 1), mrow = e >> cblog;
              float acc = 0.f;
              for (int l = 0; l < m; ++l) acc += GbM[mrow * 36 + l] * PuL[l * 8 + k];
              PdL[mrow * 8 + k] = acc * sdiv[k];
            }
            __syncthreads();
          } else if (path == 2) {
            // Pd = mb V sinv ; Pu = Gt Pd / s   (V in TM+576, Gt in GbM)
            for (int e = tid; e < m * cb; e += 128) {
              const int k = e & (cb - 1), mrow = e >> cblog;
              const int a = isel[k];
              float acc = 0.f;
              for (int r = 0; r < 4; ++r) acc += BIGT[r * 36 + mrow] * TM[576 + r * 36 + a];
              PdL[mrow * 8 + k] = acc * sinvv[k];
            }
            __syncthreads();
            for (int e = tid; e < m * cb; e += 128) {
              const int k = e & (cb - 1), mrow = e >> cblog;
              float acc = 0.f;
              for (int l = 0; l < m; ++l) acc += GbM[mrow * 36 + l] * PdL[l * 8 + k];
              PuL[mrow * 8 + k] = acc * sdiv[k];
            }
            __syncthreads();
          } else {
            // Pd = R2^T V sinv ; Pu = Gt Pd / s  (R2 in TM[0:576], V in TM+576, Gt in GbM+576)
            for (int e = tid; e < m * cb; e += 128) {
              const int k = e & (cb - 1), mrow = e >> cblog;
              const int a = isel[k];
              float acc = 0.f;
              for (int t = 0; t < 16; ++t) acc += TM[t * 36 + mrow] * TM[576 + t * 36 + a];
              PdL[mrow * 8 + k] = acc * sinvv[k];
            }
            __syncthreads();
            for (int e = tid; e < m * cb; e += 128) {
              const int k = e & (cb - 1), mrow = e >> cblog;
              float acc = 0.f;
              for (int l = 0; l < m; ++l) acc += GbM[576 + mrow * 36 + l] * PdL[l * 8 + k];
              PuL[mrow * 8 + k] = acc * sdiv[k];
            }
            __syncthreads();
          }
          // store perturbed projectors (ws slot preloaded with ETA*mlp)
          for (int e = tid; e < m * cb; e += 128)
            projb[e] += PdL[(e >> cblog) * 8 + (e & (cb - 1))];
          for (int e = tid; e < m * cb; e += 128)
            projb[m * cb + e] += PuL[(e >> cblog) * 8 + (e & (cb - 1))];
        } else {
          // ---- sweep 2: load perturbed projectors + stage mb (B-half for two-pass) ----
          for (int e = tid; e < m * cb; e += 128)
            PdL[(e >> cblog) * 8 + (e & (cb - 1))] = projb[e];
          for (int e = tid; e < m * cb; e += 128)
            PuL[(e >> cblog) * 8 + (e & (cb - 1))] = projb[m * cb + e];
          __syncthreads();
          if (!two) absorb_T(Tg, pool + (i + 1) * 264, BIGT, ATile, xi, i + 1, j, U1, Dd1, 0, 4, tid);
          else      absorb_T(Tg, pool + (i + 1) * 264, BIGT, ATile, xi, i + 1, j, U1, Dd1, 2, 4, tid);
        }

        // ---- common: Bn[i] = Tt*Pd -> pool[i]; Bn[i+1] = Pu applied to mb -> CUR (or pool[5]) ----
        {
          const int nel = ucur * 4 * cb;
          const float4* C4 = (const float4*)CUR;
          for (int e = tid; e < nel; e += 128) {
            const int cc = e & (cb - 1);
            const int rr = (e >> cblog) & 3;
            const int u = e >> (cblog + 2);
            const int row = u * 4 + rr;
            float acc = 0.f;
            for (int mq = 0; mq < mq4; ++mq) {
              const float4 cv = C4[row * 9 + mq];
              acc += cv.x * PdL[(mq * 4 + 0) * 8 + cc] + cv.y * PdL[(mq * 4 + 1) * 8 + cc]
                   + cv.z * PdL[(mq * 4 + 2) * 8 + cc] + cv.w * PdL[(mq * 4 + 3) * 8 + cc];
            }
            pool[i * 264 + u * 33 + rr * 8 + cc] = acc;
          }
          __syncthreads();

          const int dnlog = 31 - __clz(dn);
          auto bn1 = [&](int rr0, int nloc) {
            const int ne2 = cb * nloc * dn;
            const float4* B4 = (const float4*)BIGT;
            for (int e = tid; e < ne2; e += 128) {
              const int dd = e & (dn - 1);
              const int t = e >> dnlog;
              const int rrL = t & (nloc - 1);
              const int cc = t >> ((nloc == 4) ? 2 : 1);
              const int row = rrL * dn + dd;
              float acc = 0.f;
              for (int mq = 0; mq < mq4; ++mq) {
                const float4 bv = B4[row * 9 + mq];
                acc += bv.x * PuL[(mq * 4 + 0) * 8 + cc] + bv.y * PuL[(mq * 4 + 1) * 8 + cc]
                     + bv.z * PuL[(mq * 4 + 2) * 8 + cc] + bv.w * PuL[(mq * 4 + 3) * 8 + cc];
              }
              if (i < 4) CUR[(cc * 4 + rr0 + rrL) * 36 + dd] = acc;
              else       pool[5 * 264 + cc * 33 + (rr0 + rrL) * 8] = acc;
            }
            __syncthreads();
          };
          if (!two) {
            bn1(0, 4);
          } else {
            bn1(2, 2);
            absorb_T(Tg, pool + (i + 1) * 264, BIGT, ATile, xi, i + 1, j, U1, Dd1, 0, 2, tid);
            bn1(0, 2);
          }
        }
      }
    }

    if (sweep == 1) {
      // ---- finalize: scalar = prod_i C_i ----
      if (tid == 0) vvec[0] = 1.0f;
      __syncthreads();
      for (int i = 0; i < 6; ++i) {
        const int ad = (i == 0) ? 1 : 4, bd = (i == 5) ? 1 : 4;
        const int adlog = (ad == 4) ? 2 : 0, bdlog = (bd == 4) ? 2 : 0;
        const int rows = g_ufin[i] * ad, cols = g_dfin[i] * bd;
        const int clog = 31 - __clz(cols);
        const int ph = xi[i * 6 + 5];
        const float* tb = Tg + (size_t)(i * 6 + 5) * 512;
        for (int e = tid; e < 256; e += 128) ATile[e] = tb[e * 2 + ph];
        __syncthreads();
        for (int e = tid; e < rows * cols; e += 128) {
          const int col = e & (cols - 1);
          const int ua = e >> clog;
          const int u = ua >> adlog, a = ua & (ad - 1);
          const int d_ = col >> bdlog, b = col & (bd - 1);
          const float* fb = pool + i * 264 + u * 33 + d_;
          const float4 av = *(const float4*)(ATile + a * 64 + b * 4);  // R = 0 slice
          GM[ua * 36 + col] = fb[0] * av.x + fb[8] * av.y + fb[16] * av.z + fb[24] * av.w;
        }
        __syncthreads();
        if (tid < cols) {
          float acc = 0.f;
          for (int r_ = 0; r_ < rows; ++r_) acc += vvec[r_] * GM[r_ * 36 + tid];
          vvec2[tid] = acc;
        }
        __syncthreads();
        if (tid < cols) vvec[tid] = vvec2[tid];
        __syncthreads();
      }
      if (tid == 0) out[s] = vvec[0];
    }
  }
}

extern "C" void kernel_launch(void* const* d_in, const int* in_sizes, int n_in,
                              void* d_out, int out_size, void* d_ws, size_t ws_size,
                              hipStream_t stream) {
  const float* Tg = (const float*)d_in[0];
  const float* W1 = (const float*)d_in[1];
  const float* b1 = (const float*)d_in[2];
  const float* W2 = (const float*)d_in[3];
  const float* b2 = (const float*)d_in[4];
  const int*   x  = (const int*)d_in[5];
  float* out = (float*)d_out;
  float* proj = (float*)d_ws;   // 1024*6400 floats: ETA*mlp then += projectors
  (void)in_sizes; (void)n_in; (void)out_size; (void)ws_size;

  mlp_kernel<<<dim3(128), dim3(256), 0, stream>>>(W1, b1, W2, b2, x, proj);
  peps_kernel<<<dim3(1024), dim3(128), 0, stream>>>(Tg, x, proj, out);
}

// Round 11
// 1497.385 us; speedup vs baseline: 4.4310x; 1.0769x over previous
//
#include <hip/hip_runtime.h>

// ---------------- static schedule tables ----------------
__device__ const int g_uprev[2][6] = {{1,4,4,4,4,4},{1,4,8,8,8,4}};
__device__ const int g_dprev[2][6] = {{4,4,4,4,4,1},{4,8,8,8,4,1}};
__device__ const int g_mtab[2][5]  = {{16,16,16,16,16},{16,32,32,32,16}};
__device__ const int g_cbtab[5]    = {4,8,8,8,4};
__device__ const int g_ucurtab[5]  = {1,4,8,8,8};
__device__ const int g_dntab[2][5] = {{16,16,16,16,1},{32,32,32,16,1}};
__device__ const int g_path[2][5]  = {{0,0,1,1,2},{0,0,0,0,2}};  // 0=p-side,1=m-side(chol),2=q-side
__device__ const int g_offtab[4][5]= {{0,128,384,640,896},
                                      {1024,1152,1664,2176,2688},
                                      {2816,2944,3456,3968,4480},
                                      {4608,4736,5248,5760,6272}};
__device__ const int g_ufin[6] = {1,4,8,8,8,4};
__device__ const int g_dfin[6] = {4,8,8,8,4,1};

// ============ kernel 1: proj[s][k] = ETA*mlp(x_s)[k] ============
__global__ __launch_bounds__(256) void mlp_kernel(
    const float* __restrict__ W1, const float* __restrict__ b1,
    const float* __restrict__ W2, const float* __restrict__ b2,
    const int* __restrict__ x, float* __restrict__ proj)
{
  __shared__ float hbuf[8][64];
  const int tid = threadIdx.x;
  const int s0 = blockIdx.x << 3;
  for (int e = tid; e < 512; e += 256) {
    const int sl = e >> 6, hh = e & 63;
    const int* xr = x + (s0 + sl) * 36;
    const float* wr = W1 + hh * 36;
    float acc = b1[hh];
    #pragma unroll
    for (int t = 0; t < 36; ++t) acc += wr[t] * (float)xr[t];
    hbuf[sl][hh] = fmaxf(acc, 0.0f);
  }
  __syncthreads();
  for (int k = tid; k < 6400; k += 256) {
    const float4* wr = (const float4*)(W2 + (size_t)k * 64);
    float acc[8];
    #pragma unroll
    for (int s2 = 0; s2 < 8; ++s2) acc[s2] = 0.0f;
    #pragma unroll
    for (int c = 0; c < 16; ++c) {
      const float4 w = wr[c];
      #pragma unroll
      for (int s2 = 0; s2 < 8; ++s2) {
        const float4 hv = ((const float4*)hbuf[s2])[c];
        acc[s2] += w.x * hv.x + w.y * hv.y + w.z * hv.z + w.w * hv.w;
      }
    }
    const float bb = b2[k];
    #pragma unroll
    for (int s2 = 0; s2 < 8; ++s2)
      proj[(size_t)(s0 + s2) * 6400 + k] = 0.001f * (acc[s2] + bb);
  }
}

// ---------------- rotation angle (HW-approx rcp/rsq/sqrt, ~1ulp) ----------------
__device__ __forceinline__ void jrot(float app, float aqq, float apq, float& c, float& sn) {
  c = 1.0f; sn = 0.0f;
  if (fabsf(apq) > 1e-36f + 1e-12f * (fabsf(app) + fabsf(aqq))) {
    const float tau = (aqq - app) * 0.5f * __builtin_amdgcn_rcpf(apq);
    const float t = copysignf(1.0f, tau) *
                    __builtin_amdgcn_rcpf(fabsf(tau) + __builtin_amdgcn_sqrtf(1.0f + tau * tau));
    c = __builtin_amdgcn_rsqf(1.0f + t * t);
    sn = t * c;
  }
}

// seat of matrix index i at round 0 (inverse of idx0): i==n-1 -> 0; i==0 -> 1; i<n/2 -> 2i; else 2(n-1-i)+1
__device__ __forceinline__ int seatof(int i, int n) {
  return (i == n - 1) ? 0 : ((i == 0) ? 1 : ((i < (n >> 1)) ? (2 * i) : (2 * (n - 1 - i) + 1)));
}

// tournament seat shift to next round: 0->0; odd s: s+2 (wrap 2NP-1 -> 2NP-2); even s: s-2 (2 -> 1)
__device__ __forceinline__ int sgshift(int s, int np) {
  if (s == 0) return 0;
  if (s & 1) return (s == 2 * np - 1) ? (2 * np - 2) : (s + 2);
  return (s == 2) ? 1 : (s - 2);
}

// SEAT-SPACE pair-blocked two-sided Jacobi. H stored seat-indexed (stride 36): pair t = seats (2t,2t+1),
// all addresses per-lane static; pairs are adjacent -> float2 reads; writes go to sigma-shifted seats.
// V rows = G-space, cols = seats; init V = round-0 permutation. diag -> eigenvalues at seats;
// V columns = eigvecs at seats (labels opaque to consumers). Sweeps 5/5/3 (4 fails - R9).
template<int N>
__device__ void jacobi_pb(float* __restrict__ H, float* __restrict__ V, int tid)
{
  constexpr int NP = N / 2;
  constexpr int NM1 = N - 1;
  constexpr int NL = (N == 32) ? 5 : ((N == 16) ? 4 : 2);
  constexpr int NBMAX = (N == 32) ? 2 : 1;
  constexpr int NVMAX = (N == 32) ? 4 : 1;
  constexpr int MAXSW = (N == 32) ? 5 : ((N == 16) ? 5 : 3);
  // V init: V[g][seat] = (g == idx0(seat))
  for (int e = tid; e < N * N; e += 128) {
    const int r = e >> NL, c = e & (N - 1);
    const int i0 = (c == 0) ? NM1 : ((c == 1) ? 0 : ((c & 1) ? (NM1 - (c >> 1)) : (c >> 1)));
    V[r * 36 + c] = (r == i0) ? 1.0f : 0.0f;
  }
  __syncthreads();
  const int cp = tid & (NP - 1);
  const bool hact = (N == 32) ? true : (tid < NP * NP);
  const bool vact = (N >= 16) ? true : (tid < N * NP);
  const int q0 = 2 * cp, q1 = q0 + 1;
  const int d0 = sgshift(q0, NP), d1 = sgshift(q1, NP);
  int rt[NBMAX], r0[NBMAX], r1[NBMAX], e0[NBMAX], e1[NBMAX];
  #pragma unroll
  for (int bi = 0; bi < NBMAX; ++bi) {
    rt[bi] = (N == 32) ? ((tid >> 4) + 8 * bi) : ((N == 16) ? (tid >> 3) : (tid >> 1));
    r0[bi] = 2 * rt[bi]; r1[bi] = r0[bi] + 1;
    e0[bi] = sgshift(r0[bi], NP); e1[bi] = sgshift(r1[bi], NP);
  }
  int vr[NVMAX];
  #pragma unroll
  for (int vi = 0; vi < NVMAX; ++vi)
    vr[vi] = (N == 32) ? ((tid >> 4) + 8 * vi) : ((N == 16) ? (tid >> 3) : (tid >> 1));

  for (int sw = 0; sw < MAXSW; ++sw) {
    for (int rd = 0; rd < NM1; ++rd) {
      // my column-pair angle from the diag block (float2: H[q0][q0], H[q0][q1])
      const float2 dg = *(const float2*)(H + q0 * 36 + q0);
      const float aqq = H[q1 * 36 + q1];
      float cc_, cs_;
      jrot(dg.x, aqq, dg.y, cc_, cs_);
      float o00[NBMAX], o01[NBMAX], o10[NBMAX], o11[NBMAX];
      #pragma unroll
      for (int bi = 0; bi < NBMAX; ++bi) {
        if (bi == 0 && !hact) continue;
        const float cr_ = __shfl(cc_, rt[bi]);
        const float sr_ = __shfl(cs_, rt[bi]);
        const float2 rA = *(const float2*)(H + r0[bi] * 36 + q0);
        const float2 rB = *(const float2*)(H + r1[bi] * 36 + q0);
        const float t1 = cr_ * rA.x - sr_ * rB.x, t2 = cr_ * rA.y - sr_ * rB.y;
        const float u1 = sr_ * rA.x + cr_ * rB.x, u2 = sr_ * rA.y + cr_ * rB.y;
        o00[bi] = cc_ * t1 - cs_ * t2; o01[bi] = cs_ * t1 + cc_ * t2;
        o10[bi] = cc_ * u1 - cs_ * u2; o11[bi] = cs_ * u1 + cc_ * u2;
      }
      float v0[NVMAX], v1[NVMAX];
      #pragma unroll
      for (int vi = 0; vi < NVMAX; ++vi) {
        if (vi == 0 && !vact) continue;
        const float2 vv = *(const float2*)(V + vr[vi] * 36 + q0);
        v0[vi] = cc_ * vv.x - cs_ * vv.y;
        v1[vi] = cs_ * vv.x + cc_ * vv.y;
      }
      __syncthreads();
      #pragma unroll
      for (int bi = 0; bi < NBMAX; ++bi) {
        if (bi == 0 && !hact) continue;
        H[e0[bi] * 36 + d0] = o00[bi]; H[e0[bi] * 36 + d1] = o01[bi];
        H[e1[bi] * 36 + d0] = o10[bi]; H[e1[bi] * 36 + d1] = o11[bi];
      }
      #pragma unroll
      for (int vi = 0; vi < NVMAX; ++vi) {
        if (vi == 0 && !vact) continue;
        V[vr[vi] * 36 + d0] = v0[vi];
        V[vr[vi] * 36 + d1] = v1[vi];
      }
      __syncthreads();
    }
  }
}

// G(+)= A^T A over 'nrows' stride-36 rows of A, mcols in {16,32}; float4 on column quads
__device__ __forceinline__ void gram_cols(float* __restrict__ G, const float* __restrict__ A,
                                          int nrows, int mcols, bool init, int tid)
{
  const int q4 = mcols >> 2;
  const int q4log = (mcols == 32) ? 3 : 2;
  const int nel = mcols * q4;
  const float4* A4 = (const float4*)A;
  float4* G4 = (float4*)G;
  for (int e = tid; e < nel; e += 128) {
    const int c2q = e & (q4 - 1);
    const int c1 = e >> q4log;
    float ax = 0.f, ay = 0.f, az = 0.f, aw = 0.f;
    for (int r = 0; r < nrows; ++r) {
      const float a1 = A[r * 36 + c1];
      const float4 a2 = A4[r * 9 + c2q];
      ax += a1 * a2.x; ay += a1 * a2.y; az += a1 * a2.z; aw += a1 * a2.w;
    }
    float4* gp = G4 + c1 * 9 + c2q;
    if (init) { float4 o; o.x = ax; o.y = ay; o.z = az; o.w = aw; *gp = o; }
    else { float4 o = *gp; o.x += ax; o.y += ay; o.z += az; o.w += aw; *gp = o; }
  }
  __syncthreads();
}

// absorb column i1 of row j into BIGT[(rr-rr0)*dbw+db][ua] (stride 36), rr in [rr0,rr1)
__device__ __forceinline__ void absorb_T(const float* __restrict__ Tg, const float* __restrict__ poolS,
    float* __restrict__ BIGT, float* __restrict__ ATile, const int* __restrict__ xi,
    int i1, int j, int U, int Dd, int rr0, int rr1, int tid)
{
  const int bd = (i1 == 5) ? 1 : 4;
  const int dbw = Dd * bd;
  const int mt_ = U * 4;
  const int ph = xi[i1 * 6 + j];
  const float* tb = Tg + (size_t)(i1 * 6 + j) * 512;
  for (int e = tid; e < 256; e += 128) ATile[e] = tb[e * 2 + ph];
  __syncthreads();
  const int mlog = (mt_ == 32) ? 5 : 4;
  const int dblog = 31 - __clz(dbw);
  const int bdlog = (bd == 4) ? 2 : 0;
  const int nel = mt_ * dbw * (rr1 - rr0);
  for (int e = tid; e < nel; e += 128) {
    const int ua = e & (mt_ - 1);
    const int db = (e >> mlog) & (dbw - 1);
    const int rr = rr0 + (e >> (mlog + dblog));
    const int u = ua >> 2, a = ua & 3;
    const int d_ = db >> bdlog, b = db & (bd - 1);
    const float* op = poolS + u * 33 + d_;
    const float4 av = *(const float4*)(ATile + a * 64 + rr * 16 + b * 4);
    BIGT[((rr - rr0) * dbw + db) * 36 + ua] = op[0] * av.x + op[8] * av.y + op[16] * av.z + op[24] * av.w;
  }
  __syncthreads();
}

// ============ kernel 2: one sample per 128-thread workgroup ============
__global__ __launch_bounds__(128, 2) void peps_kernel(
    const float* __restrict__ Tg, const int* __restrict__ x,
    float* __restrict__ proj, float* __restrict__ out)
{
  __shared__ __align__(16) float pool[6 * 264];   // [i][u<=8 stride33][x=4 stride8][d<=8]
  __shared__ __align__(16) float CUR[1152];       // mt: rows (u*4+rr)<=32, stride 36
  __shared__ __align__(16) float BIGT[2304];      // mb^T half: rows <=64, stride 36
  __shared__ __align__(16) float GbM[1152];       // Gb (or Gt); m-path: Gb@0, Gt@576
  __shared__ __align__(16) float TM[1152];        // T / R2@0+V@576 / eigvecs V
  __shared__ __align__(16) float GM[1152];        // G / H in SEAT space
  __shared__ __align__(16) float ATile[256];
  __shared__ __align__(16) float PdL[256], PuL[256];  // [mrow][8]
  __shared__ float red[4];
  __shared__ int isel[8];
  __shared__ float sinvv[8], sdiv[8];
  __shared__ int xi[36];
  __shared__ float vvec[36], vvec2[36];

  const int s = blockIdx.x;
  const int tid = threadIdx.x;
  if (tid < 36) xi[tid] = x[s * 36 + tid];
  __syncthreads();

  for (int sweep = 0; sweep < 2; ++sweep) {
    // --- init boundary MPS from row j=0 ---
    for (int i2 = 0; i2 < 6; ++i2) {
      const int ad = (i2 == 0) ? 1 : 4, bd = (i2 == 5) ? 1 : 4;
      const int bdlog = (bd == 4) ? 2 : 0;
      const int ph = xi[i2 * 6];
      const float* tb = Tg + (size_t)(i2 * 6) * 512;
      const int nel = ad * 4 * bd;
      for (int e = tid; e < nel; e += 128) {
        const int b = e & (bd - 1);
        const int rr = (e >> bdlog) & 3;
        const int a = e >> (bdlog + 2);
        pool[i2 * 264 + a * 33 + rr * 8 + b] = tb[(a * 64 + rr * 16 + b * 4) * 2 + ph];
      }
    }
    __syncthreads();

    for (int j = 1; j <= 4; ++j) {
      const int jj = (j > 1) ? 1 : 0;
      // absorb column 0 into CUR (4 rows x 16 cols)
      {
        const int ph = xi[j];          // site (0,j)
        const float* tb = Tg + (size_t)j * 512;
        for (int e = tid; e < 256; e += 128) ATile[e] = tb[e * 2 + ph];
        __syncthreads();
        for (int e = tid; e < 64; e += 128) {
          const int db = e & 15;
          const int rr = e >> 4;
          const int d_ = db >> 2, b = db & 3;
          const float* op = pool + d_;  // slot 0, u=0
          const float4 av = *(const float4*)(ATile + rr * 16 + b * 4);  // a=0
          CUR[rr * 36 + db] = op[0] * av.x + op[8] * av.y + op[16] * av.z + op[24] * av.w;
        }
        __syncthreads();
      }

      for (int i = 0; i < 5; ++i) {
        const int m = g_mtab[jj][i], cb = g_cbtab[i], ucur = g_ucurtab[i], dn = g_dntab[jj][i];
        const int p = ucur * 4, path = g_path[jj][i];
        const int U1 = g_uprev[jj][i + 1], Dd1 = g_dprev[jj][i + 1];
        const bool two = (dn == 32);
        const int cblog = (cb == 8) ? 3 : 2;
        const int mq4 = m >> 2;
        float* projb = proj + (size_t)s * 6400 + g_offtab[j - 1][i];

        if (sweep == 0) {
          if (path == 2) {
            // ---- q-side (i=4): G = mb^T Gt mb (4x4), seat-permuted write ----
            absorb_T(Tg, pool + (i + 1) * 264, BIGT, ATile, xi, i + 1, j, U1, Dd1, 0, 4, tid);
            gram_cols(GbM, CUR, p, m, true, tid);   // Gt (16x16)
            for (int e = tid; e < 64; e += 128) {   // T1 = Gt*mb (16x4)
              const int r = e & 3, k = e >> 2;
              float acc = 0.f;
              const float4* G4 = (const float4*)GbM;
              const float4* B4 = (const float4*)BIGT;
              for (int lq = 0; lq < 4; ++lq) {
                const float4 g = G4[k * 9 + lq], b = B4[r * 9 + lq];
                acc += g.x * b.x + g.y * b.y + g.z * b.z + g.w * b.w;
              }
              TM[k * 36 + r] = acc;
            }
            __syncthreads();
            for (int e = tid; e < 16; e += 128) {   // G = mb^T * T1 (4x4)
              const int c = e & 3, r = e >> 2;
              float acc = 0.f;
              for (int k = 0; k < 16; ++k) acc += BIGT[r * 36 + k] * TM[k * 36 + c];
              GM[seatof(r, 4) * 36 + seatof(c, 4)] = acc;
            }
            __syncthreads();
            jacobi_pb<4>(GM, TM + 576, tid);
          } else if (path == 0) {
            // ---- p-side: G = mt Gb mt^T (p x p), seat-permuted write ----
            if (!two) {
              absorb_T(Tg, pool + (i + 1) * 264, BIGT, ATile, xi, i + 1, j, U1, Dd1, 0, 4, tid);
              gram_cols(GbM, BIGT, 4 * dn, m, true, tid);
            } else {
              absorb_T(Tg, pool + (i + 1) * 264, BIGT, ATile, xi, i + 1, j, U1, Dd1, 0, 2, tid);
              gram_cols(GbM, BIGT, 2 * dn, m, true, tid);
              absorb_T(Tg, pool + (i + 1) * 264, BIGT, ATile, xi, i + 1, j, U1, Dd1, 2, 4, tid);
              gram_cols(GbM, BIGT, 2 * dn, m, false, tid);
            }
            const int q4log = (m == 32) ? 3 : 2;
            for (int e = tid; e < p * mq4; e += 128) {  // T = mt*Gb (p x m)
              const int lq = e & (mq4 - 1), pr = e >> q4log;
              float ax = 0.f, ay = 0.f, az = 0.f, aw = 0.f;
              const float4* G4 = (const float4*)GbM;
              for (int k = 0; k < m; ++k) {
                const float a1 = CUR[pr * 36 + k];
                const float4 g = G4[k * 9 + lq];
                ax += a1 * g.x; ay += a1 * g.y; az += a1 * g.z; aw += a1 * g.w;
              }
              float4 o; o.x = ax; o.y = ay; o.z = az; o.w = aw;
              ((float4*)TM)[pr * 9 + lq] = o;
            }
            __syncthreads();
            const int plog = (p == 32) ? 5 : ((p == 16) ? 4 : 2);
            for (int e = tid; e < p * p; e += 128) {    // G = T*mt^T (p x p)
              const int pc = e & (p - 1), pr = e >> plog;
              float acc = 0.f;
              const float4* T4 = (const float4*)TM;
              const float4* C4 = (const float4*)CUR;
              for (int lq = 0; lq < mq4; ++lq) {
                const float4 t = T4[pr * 9 + lq], c = C4[pc * 9 + lq];
                acc += t.x * c.x + t.y * c.y + t.z * c.z + t.w * c.w;
              }
              GM[seatof(pr, p) * 36 + seatof(pc, p)] = acc;
            }
            __syncthreads();
            if (p == 4)       jacobi_pb<4>(GM, TM, tid);
            else if (p == 16) jacobi_pb<16>(GM, TM, tid);
            else              jacobi_pb<32>(GM, TM, tid);
          } else {
            // ---- m-side (jj0 i=2,3): Gt, Gb, chol(Gb), H = R2 Gt R2^T (16x16), seat write ----
            absorb_T(Tg, pool + (i + 1) * 264, BIGT, ATile, xi, i + 1, j, U1, Dd1, 0, 4, tid);
            gram_cols(GbM + 576, CUR, p, m, true, tid);     // Gt
            gram_cols(GbM, BIGT, 4 * dn, m, true, tid);     // Gb
            // cholesky Gb -> R2 (TM[0:576]) with zero-skip
            if (tid < 64) {
              float v_ = (tid < 16) ? GbM[tid * 37] : -3.0e38f;
              for (int mk = 32; mk; mk >>= 1) v_ = fmaxf(v_, __shfl_xor(v_, mk));
              if (tid == 0) red[0] = v_;
            }
            __syncthreads();
            const float thr = 1e-10f * red[0] + 1e-35f;
            for (int k = 0; k < 16; ++k) {
              const float dk = GbM[k * 37];
              const float rs = (dk > thr) ? (1.0f / sqrtf(dk)) : 0.0f;
              if (tid < 16) TM[k * 36 + tid] = GbM[k * 36 + tid] * rs;
              __syncthreads();
              const int rows = 15 - k;
              for (int e = tid; e < rows * 16; e += 128) {
                const int ii = k + 1 + (e >> 4), jc = e & 15;
                GbM[ii * 36 + jc] -= TM[k * 36 + ii] * TM[k * 36 + jc];
              }
              __syncthreads();
            }
            for (int e = tid; e < 64; e += 128) {   // T1 = R2*Gt -> TM+576
              const int jq = e & 3, k = e >> 2;
              float ax = 0.f, ay = 0.f, az = 0.f, aw = 0.f;
              const float4* Gt4 = (const float4*)(GbM + 576);
              for (int l = 0; l < 16; ++l) {
                const float r2 = TM[k * 36 + l];
                const float4 g = Gt4[l * 9 + jq];
                ax += r2 * g.x; ay += r2 * g.y; az += r2 * g.z; aw += r2 * g.w;
              }
              float4 o; o.x = ax; o.y = ay; o.z = az; o.w = aw;
              ((float4*)(TM + 576))[k * 9 + jq] = o;
            }
            __syncthreads();
            for (int e = tid; e < 256; e += 128) {  // H = T1*R2^T -> GM (seat space)
              const int k2 = e & 15, k = e >> 4;
              float acc = 0.f;
              const float4* T14 = (const float4*)(TM + 576);
              const float4* R24 = (const float4*)TM;
              for (int lq = 0; lq < 4; ++lq) {
                const float4 t = T14[k * 9 + lq], r = R24[k2 * 9 + lq];
                acc += t.x * r.x + t.y * r.y + t.z * r.z + t.w * r.w;
              }
              GM[seatof(k, 16) * 36 + seatof(k2, 16)] = acc;
            }
            __syncthreads();
            jacobi_pb<16>(GM, TM + 576, tid);
          }

          // ---- top-cb selection + scales (seat labels are opaque) ----
          const int N = (path == 2) ? 4 : ((path == 1) ? 16 : p);
          if (tid < 64) {
            float v_ = (tid < N) ? GM[tid * 37] : -3.0e38f;
            int ix = tid;
            for (int t = 0; t < cb; ++t) {
              float bv = v_; int bi = ix;
              for (int mk = 32; mk; mk >>= 1) {
                const float ov = __shfl_xor(bv, mk);
                const int oi = __shfl_xor(bi, mk);
                if (ov > bv || (ov == bv && oi < bi)) { bv = ov; bi = oi; }
              }
              if (tid == 0) isel[t] = bi;
              if (ix == bi) v_ = -3.0e38f;
            }
          }
          __syncthreads();
          if (tid < cb) {
            const float lam = GM[isel[tid] * 37];
            const float s_ = sqrtf(fmaxf(lam, 0.0f));
            sinvv[tid] = 1.0f / sqrtf(s_ + 1e-12f);
            sdiv[tid]  = 1.0f / fmaxf(s_, 1e-25f);
          }
          __syncthreads();

          // ---- projectors (V rows are G-space; columns indexed by seat isel) ----
          if (path == 0) {
            // Pu = mt^T U sinv ; Pd = Gb Pu / s   (U cols in TM)
            for (int e = tid; e < m * cb; e += 128) {
              const int k = e & (cb - 1), mrow = e >> cblog;
              const int a = isel[k];
              float acc = 0.f;
              for (int pr = 0; pr < p; ++pr) acc += CUR[pr * 36 + mrow] * TM[pr * 36 + a];
              PuL[mrow * 8 + k] = acc * sinvv[k];
            }
            __syncthreads();
            for (int e = tid; e < m * cb; e += 128) {
              const int k = e & (cb - 1), mrow = e >> cblog;
              float acc = 0.f;
              for (int l = 0; l < m; ++l) acc += GbM[mrow * 36 + l] * PuL[l * 8 + k];
              PdL[mrow * 8 + k] = acc * sdiv[k];
            }
            __syncthreads();
          } else if (path == 2) {
            // Pd = mb V sinv ; Pu = Gt Pd / s   (V in TM+576, Gt in GbM)
            for (int e = tid; e < m * cb; e += 128) {
              const int k = e & (cb - 1), mrow = e >> cblog;
              const int a = isel[k];
              float acc = 0.f;
              for (int r = 0; r < 4; ++r) acc += BIGT[r * 36 + mrow] * TM[576 + r * 36 + a];
              PdL[mrow * 8 + k] = acc * sinvv[k];
            }
            __syncthreads();
            for (int e = tid; e < m * cb; e += 128) {
              const int k = e & (cb - 1), mrow = e >> cblog;
              float acc = 0.f;
              for (int l = 0; l < m; ++l) acc += GbM[mrow * 36 + l] * PdL[l * 8 + k];
              PuL[mrow * 8 + k] = acc * sdiv[k];
            }
            __syncthreads();
          } else {
            // Pd = R2^T V sinv ; Pu = Gt Pd / s  (R2 in TM[0:576], V in TM+576, Gt in GbM+576)
            for (int e = tid; e < m * cb; e += 128) {
              const int k = e & (cb - 1), mrow = e >> cblog;
              const int a = isel[k];
              float acc = 0.f;
              for (int t = 0; t < 16; ++t) acc += TM[t * 36 + mrow] * TM[576 + t * 36 + a];
              PdL[mrow * 8 + k] = acc * sinvv[k];
            }
            __syncthreads();
            for (int e = tid; e < m * cb; e += 128) {
              const int k = e & (cb - 1), mrow = e >> cblog;
              float acc = 0.f;
              for (int l = 0; l < m; ++l) acc += GbM[576 + mrow * 36 + l] * PdL[l * 8 + k];
              PuL[mrow * 8 + k] = acc * sdiv[k];
            }
            __syncthreads();
          }
          // store perturbed projectors (ws slot preloaded with ETA*mlp)
          for (int e = tid; e < m * cb; e += 128)
            projb[e] += PdL[(e >> cblog) * 8 + (e & (cb - 1))];
          for (int e = tid; e < m * cb; e += 128)
            projb[m * cb + e] += PuL[(e >> cblog) * 8 + (e & (cb - 1))];
        } else {
          // ---- sweep 2: load perturbed projectors + stage mb (B-half for two-pass) ----
          for (int e = tid; e < m * cb; e += 128)
            PdL[(e >> cblog) * 8 + (e & (cb - 1))] = projb[e];
          for (int e = tid; e < m * cb; e += 128)
            PuL[(e >> cblog) * 8 + (e & (cb - 1))] = projb[m * cb + e];
          __syncthreads();
          if (!two) absorb_T(Tg, pool + (i + 1) * 264, BIGT, ATile, xi, i + 1, j, U1, Dd1, 0, 4, tid);
          else      absorb_T(Tg, pool + (i + 1) * 264, BIGT, ATile, xi, i + 1, j, U1, Dd1, 2, 4, tid);
        }

        // ---- common: Bn[i] = Tt*Pd -> pool[i]; Bn[i+1] = Pu applied to mb -> CUR (or pool[5]) ----
        {
          const int nel = ucur * 4 * cb;
          const float4* C4 = (const float4*)CUR;
          for (int e = tid; e < nel; e += 128) {
            const int cc = e & (cb - 1);
            const int rr = (e >> cblog) & 3;
            const int u = e >> (cblog + 2);
            const int row = u * 4 + rr;
            float acc = 0.f;
            for (int mq = 0; mq < mq4; ++mq) {
              const float4 cv = C4[row * 9 + mq];
              acc += cv.x * PdL[(mq * 4 + 0) * 8 + cc] + cv.y * PdL[(mq * 4 + 1) * 8 + cc]
                   + cv.z * PdL[(mq * 4 + 2) * 8 + cc] + cv.w * PdL[(mq * 4 + 3) * 8 + cc];
            }
            pool[i * 264 + u * 33 + rr * 8 + cc] = acc;
          }
          __syncthreads();

          const int dnlog = 31 - __clz(dn);
          auto bn1 = [&](int rr0, int nloc) {
            const int ne2 = cb * nloc * dn;
            const float4* B4 = (const float4*)BIGT;
            for (int e = tid; e < ne2; e += 128) {
              const int dd = e & (dn - 1);
              const int t = e >> dnlog;
              const int rrL = t & (nloc - 1);
              const int cc = t >> ((nloc == 4) ? 2 : 1);
              const int row = rrL * dn + dd;
              float acc = 0.f;
              for (int mq = 0; mq < mq4; ++mq) {
                const float4 bv = B4[row * 9 + mq];
                acc += bv.x * PuL[(mq * 4 + 0) * 8 + cc] + bv.y * PuL[(mq * 4 + 1) * 8 + cc]
                     + bv.z * PuL[(mq * 4 + 2) * 8 + cc] + bv.w * PuL[(mq * 4 + 3) * 8 + cc];
              }
              if (i < 4) CUR[(cc * 4 + rr0 + rrL) * 36 + dd] = acc;
              else       pool[5 * 264 + cc * 33 + (rr0 + rrL) * 8] = acc;
            }
            __syncthreads();
          };
          if (!two) {
            bn1(0, 4);
          } else {
            bn1(2, 2);
            absorb_T(Tg, pool + (i + 1) * 264, BIGT, ATile, xi, i + 1, j, U1, Dd1, 0, 2, tid);
            bn1(0, 2);
          }
        }
      }
    }

    if (sweep == 1) {
      // ---- finalize: scalar = prod_i C_i ----
      if (tid == 0) vvec[0] = 1.0f;
      __syncthreads();
      for (int i = 0; i < 6; ++i) {
        const int ad = (i == 0) ? 1 : 4, bd = (i == 5) ? 1 : 4;
        const int adlog = (ad == 4) ? 2 : 0, bdlog = (bd == 4) ? 2 : 0;
        const int rows = g_ufin[i] * ad, cols = g_dfin[i] * bd;
        const int clog = 31 - __clz(cols);
        const int ph = xi[i * 6 + 5];
        const float* tb = Tg + (size_t)(i * 6 + 5) * 512;
        for (int e = tid; e < 256; e += 128) ATile[e] = tb[e * 2 + ph];
        __syncthreads();
        for (int e = tid; e < rows * cols; e += 128) {
          const int col = e & (cols - 1);
          const int ua = e >> clog;
          const int u = ua >> adlog, a = ua & (ad - 1);
          const int d_ = col >> bdlog, b = col & (bd - 1);
          const float* fb = pool + i * 264 + u * 33 + d_;
          const float4 av = *(const float4*)(ATile + a * 64 + b * 4);  // R = 0 slice
          GM[ua * 36 + col] = fb[0] * av.x + fb[8] * av.y + fb[16] * av.z + fb[24] * av.w;
        }
        __syncthreads();
        if (tid < cols) {
          float acc = 0.f;
          for (int r_ = 0; r_ < rows; ++r_) acc += vvec[r_] * GM[r_ * 36 + tid];
          vvec2[tid] = acc;
        }
        __syncthreads();
        if (tid < cols) vvec[tid] = vvec2[tid];
        __syncthreads();
      }
      if (tid == 0) out[s] = vvec[0];
    }
  }
}

extern "C" void kernel_launch(void* const* d_in, const int* in_sizes, int n_in,
                              void* d_out, int out_size, void* d_ws, size_t ws_size,
                              hipStream_t stream) {
  const float* Tg = (const float*)d_in[0];
  const float* W1 = (const float*)d_in[1];
  const float* b1 = (const float*)d_in[2];
  const float* W2 = (const float*)d_in[3];
  const float* b2 = (const float*)d_in[4];
  const int*   x  = (const int*)d_in[5];
  float* out = (float*)d_out;
  float* proj = (float*)d_ws;   // 1024*6400 floats: ETA*mlp then += projectors
  (void)in_sizes; (void)n_in; (void)out_size; (void)ws_size;

  mlp_kernel<<<dim3(128), dim3(256), 0, stream>>>(W1, b1, W2, b2, x, proj);
  peps_kernel<<<dim3(1024), dim3(128), 0, stream>>>(Tg, x, proj, out);
}

// Round 12
// 1360.732 us; speedup vs baseline: 4.8760x; 1.1004x over previous
//
#include <hip/hip_runtime.h>

#define BS 256  // threads per peps block (4 waves)

// ---------------- static schedule tables ----------------
__device__ const int g_uprev[2][6] = {{1,4,4,4,4,4},{1,4,8,8,8,4}};
__device__ const int g_dprev[2][6] = {{4,4,4,4,4,1},{4,8,8,8,4,1}};
__device__ const int g_mtab[2][5]  = {{16,16,16,16,16},{16,32,32,32,16}};
__device__ const int g_cbtab[5]    = {4,8,8,8,4};
__device__ const int g_ucurtab[5]  = {1,4,8,8,8};
__device__ const int g_dntab[2][5] = {{16,16,16,16,1},{32,32,32,16,1}};
__device__ const int g_path[2][5]  = {{0,0,1,1,2},{0,0,0,0,2}};  // 0=p-side,1=m-side(chol),2=q-side
__device__ const int g_offtab[4][5]= {{0,128,384,640,896},
                                      {1024,1152,1664,2176,2688},
                                      {2816,2944,3456,3968,4480},
                                      {4608,4736,5248,5760,6272}};
__device__ const int g_ufin[6] = {1,4,8,8,8,4};
__device__ const int g_dfin[6] = {4,8,8,8,4,1};

// ============ kernel 1: proj[s][k] = ETA*mlp(x_s)[k] ============
__global__ __launch_bounds__(256) void mlp_kernel(
    const float* __restrict__ W1, const float* __restrict__ b1,
    const float* __restrict__ W2, const float* __restrict__ b2,
    const int* __restrict__ x, float* __restrict__ proj)
{
  __shared__ float hbuf[8][64];
  const int tid = threadIdx.x;
  const int s0 = blockIdx.x << 3;
  for (int e = tid; e < 512; e += 256) {
    const int sl = e >> 6, hh = e & 63;
    const int* xr = x + (s0 + sl) * 36;
    const float* wr = W1 + hh * 36;
    float acc = b1[hh];
    #pragma unroll
    for (int t = 0; t < 36; ++t) acc += wr[t] * (float)xr[t];
    hbuf[sl][hh] = fmaxf(acc, 0.0f);
  }
  __syncthreads();
  for (int k = tid; k < 6400; k += 256) {
    const float4* wr = (const float4*)(W2 + (size_t)k * 64);
    float acc[8];
    #pragma unroll
    for (int s2 = 0; s2 < 8; ++s2) acc[s2] = 0.0f;
    #pragma unroll
    for (int c = 0; c < 16; ++c) {
      const float4 w = wr[c];
      #pragma unroll
      for (int s2 = 0; s2 < 8; ++s2) {
        const float4 hv = ((const float4*)hbuf[s2])[c];
        acc[s2] += w.x * hv.x + w.y * hv.y + w.z * hv.z + w.w * hv.w;
      }
    }
    const float bb = b2[k];
    #pragma unroll
    for (int s2 = 0; s2 < 8; ++s2)
      proj[(size_t)(s0 + s2) * 6400 + k] = 0.001f * (acc[s2] + bb);
  }
}

// ---------------- rotation angle (HW-approx rcp/rsq/sqrt, ~1ulp) ----------------
__device__ __forceinline__ void jrot(float app, float aqq, float apq, float& c, float& sn) {
  c = 1.0f; sn = 0.0f;
  if (fabsf(apq) > 1e-36f + 1e-12f * (fabsf(app) + fabsf(aqq))) {
    const float tau = (aqq - app) * 0.5f * __builtin_amdgcn_rcpf(apq);
    const float t = copysignf(1.0f, tau) *
                    __builtin_amdgcn_rcpf(fabsf(tau) + __builtin_amdgcn_sqrtf(1.0f + tau * tau));
    c = __builtin_amdgcn_rsqf(1.0f + t * t);
    sn = t * c;
  }
}

// seat of matrix index i at round 0: i==n-1 -> 0; i==0 -> 1; i<n/2 -> 2i; else 2(n-1-i)+1
__device__ __forceinline__ int seatof(int i, int n) {
  return (i == n - 1) ? 0 : ((i == 0) ? 1 : ((i < (n >> 1)) ? (2 * i) : (2 * (n - 1 - i) + 1)));
}

// tournament seat shift: 0->0; odd s: s+2 (wrap 2NP-1 -> 2NP-2); even s: s-2 (2 -> 1)
__device__ __forceinline__ int sgshift(int s, int np) {
  if (s == 0) return 0;
  if (s & 1) return (s == 2 * np - 1) ? (2 * np - 2) : (s + 2);
  return (s == 2) ? 1 : (s - 2);
}

// SEAT-SPACE pair-blocked two-sided Jacobi, 256 threads. H seat-indexed (stride 36):
// pair t = seats (2t,2t+1); N=32 -> 256 H-blocks (1/lane), V 512 slots (2/lane).
// V rows = G-space, cols = seats; init V = round-0 permutation. Sweeps 5/5/3 (4 fails - R9).
template<int N>
__device__ void jacobi_pb(float* __restrict__ H, float* __restrict__ V, int tid)
{
  constexpr int NP = N / 2;
  constexpr int NM1 = N - 1;
  constexpr int NL = (N == 32) ? 5 : ((N == 16) ? 4 : 2);
  constexpr int NVMAX = (N == 32) ? 2 : 1;
  constexpr int MAXSW = (N == 32) ? 5 : ((N == 16) ? 5 : 3);
  // V init: V[g][seat] = (g == idx0(seat))
  for (int e = tid; e < N * N; e += BS) {
    const int r = e >> NL, c = e & (N - 1);
    const int i0 = (c == 0) ? NM1 : ((c == 1) ? 0 : ((c & 1) ? (NM1 - (c >> 1)) : (c >> 1)));
    V[r * 36 + c] = (r == i0) ? 1.0f : 0.0f;
  }
  __syncthreads();
  const int cp = tid & (NP - 1);
  const bool hact = (N == 32) ? true : ((N == 16) ? (tid < 64) : (tid < 4));
  const bool vact = (N == 32) ? true : ((N == 16) ? (tid < 128) : (tid < 8));
  const int q0 = 2 * cp, q1 = q0 + 1;
  const int d0 = sgshift(q0, NP), d1 = sgshift(q1, NP);
  const int rt = (N == 32) ? (tid >> 4) : ((N == 16) ? (tid >> 3) : (tid >> 1));
  const int r0 = 2 * rt, r1 = r0 + 1;
  const int e0 = sgshift(r0, NP), e1 = sgshift(r1, NP);
  int vr[NVMAX];
  #pragma unroll
  for (int vi = 0; vi < NVMAX; ++vi)
    vr[vi] = ((N == 32) ? (tid >> 4) : ((N == 16) ? (tid >> 3) : (tid >> 1))) + NP * vi;

  for (int sw = 0; sw < MAXSW; ++sw) {
    for (int rd = 0; rd < NM1; ++rd) {
      // my column-pair angle (lane cp of each wave computes pair cp's angle)
      const float2 dg = *(const float2*)(H + q0 * 36 + q0);
      const float aqq = H[q1 * 36 + q1];
      float cc_, cs_;
      jrot(dg.x, aqq, dg.y, cc_, cs_);
      float o00, o01, o10, o11;
      if (hact) {
        const float cr_ = __shfl(cc_, rt);
        const float sr_ = __shfl(cs_, rt);
        const float2 rA = *(const float2*)(H + r0 * 36 + q0);
        const float2 rB = *(const float2*)(H + r1 * 36 + q0);
        const float t1 = cr_ * rA.x - sr_ * rB.x, t2 = cr_ * rA.y - sr_ * rB.y;
        const float u1 = sr_ * rA.x + cr_ * rB.x, u2 = sr_ * rA.y + cr_ * rB.y;
        o00 = cc_ * t1 - cs_ * t2; o01 = cs_ * t1 + cc_ * t2;
        o10 = cc_ * u1 - cs_ * u2; o11 = cs_ * u1 + cc_ * u2;
      }
      float v0[NVMAX], v1[NVMAX];
      #pragma unroll
      for (int vi = 0; vi < NVMAX; ++vi) {
        if (vi == 0 && !vact) continue;
        const float2 vv = *(const float2*)(V + vr[vi] * 36 + q0);
        v0[vi] = cc_ * vv.x - cs_ * vv.y;
        v1[vi] = cs_ * vv.x + cc_ * vv.y;
      }
      __syncthreads();
      if (hact) {
        H[e0 * 36 + d0] = o00; H[e0 * 36 + d1] = o01;
        H[e1 * 36 + d0] = o10; H[e1 * 36 + d1] = o11;
      }
      #pragma unroll
      for (int vi = 0; vi < NVMAX; ++vi) {
        if (vi == 0 && !vact) continue;
        V[vr[vi] * 36 + d0] = v0[vi];
        V[vr[vi] * 36 + d1] = v1[vi];
      }
      __syncthreads();
    }
  }
}

// G(+)= A^T A over 'nrows' stride-36 rows of A, mcols in {16,32}; float4 on column quads
__device__ __forceinline__ void gram_cols(float* __restrict__ G, const float* __restrict__ A,
                                          int nrows, int mcols, bool init, int tid)
{
  const int q4 = mcols >> 2;
  const int q4log = (mcols == 32) ? 3 : 2;
  const int nel = mcols * q4;
  const float4* A4 = (const float4*)A;
  float4* G4 = (float4*)G;
  for (int e = tid; e < nel; e += BS) {
    const int c2q = e & (q4 - 1);
    const int c1 = e >> q4log;
    float ax = 0.f, ay = 0.f, az = 0.f, aw = 0.f;
    for (int r = 0; r < nrows; ++r) {
      const float a1 = A[r * 36 + c1];
      const float4 a2 = A4[r * 9 + c2q];
      ax += a1 * a2.x; ay += a1 * a2.y; az += a1 * a2.z; aw += a1 * a2.w;
    }
    float4* gp = G4 + c1 * 9 + c2q;
    if (init) { float4 o; o.x = ax; o.y = ay; o.z = az; o.w = aw; *gp = o; }
    else { float4 o = *gp; o.x += ax; o.y += ay; o.z += az; o.w += aw; *gp = o; }
  }
  __syncthreads();
}

// absorb column i1 of row j into BIGT[(rr-rr0)*dbw+db][ua] (stride 36), rr in [rr0,rr1)
__device__ __forceinline__ void absorb_T(const float* __restrict__ Tg, const float* __restrict__ poolS,
    float* __restrict__ BIGT, float* __restrict__ ATile, const int* __restrict__ xi,
    int i1, int j, int U, int Dd, int rr0, int rr1, int tid)
{
  const int bd = (i1 == 5) ? 1 : 4;
  const int dbw = Dd * bd;
  const int mt_ = U * 4;
  const int ph = xi[i1 * 6 + j];
  const float* tb = Tg + (size_t)(i1 * 6 + j) * 512;
  for (int e = tid; e < 256; e += BS) ATile[e] = tb[e * 2 + ph];
  __syncthreads();
  const int mlog = (mt_ == 32) ? 5 : 4;
  const int dblog = 31 - __clz(dbw);
  const int bdlog = (bd == 4) ? 2 : 0;
  const int nel = mt_ * dbw * (rr1 - rr0);
  for (int e = tid; e < nel; e += BS) {
    const int ua = e & (mt_ - 1);
    const int db = (e >> mlog) & (dbw - 1);
    const int rr = rr0 + (e >> (mlog + dblog));
    const int u = ua >> 2, a = ua & 3;
    const int d_ = db >> bdlog, b = db & (bd - 1);
    const float* op = poolS + u * 33 + d_;
    const float4 av = *(const float4*)(ATile + a * 64 + rr * 16 + b * 4);
    BIGT[((rr - rr0) * dbw + db) * 36 + ua] = op[0] * av.x + op[8] * av.y + op[16] * av.z + op[24] * av.w;
  }
  __syncthreads();
}

// ============ kernel 2: one sample per 256-thread (4-wave) workgroup ============
__global__ __launch_bounds__(256, 4) void peps_kernel(
    const float* __restrict__ Tg, const int* __restrict__ x,
    float* __restrict__ proj, float* __restrict__ out)
{
  __shared__ __align__(16) float pool[6 * 264];   // [i][u<=8 stride33][x=4 stride8][d<=8]
  __shared__ __align__(16) float CUR[1152];       // mt: rows (u*4+rr)<=32, stride 36
  __shared__ __align__(16) float BIGT[2304];      // mb^T half: rows <=64, stride 36
  __shared__ __align__(16) float GbM[1152];       // Gb (or Gt); m-path: Gb@0, Gt@576
  __shared__ __align__(16) float TM[1152];        // T / R2@0+V@576 / eigvecs V
  __shared__ __align__(16) float GM[1152];        // G / H in SEAT space
  __shared__ __align__(16) float ATile[256];
  __shared__ __align__(16) float PdL[256], PuL[256];  // [mrow][8]
  __shared__ float red[4];
  __shared__ int isel[8];
  __shared__ float sinvv[8], sdiv[8];
  __shared__ int xi[36];
  __shared__ float vvec[36], vvec2[36];

  const int s = blockIdx.x;
  const int tid = threadIdx.x;
  if (tid < 36) xi[tid] = x[s * 36 + tid];
  __syncthreads();

  for (int sweep = 0; sweep < 2; ++sweep) {
    // --- init boundary MPS from row j=0 ---
    for (int i2 = 0; i2 < 6; ++i2) {
      const int ad = (i2 == 0) ? 1 : 4, bd = (i2 == 5) ? 1 : 4;
      const int bdlog = (bd == 4) ? 2 : 0;
      const int ph = xi[i2 * 6];
      const float* tb = Tg + (size_t)(i2 * 6) * 512;
      const int nel = ad * 4 * bd;
      for (int e = tid; e < nel; e += BS) {
        const int b = e & (bd - 1);
        const int rr = (e >> bdlog) & 3;
        const int a = e >> (bdlog + 2);
        pool[i2 * 264 + a * 33 + rr * 8 + b] = tb[(a * 64 + rr * 16 + b * 4) * 2 + ph];
      }
    }
    __syncthreads();

    for (int j = 1; j <= 4; ++j) {
      const int jj = (j > 1) ? 1 : 0;
      // absorb column 0 into CUR (4 rows x 16 cols)
      {
        const int ph = xi[j];          // site (0,j)
        const float* tb = Tg + (size_t)j * 512;
        for (int e = tid; e < 256; e += BS) ATile[e] = tb[e * 2 + ph];
        __syncthreads();
        for (int e = tid; e < 64; e += BS) {
          const int db = e & 15;
          const int rr = e >> 4;
          const int d_ = db >> 2, b = db & 3;
          const float* op = pool + d_;  // slot 0, u=0
          const float4 av = *(const float4*)(ATile + rr * 16 + b * 4);  // a=0
          CUR[rr * 36 + db] = op[0] * av.x + op[8] * av.y + op[16] * av.z + op[24] * av.w;
        }
        __syncthreads();
      }

      for (int i = 0; i < 5; ++i) {
        const int m = g_mtab[jj][i], cb = g_cbtab[i], ucur = g_ucurtab[i], dn = g_dntab[jj][i];
        const int p = ucur * 4, path = g_path[jj][i];
        const int U1 = g_uprev[jj][i + 1], Dd1 = g_dprev[jj][i + 1];
        const bool two = (dn == 32);
        const int cblog = (cb == 8) ? 3 : 2;
        const int mq4 = m >> 2;
        float* projb = proj + (size_t)s * 6400 + g_offtab[j - 1][i];

        if (sweep == 0) {
          if (path == 2) {
            // ---- q-side (i=4): G = mb^T Gt mb (4x4), seat-permuted write ----
            absorb_T(Tg, pool + (i + 1) * 264, BIGT, ATile, xi, i + 1, j, U1, Dd1, 0, 4, tid);
            gram_cols(GbM, CUR, p, m, true, tid);   // Gt (16x16)
            for (int e = tid; e < 64; e += BS) {    // T1 = Gt*mb (16x4)
              const int r = e & 3, k = e >> 2;
              float acc = 0.f;
              const float4* G4 = (const float4*)GbM;
              const float4* B4 = (const float4*)BIGT;
              for (int lq = 0; lq < 4; ++lq) {
                const float4 g = G4[k * 9 + lq], b = B4[r * 9 + lq];
                acc += g.x * b.x + g.y * b.y + g.z * b.z + g.w * b.w;
              }
              TM[k * 36 + r] = acc;
            }
            __syncthreads();
            for (int e = tid; e < 16; e += BS) {    // G = mb^T * T1 (4x4)
              const int c = e & 3, r = e >> 2;
              float acc = 0.f;
              for (int k = 0; k < 16; ++k) acc += BIGT[r * 36 + k] * TM[k * 36 + c];
              GM[seatof(r, 4) * 36 + seatof(c, 4)] = acc;
            }
            __syncthreads();
            jacobi_pb<4>(GM, TM + 576, tid);
          } else if (path == 0) {
            // ---- p-side: G = mt Gb mt^T (p x p), seat-permuted write ----
            if (!two) {
              absorb_T(Tg, pool + (i + 1) * 264, BIGT, ATile, xi, i + 1, j, U1, Dd1, 0, 4, tid);
              gram_cols(GbM, BIGT, 4 * dn, m, true, tid);
            } else {
              absorb_T(Tg, pool + (i + 1) * 264, BIGT, ATile, xi, i + 1, j, U1, Dd1, 0, 2, tid);
              gram_cols(GbM, BIGT, 2 * dn, m, true, tid);
              absorb_T(Tg, pool + (i + 1) * 264, BIGT, ATile, xi, i + 1, j, U1, Dd1, 2, 4, tid);
              gram_cols(GbM, BIGT, 2 * dn, m, false, tid);
            }
            const int q4log = (m == 32) ? 3 : 2;
            for (int e = tid; e < p * mq4; e += BS) {  // T = mt*Gb (p x m)
              const int lq = e & (mq4 - 1), pr = e >> q4log;
              float ax = 0.f, ay = 0.f, az = 0.f, aw = 0.f;
              const float4* G4 = (const float4*)GbM;
              for (int k = 0; k < m; ++k) {
                const float a1 = CUR[pr * 36 + k];
                const float4 g = G4[k * 9 + lq];
                ax += a1 * g.x; ay += a1 * g.y; az += a1 * g.z; aw += a1 * g.w;
              }
              float4 o; o.x = ax; o.y = ay; o.z = az; o.w = aw;
              ((float4*)TM)[pr * 9 + lq] = o;
            }
            __syncthreads();
            const int plog = (p == 32) ? 5 : ((p == 16) ? 4 : 2);
            for (int e = tid; e < p * p; e += BS) {    // G = T*mt^T (p x p)
              const int pc = e & (p - 1), pr = e >> plog;
              float acc = 0.f;
              const float4* T4 = (const float4*)TM;
              const float4* C4 = (const float4*)CUR;
              for (int lq = 0; lq < mq4; ++lq) {
                const float4 t = T4[pr * 9 + lq], c = C4[pc * 9 + lq];
                acc += t.x * c.x + t.y * c.y + t.z * c.z + t.w * c.w;
              }
              GM[seatof(pr, p) * 36 + seatof(pc, p)] = acc;
            }
            __syncthreads();
            if (p == 4)       jacobi_pb<4>(GM, TM, tid);
            else if (p == 16) jacobi_pb<16>(GM, TM, tid);
            else              jacobi_pb<32>(GM, TM, tid);
          } else {
            // ---- m-side (j=1, i=2,3): Gt, Gb, chol(Gb), H = R2 Gt R2^T (16x16), seat write ----
            absorb_T(Tg, pool + (i + 1) * 264, BIGT, ATile, xi, i + 1, j, U1, Dd1, 0, 4, tid);
            gram_cols(GbM + 576, CUR, p, m, true, tid);     // Gt
            gram_cols(GbM, BIGT, 4 * dn, m, true, tid);     // Gb
            // cholesky Gb -> R2 (TM[0:576]) with zero-skip
            if (tid < 64) {
              float v_ = (tid < 16) ? GbM[tid * 37] : -3.0e38f;
              for (int mk = 32; mk; mk >>= 1) v_ = fmaxf(v_, __shfl_xor(v_, mk));
              if (tid == 0) red[0] = v_;
            }
            __syncthreads();
            const float thr = 1e-10f * red[0] + 1e-35f;
            for (int k = 0; k < 16; ++k) {
              const float dk = GbM[k * 37];
              const float rs = (dk > thr) ? (1.0f / sqrtf(dk)) : 0.0f;
              if (tid < 16) TM[k * 36 + tid] = GbM[k * 36 + tid] * rs;
              __syncthreads();
              const int rows = 15 - k;
              for (int e = tid; e < rows * 16; e += BS) {
                const int ii = k + 1 + (e >> 4), jc = e & 15;
                GbM[ii * 36 + jc] -= TM[k * 36 + ii] * TM[k * 36 + jc];
              }
              __syncthreads();
            }
            for (int e = tid; e < 64; e += BS) {   // T1 = R2*Gt -> TM+576
              const int jq = e & 3, k = e >> 2;
              float ax = 0.f, ay = 0.f, az = 0.f, aw = 0.f;
              const float4* Gt4 = (const float4*)(GbM + 576);
              for (int l = 0; l < 16; ++l) {
                const float r2 = TM[k * 36 + l];
                const float4 g = Gt4[l * 9 + jq];
                ax += r2 * g.x; ay += r2 * g.y; az += r2 * g.z; aw += r2 * g.w;
              }
              float4 o; o.x = ax; o.y = ay; o.z = az; o.w = aw;
              ((float4*)(TM + 576))[k * 9 + jq] = o;
            }
            __syncthreads();
            for (int e = tid; e < 256; e += BS) {  // H = T1*R2^T -> GM (seat space)
              const int k2 = e & 15, k = e >> 4;
              float acc = 0.f;
              const float4* T14 = (const float4*)(TM + 576);
              const float4* R24 = (const float4*)TM;
              for (int lq = 0; lq < 4; ++lq) {
                const float4 t = T14[k * 9 + lq], r = R24[k2 * 9 + lq];
                acc += t.x * r.x + t.y * r.y + t.z * r.z + t.w * r.w;
              }
              GM[seatof(k, 16) * 36 + seatof(k2, 16)] = acc;
            }
            __syncthreads();
            jacobi_pb<16>(GM, TM + 576, tid);
          }

          // ---- top-cb selection + scales (seat labels opaque; wave 0 only) ----
          const int N = (path == 2) ? 4 : ((path == 1) ? 16 : p);
          if (tid < 64) {
            float v_ = (tid < N) ? GM[tid * 37] : -3.0e38f;
            int ix = tid;
            for (int t = 0; t < cb; ++t) {
              float bv = v_; int bi = ix;
              for (int mk = 32; mk; mk >>= 1) {
                const float ov = __shfl_xor(bv, mk);
                const int oi = __shfl_xor(bi, mk);
                if (ov > bv || (ov == bv && oi < bi)) { bv = ov; bi = oi; }
              }
              if (tid == 0) isel[t] = bi;
              if (ix == bi) v_ = -3.0e38f;
            }
          }
          __syncthreads();
          if (tid < cb) {
            const float lam = GM[isel[tid] * 37];
            const float s_ = sqrtf(fmaxf(lam, 0.0f));
            sinvv[tid] = 1.0f / sqrtf(s_ + 1e-12f);
            sdiv[tid]  = 1.0f / fmaxf(s_, 1e-25f);
          }
          __syncthreads();

          // ---- projectors (V rows are G-space; columns indexed by seat isel) ----
          if (path == 0) {
            // Pu = mt^T U sinv ; Pd = Gb Pu / s   (U cols in TM)
            for (int e = tid; e < m * cb; e += BS) {
              const int k = e & (cb - 1), mrow = e >> cblog;
              const int a = isel[k];
              float acc = 0.f;
              for (int pr = 0; pr < p; ++pr) acc += CUR[pr * 36 + mrow] * TM[pr * 36 + a];
              PuL[mrow * 8 + k] = acc * sinvv[k];
            }
            __syncthreads();
            for (int e = tid; e < m * cb; e += BS) {
              const int k = e & (cb - 1), mrow = e >> cblog;
              float acc = 0.f;
              for (int l = 0; l < m; ++l) acc += GbM[mrow * 36 + l] * PuL[l * 8 + k];
              PdL[mrow * 8 + k] = acc * sdiv[k];
            }
            __syncthreads();
          } else if (path == 2) {
            // Pd = mb V sinv ; Pu = Gt Pd / s   (V in TM+576, Gt in GbM)
            for (int e = tid; e < m * cb; e += BS) {
              const int k = e & (cb - 1), mrow = e >> cblog;
              const int a = isel[k];
              float acc = 0.f;
              for (int r = 0; r < 4; ++r) acc += BIGT[r * 36 + mrow] * TM[576 + r * 36 + a];
              PdL[mrow * 8 + k] = acc * sinvv[k];
            }
            __syncthreads();
            for (int e = tid; e < m * cb; e += BS) {
              const int k = e & (cb - 1), mrow = e >> cblog;
              float acc = 0.f;
              for (int l = 0; l < m; ++l) acc += GbM[mrow * 36 + l] * PdL[l * 8 + k];
              PuL[mrow * 8 + k] = acc * sdiv[k];
            }
            __syncthreads();
          } else {
            // Pd = R2^T V sinv ; Pu = Gt Pd / s  (R2 in TM[0:576], V in TM+576, Gt in GbM+576)
            for (int e = tid; e < m * cb; e += BS) {
              const int k = e & (cb - 1), mrow = e >> cblog;
              const int a = isel[k];
              float acc = 0.f;
              for (int t = 0; t < 16; ++t) acc += TM[t * 36 + mrow] * TM[576 + t * 36 + a];
              PdL[mrow * 8 + k] = acc * sinvv[k];
            }
            __syncthreads();
            for (int e = tid; e < m * cb; e += BS) {
              const int k = e & (cb - 1), mrow = e >> cblog;
              float acc = 0.f;
              for (int l = 0; l < m; ++l) acc += GbM[576 + mrow * 36 + l] * PdL[l * 8 + k];
              PuL[mrow * 8 + k] = acc * sdiv[k];
            }
            __syncthreads();
          }
          // store perturbed projectors (ws slot preloaded with ETA*mlp)
          for (int e = tid; e < m * cb; e += BS)
            projb[e] += PdL[(e >> cblog) * 8 + (e & (cb - 1))];
          for (int e = tid; e < m * cb; e += BS)
            projb[m * cb + e] += PuL[(e >> cblog) * 8 + (e & (cb - 1))];
        } else {
          // ---- sweep 2: load perturbed projectors + stage mb (B-half for two-pass) ----
          for (int e = tid; e < m * cb; e += BS)
            PdL[(e >> cblog) * 8 + (e & (cb - 1))] = projb[e];
          for (int e = tid; e < m * cb; e += BS)
            PuL[(e >> cblog) * 8 + (e & (cb - 1))] = projb[m * cb + e];
          __syncthreads();
          if (!two) absorb_T(Tg, pool + (i + 1) * 264, BIGT, ATile, xi, i + 1, j, U1, Dd1, 0, 4, tid);
          else      absorb_T(Tg, pool + (i + 1) * 264, BIGT, ATile, xi, i + 1, j, U1, Dd1, 2, 4, tid);
        }

        // ---- common: Bn[i] = Tt*Pd -> pool[i]; Bn[i+1] = Pu applied to mb -> CUR (or pool[5]) ----
        {
          const int nel = ucur * 4 * cb;
          const float4* C4 = (const float4*)CUR;
          for (int e = tid; e < nel; e += BS) {
            const int cc = e & (cb - 1);
            const int rr = (e >> cblog) & 3;
            const int u = e >> (cblog + 2);
            const int row = u * 4 + rr;
            float acc = 0.f;
            for (int mq = 0; mq < mq4; ++mq) {
              const float4 cv = C4[row * 9 + mq];
              acc += cv.x * PdL[(mq * 4 + 0) * 8 + cc] + cv.y * PdL[(mq * 4 + 1) * 8 + cc]
                   + cv.z * PdL[(mq * 4 + 2) * 8 + cc] + cv.w * PdL[(mq * 4 + 3) * 8 + cc];
            }
            pool[i * 264 + u * 33 + rr * 8 + cc] = acc;
          }
          __syncthreads();

          const int dnlog = 31 - __clz(dn);
          auto bn1 = [&](int rr0, int nloc) {
            const int ne2 = cb * nloc * dn;
            const float4* B4 = (const float4*)BIGT;
            for (int e = tid; e < ne2; e += BS) {
              const int dd = e & (dn - 1);
              const int t = e >> dnlog;
              const int rrL = t & (nloc - 1);
              const int cc = t >> ((nloc == 4) ? 2 : 1);
              const int row = rrL * dn + dd;
              float acc = 0.f;
              for (int mq = 0; mq < mq4; ++mq) {
                const float4 bv = B4[row * 9 + mq];
                acc += bv.x * PuL[(mq * 4 + 0) * 8 + cc] + bv.y * PuL[(mq * 4 + 1) * 8 + cc]
                     + bv.z * PuL[(mq * 4 + 2) * 8 + cc] + bv.w * PuL[(mq * 4 + 3) * 8 + cc];
              }
              if (i < 4) CUR[(cc * 4 + rr0 + rrL) * 36 + dd] = acc;
              else       pool[5 * 264 + cc * 33 + (rr0 + rrL) * 8] = acc;
            }
            __syncthreads();
          };
          if (!two) {
            bn1(0, 4);
          } else {
            bn1(2, 2);
            absorb_T(Tg, pool + (i + 1) * 264, BIGT, ATile, xi, i + 1, j, U1, Dd1, 0, 2, tid);
            bn1(0, 2);
          }
        }
      }
    }

    if (sweep == 1) {
      // ---- finalize: scalar = prod_i C_i ----
      if (tid == 0) vvec[0] = 1.0f;
      __syncthreads();
      for (int i = 0; i < 6; ++i) {
        const int ad = (i == 0) ? 1 : 4, bd = (i == 5) ? 1 : 4;
        const int adlog = (ad == 4) ? 2 : 0, bdlog = (bd == 4) ? 2 : 0;
        const int rows = g_ufin[i] * ad, cols = g_dfin[i] * bd;
        const int clog = 31 - __clz(cols);
        const int ph = xi[i * 6 + 5];
        const float* tb = Tg + (size_t)(i * 6 + 5) * 512;
        for (int e = tid; e < 256; e += BS) ATile[e] = tb[e * 2 + ph];
        __syncthreads();
        for (int e = tid; e < rows * cols; e += BS) {
          const int col = e & (cols - 1);
          const int ua = e >> clog;
          const int u = ua >> adlog, a = ua & (ad - 1);
          const int d_ = col >> bdlog, b = col & (bd - 1);
          const float* fb = pool + i * 264 + u * 33 + d_;
          const float4 av = *(const float4*)(ATile + a * 64 + b * 4);  // R = 0 slice
          GM[ua * 36 + col] = fb[0] * av.x + fb[8] * av.y + fb[16] * av.z + fb[24] * av.w;
        }
        __syncthreads();
        if (tid < cols) {
          float acc = 0.f;
          for (int r_ = 0; r_ < rows; ++r_) acc += vvec[r_] * GM[r_ * 36 + tid];
          vvec2[tid] = acc;
        }
        __syncthreads();
        if (tid < cols) vvec[tid] = vvec2[tid];
        __syncthreads();
      }
      if (tid == 0) out[s] = vvec[0];
    }
  }
}

extern "C" void kernel_launch(void* const* d_in, const int* in_sizes, int n_in,
                              void* d_out, int out_size, void* d_ws, size_t ws_size,
                              hipStream_t stream) {
  const float* Tg = (const float*)d_in[0];
  const float* W1 = (const float*)d_in[1];
  const float* b1 = (const float*)d_in[2];
  const float* W2 = (const float*)d_in[3];
  const float* b2 = (const float*)d_in[4];
  const int*   x  = (const int*)d_in[5];
  float* out = (float*)d_out;
  float* proj = (float*)d_ws;   // 1024*6400 floats: ETA*mlp then += projectors
  (void)in_sizes; (void)n_in; (void)out_size; (void)ws_size;

  mlp_kernel<<<dim3(128), dim3(256), 0, stream>>>(W1, b1, W2, b2, x, proj);
  peps_kernel<<<dim3(1024), dim3(256), 0, stream>>>(Tg, x, proj, out);
}